// Round 1
// 1879.255 us; speedup vs baseline: 1.0282x; 1.0282x over previous
//
#include <hip/hip_runtime.h>
#include <cstdint>
#include <cstddef>

// ---------------- problem constants ----------------
constexpr int Nn  = 200000;
constexpr int Ee  = 1600000;
constexpr int EPp = 1000000;

typedef __attribute__((ext_vector_type(8))) short bf8_t;
typedef __attribute__((ext_vector_type(4))) float f4_t;

__device__ inline unsigned short f2bf(float f) {
  union { float f; unsigned u; } v; v.f = f;
  unsigned r = v.u + 0x7FFFu + ((v.u >> 16) & 1u);
  return (unsigned short)(r >> 16);
}
__device__ inline float bf2f(unsigned short u) {
  union { unsigned u; float f; } v; v.u = ((unsigned)u) << 16;
  return v.f;
}
// tanh-form GELU, algebraically reduced: 0.5v(1+tanh(u)) = v*(1-r), r=1/(e^{2u}+1)
__device__ inline float gelu_f(float v) {
  float u = v * fmaf(0.0356774081f, v * v, 0.7978845608f);
  float r = __builtin_amdgcn_rcpf(__expf(u + u) + 1.0f);
  return fmaf(-v, r, v);
}
// dyt: w*tanh(a x)+b with s2 = 2*a prefolded: tanh = 1-2r
__device__ inline float dyt_f(float x, float s2, float w, float b) {
  float r = __builtin_amdgcn_rcpf(__expf(s2 * x) + 1.0f);
  return fmaf(w, fmaf(-2.0f, r, 1.0f), b);
}

// ---------------- degree / CSR build ----------------

__global__ __launch_bounds__(256) void k_degi(const int* __restrict__ dst,
                                              int* __restrict__ cnt, int E) {
  int i = blockIdx.x * 256 + threadIdx.x;
  if (i < E) atomicAdd(&cnt[dst[i]], 1);
}

__global__ __launch_bounds__(256) void k_rdeg(const int* __restrict__ cnt,
                                              float* __restrict__ rdeg, int n) {
  int i = blockIdx.x * 256 + threadIdx.x;
  if (i < n) rdeg[i] = 1.0f / (float)(cnt[i] > 1 ? cnt[i] : 1);
}

__global__ __launch_bounds__(256) void k_scan1(const int* __restrict__ in,
                                               int* __restrict__ out,
                                               int* __restrict__ bsum, int n) {
  __shared__ int sd[256];
  int t = threadIdx.x;
  int base = blockIdx.x * 1024 + t * 4;
  int v[4]; int ts = 0;
  #pragma unroll
  for (int j = 0; j < 4; ++j) { v[j] = (base + j < n) ? in[base + j] : 0; ts += v[j]; }
  sd[t] = ts; __syncthreads();
  for (int off = 1; off < 256; off <<= 1) {
    int x = (t >= off) ? sd[t - off] : 0;
    __syncthreads();
    sd[t] += x;
    __syncthreads();
  }
  int excl = sd[t] - ts;
  #pragma unroll
  for (int j = 0; j < 4; ++j) { if (base + j < n) out[base + j] = excl; excl += v[j]; }
  if (t == 255) bsum[blockIdx.x] = sd[255];
}

__global__ void k_scan2(int* bsum, int nb) {
  __shared__ int sd[256];
  int t = threadIdx.x;
  int v = (t < nb) ? bsum[t] : 0;
  sd[t] = v; __syncthreads();
  for (int off = 1; off < 256; off <<= 1) {
    int x = (t >= off) ? sd[t - off] : 0;
    __syncthreads();
    sd[t] += x;
    __syncthreads();
  }
  if (t < nb) bsum[t] = sd[t] - v;
}

__global__ __launch_bounds__(256) void k_scan3(const int* __restrict__ part,
                                               const int* __restrict__ bsum,
                                               int* __restrict__ rowptr,
                                               int* __restrict__ cursor,
                                               int n, int total) {
  int i = blockIdx.x * 256 + threadIdx.x;
  if (i == 0) rowptr[n] = total;
  if (i < n) { int v = part[i] + bsum[i >> 10]; rowptr[i] = v; cursor[i] = v; }
}

__global__ __launch_bounds__(256) void k_fill(const int* __restrict__ src,
                                              const int* __restrict__ dst,
                                              int* __restrict__ cursor,
                                              int* __restrict__ colidx, int E) {
  int e = blockIdx.x * 256 + threadIdx.x;
  if (e >= E) return;
  int pos = atomicAdd(&cursor[dst[e]], 1);
  colidx[pos] = src[e];
}

// gather-mean over bf16 features: one wave per node, 8 groups of 8 lanes
__global__ __launch_bounds__(256) void k_gather(const unsigned short* __restrict__ x, int ldx,
                                                const int* __restrict__ rowptr,
                                                const int* __restrict__ colidx,
                                                const float* __restrict__ rdeg,
                                                unsigned short* __restrict__ agg, int n) {
  int wave = threadIdx.x >> 6, lane = threadIdx.x & 63;
  int node = blockIdx.x * 4 + wave;
  if (node >= n) return;
  int grp = lane >> 3, c = (lane & 7) * 8;
  int r0 = rowptr[node], r1 = rowptr[node + 1];
  float s[8] = {0.f, 0.f, 0.f, 0.f, 0.f, 0.f, 0.f, 0.f};
  for (int j = r0 + grp; j < r1; j += 8) {
    bf8_t v = *(const bf8_t*)(x + (size_t)colidx[j] * ldx + c);
    #pragma unroll
    for (int jj = 0; jj < 8; ++jj) s[jj] += bf2f((unsigned short)v[jj]);
  }
  #pragma unroll
  for (int jj = 0; jj < 8; ++jj) {
    s[jj] += __shfl_xor(s[jj], 8, 64);
    s[jj] += __shfl_xor(s[jj], 16, 64);
    s[jj] += __shfl_xor(s[jj], 32, 64);
  }
  if (grp == 0) {
    float r = rdeg[node];
    bf8_t o;
    #pragma unroll
    for (int jj = 0; jj < 8; ++jj) o[jj] = (short)f2bf(s[jj] * r);
    *(bf8_t*)(agg + (size_t)node * 64 + c) = o;
  }
}

// ---------------- misc small kernels ----------------

__global__ __launch_bounds__(256) void k_cvt(const float* __restrict__ in,
                                             unsigned short* __restrict__ out, int n) {
  int i = blockIdx.x * 256 + threadIdx.x;
  if (i < n) out[i] = f2bf(in[i]);
}

__global__ __launch_bounds__(256) void k_wt2(const float* __restrict__ W,
                                             unsigned short* __restrict__ Wt,
                                             int K, int N, int total) {
  int i = blockIdx.x * 256 + threadIdx.x;
  if (i >= total) return;
  int n = i / K, k = i - n * K;
  float v = (n < N) ? W[(size_t)k * N + n] : 0.f;
  Wt[i] = f2bf(v);
}

// blocked layout for the wave-private node pipeline:
// Wt[((k>>5)*Np + n)*32 + (k&31)] = W[k][n]   (zero-padded for n >= Nr)
__global__ __launch_bounds__(256) void k_wt3(const float* __restrict__ W,
                                             unsigned short* __restrict__ Wt,
                                             int Np, int Nr, int total) {
  int i = blockIdx.x * 256 + threadIdx.x;
  if (i >= total) return;
  int kin = i & 31;
  int j = i >> 5;
  int n = j % Np, kb = j / Np;
  int k = kb * 32 + kin;
  float v = (n < Nr) ? W[(size_t)k * Nr + n] : 0.f;
  Wt[i] = f2bf(v);
}

__global__ __launch_bounds__(256) void k_wtsage(const float* __restrict__ Wl,
                                                const float* __restrict__ Wr,
                                                unsigned short* __restrict__ Wt) {
  int i = blockIdx.x * 256 + threadIdx.x;
  if (i >= 3 * 64 * 128) return;
  int l = i >> 13, r = i & 8191, n = r >> 7, k = r & 127;
  float v = (k < 64) ? Wl[l * 4096 + k * 64 + n] : Wr[l * 4096 + (k - 64) * 64 + n];
  Wt[i] = f2bf(v);
}

__global__ __launch_bounds__(256) void k_stats(const float* __restrict__ h,
                                               float* __restrict__ stats, int n) {
  int lane = threadIdx.x & 63, grp = threadIdx.x >> 6;
  float s = 0.f, s2 = 0.f;
  for (int r = blockIdx.x * 4 + grp; r < n; r += gridDim.x * 4) {
    float v = h[(size_t)r * 64 + lane];
    s += v; s2 += v * v;
  }
  __shared__ float l1[4][64], l2[4][64];
  l1[grp][lane] = s; l2[grp][lane] = s2;
  __syncthreads();
  if (grp == 0) {
    s  = l1[0][lane] + l1[1][lane] + l1[2][lane] + l1[3][lane];
    s2 = l2[0][lane] + l2[1][lane] + l2[2][lane] + l2[3][lane];
    atomicAdd(&stats[lane], s);
    atomicAdd(&stats[64 + lane], s2);
  }
}

__global__ void k_statfin(float* stats, const float* __restrict__ ms_, int n) {
  int d = threadIdx.x;
  if (d < 64) {
    float invn = 1.0f / (float)n;
    float m  = stats[d] * invn;
    float e2 = stats[64 + d] * invn;
    float ms = ms_[d];
    float var = e2 - (2.0f * ms - ms * ms) * m * m;
    stats[128 + d] = ms * m;
    stats[192 + d] = rsqrtf(var + 1e-5f);
  }
}

__global__ __launch_bounds__(256) void k_norm(const float* __restrict__ h,
                                              const float* __restrict__ stats,
                                              const float* __restrict__ w,
                                              const float* __restrict__ b,
                                              unsigned short* __restrict__ zcol,
                                              const unsigned short* __restrict__ prev, int n) {
  int i = blockIdx.x * 256 + threadIdx.x;
  if (i >= n * 64) return;
  int r = i >> 6, d = i & 63;
  float v = (h[i] - stats[128 + d]) * stats[192 + d] * w[d] + b[d];
  if (prev) v += bf2f(prev[(size_t)r * 192 + d]);
  zcol[(size_t)r * 192 + d] = f2bf(v);
}

// ---------------- generic bf16 MFMA GEMM (barrier-free, for SAGE) ----------------
template <int NT>
__global__ __launch_bounds__(256) void mgemm(
    const void* __restrict__ A1, int lda1,
    const void* __restrict__ A2, int lda2, int K1, int a_bf16,
    const unsigned short* __restrict__ Wt,
    const float* __restrict__ bias,
    void* __restrict__ Cout, int ldc, int c_bf16, int act,
    int M, int K, int N) {
  int lane = threadIdx.x & 63, wave = threadIdx.x >> 6;
  int quad = lane >> 4, col = lane & 15;
  int row0 = blockIdx.x * 128 + wave * 32;
  int n_base = blockIdx.y * NT * 16;

  f4_t acc[2][NT];
  #pragma unroll
  for (int mt = 0; mt < 2; ++mt)
    #pragma unroll
    for (int nt = 0; nt < NT; ++nt) acc[mt][nt] = (f4_t)0.f;

  int gm[2];
  gm[0] = row0 + col;      if (gm[0] >= M) gm[0] = M - 1;
  gm[1] = row0 + 16 + col; if (gm[1] >= M) gm[1] = M - 1;

  for (int kc0 = 0; kc0 < K; kc0 += 32) {
    int kc = kc0 + quad * 8;
    bf8_t a[2];
    #pragma unroll
    for (int mt = 0; mt < 2; ++mt) {
      const void* src; size_t off;
      if (kc < K1) { src = A1; off = (size_t)gm[mt] * lda1 + kc; }
      else         { src = A2; off = (size_t)gm[mt] * lda2 + kc - K1; }
      if (a_bf16) {
        a[mt] = *(const bf8_t*)((const unsigned short*)src + off);
      } else {
        const float* p = (const float*)src + off;
        float4 f0 = *(const float4*)p;
        float4 f1 = *(const float4*)(p + 4);
        float ff[8] = {f0.x, f0.y, f0.z, f0.w, f1.x, f1.y, f1.z, f1.w};
        #pragma unroll
        for (int j = 0; j < 8; ++j) a[mt][j] = (short)f2bf(ff[j]);
      }
    }
    #pragma unroll
    for (int nt = 0; nt < NT; ++nt) {
      bf8_t b = *(const bf8_t*)(Wt + (size_t)(n_base + nt * 16 + col) * K + kc);
      acc[0][nt] = __builtin_amdgcn_mfma_f32_16x16x32_bf16(a[0], b, acc[0][nt], 0, 0, 0);
      acc[1][nt] = __builtin_amdgcn_mfma_f32_16x16x32_bf16(a[1], b, acc[1][nt], 0, 0, 0);
    }
  }

  #pragma unroll
  for (int nt = 0; nt < NT; ++nt) {
    int n = n_base + nt * 16 + col;
    float bs = (bias && n < N) ? bias[n] : 0.f;
    #pragma unroll
    for (int mt = 0; mt < 2; ++mt)
      #pragma unroll
      for (int r = 0; r < 4; ++r) {
        int row = row0 + mt * 16 + quad * 4 + r;
        if (row >= M || n >= N) continue;
        float v = acc[mt][nt][r] + bs;
        if (act) v = gelu_f(v);
        if (c_bf16) ((unsigned short*)Cout)[(size_t)row * ldc + n] = f2bf(v);
        else        ((float*)Cout)[(size_t)row * ldc + n] = v;
      }
  }
}

// ---------------- wave-private fused node pipeline (ZERO barriers) ----------
// Block = 256 thr = 4 independent waves. Wave w owns 16 rows and its private
// LDS slab H[16w .. 16w+16). Each wave computes ALL output columns of every
// layer for its own rows, so no cross-wave data sharing exists and no
// __syncthreads is needed anywhere: waves slide freely past each other,
// hiding each other's VALU-epilogue and weight-load latency.
// Weights use the blocked layout [(k>>5)*N + n][k&31] so the per-k-step
// b-loads of one wave form one contiguous, fully line-coalesced 1KB stream.
template <int K, int NN, bool DYT>
__device__ inline void wgemm(unsigned short (*H)[264], int hb,
                             const unsigned short* __restrict__ W,
                             const float* __restrict__ bias,
                             int quad, int col,
                             const float* __restrict__ aw,
                             const float* __restrict__ ab,
                             const float* __restrict__ aal) {
  constexpr int KS = K >> 5, NTI = NN >> 4;
  f4_t acc[NTI];
#pragma unroll
  for (int nt = 0; nt < NTI; ++nt) acc[nt] = (f4_t)0.f;
  const unsigned short* hp = &H[hb + col][quad * 8];
  const unsigned short* wp = W + col * 32 + quad * 8;
#pragma unroll
  for (int s = 0; s < KS; ++s) {
    bf8_t am = *(const bf8_t*)(hp + s * 32);   // 1 LDS read feeds NTI MFMAs
#pragma unroll
    for (int nt = 0; nt < NTI; ++nt) {
      bf8_t b = *(const bf8_t*)(wp + (s * NN + nt * 16) * 32);
      acc[nt] = __builtin_amdgcn_mfma_f32_16x16x32_bf16(am, b, acc[nt], 0, 0, 0);
    }
  }
  float sa = DYT ? (2.0f * aal[0]) : 0.f;
  // wavefront-scope fence: zero-cost; orders this wave's LDS reads (k-loop)
  // before the epilogue's LDS writes (WAR) at compiler level.
  __builtin_amdgcn_fence(__ATOMIC_ACQ_REL, "wavefront");
#pragma unroll
  for (int nt = 0; nt < NTI; ++nt) {
    int n = nt * 16 + col;
    float bs = bias[n];
    float w_ = DYT ? aw[n] : 0.f;
    float b_ = DYT ? ab[n] : 0.f;
#pragma unroll
    for (int r4 = 0; r4 < 4; ++r4) {
      float v = gelu_f(acc[nt][r4] + bs);
      if (DYT) v = dyt_f(v, sa, w_, b_);
      H[hb + quad * 4 + r4][n] = f2bf(v);
    }
  }
  // order epilogue writes before the next phase's LDS reads (RAW).
  __builtin_amdgcn_fence(__ATOMIC_ACQ_REL, "wavefront");
}

__global__ __launch_bounds__(256, 3) void k_node(
    const unsigned short* __restrict__ z_bf,
    const float* __restrict__ x_res,
    const float* __restrict__ d1w, const float* __restrict__ d1b, const float* __restrict__ d1a,
    const unsigned short* __restrict__ wt1, const float* __restrict__ b1,
    const unsigned short* __restrict__ wt2, const float* __restrict__ b2,
    const unsigned short* __restrict__ wt3, const float* __restrict__ b3,
    const float* __restrict__ d2w, const float* __restrict__ d2b, const float* __restrict__ d2a,
    const float* __restrict__ a1w, const float* __restrict__ a1b, const float* __restrict__ a1a,
    const unsigned short* __restrict__ wa1, const float* __restrict__ ba1,
    const unsigned short* __restrict__ wa2, const float* __restrict__ ba2,
    const unsigned short* __restrict__ wa3, const float* __restrict__ ba3,
    const float* __restrict__ a2w, const float* __restrict__ a2b, const float* __restrict__ a2a,
    const unsigned short* __restrict__ wa4, const float* __restrict__ ba4,
    unsigned short* __restrict__ zn_bf,
    float* __restrict__ out, int M) {
  __shared__ unsigned short H[64][264];   // 4 x wave-private 16-row slabs
  int t = threadIdx.x;
  int lane = t & 63, wave = t >> 6;
  int quad = lane >> 4, col = lane & 15;
  int hb = wave * 16;                     // this wave's private H row base
  int row0 = blockIdx.x * 64 + hb;        // global row of wave-local row 0

  // ---- stage H[hb..hb+16) = dyt1(z rows) (wave-private) ----
  {
    int row = lane >> 2, part = lane & 3;
    int gr = row0 + row; if (gr >= M) gr = M - 1;
    const unsigned short* zp = z_bf + (size_t)gr * 192 + part * 48;
    float s1 = 2.0f * d1a[0];
    #pragma unroll
    for (int j = 0; j < 6; ++j) {
      bf8_t v = *(const bf8_t*)(zp + j * 8);
      int k0 = part * 48 + j * 8;
      #pragma unroll
      for (int jj = 0; jj < 8; ++jj) {
        float f = bf2f((unsigned short)v[jj]);
        v[jj] = (short)f2bf(dyt_f(f, s1, d1w[k0 + jj], d1b[k0 + jj]));
      }
      *(bf8_t*)&H[hb + row][k0] = v;
    }
  }
  __builtin_amdgcn_fence(__ATOMIC_ACQ_REL, "wavefront");

  // ---- lin1 (K=192), lin2 (K=256) ----
  wgemm<192, 256, false>(H, hb, wt1, b1, quad, col, nullptr, nullptr, nullptr);
  wgemm<256, 256, false>(H, hb, wt2, b2, quad, col, nullptr, nullptr, nullptr);

  // ---- lin3 (K=256, N=64) + dyt2 + resid + rownorm + adyt1, all in regs ----
  {
    f4_t a3[4];
    #pragma unroll
    for (int nt = 0; nt < 4; ++nt) a3[nt] = (f4_t)0.f;
    const unsigned short* hp = &H[hb + col][quad * 8];
    const unsigned short* wp = wt3 + col * 32 + quad * 8;
    #pragma unroll
    for (int s = 0; s < 8; ++s) {
      bf8_t am = *(const bf8_t*)(hp + s * 32);
      #pragma unroll
      for (int nt = 0; nt < 4; ++nt) {
        bf8_t b = *(const bf8_t*)(wp + (s * 64 + nt * 16) * 32);
        a3[nt] = __builtin_amdgcn_mfma_f32_16x16x32_bf16(am, b, a3[nt], 0, 0, 0);
      }
    }
    __builtin_amdgcn_fence(__ATOMIC_ACQ_REL, "wavefront");
    float s2d = 2.0f * d2a[0];
    float val[4][4], xv[4][4];
    #pragma unroll
    for (int nt = 0; nt < 4; ++nt) {
      int n = nt * 16 + col;
      float bs = b3[n], wd = d2w[n], bd = d2b[n];
      #pragma unroll
      for (int r4 = 0; r4 < 4; ++r4) {
        int gr = row0 + quad * 4 + r4; if (gr >= M) gr = M - 1;
        float g = gelu_f(a3[nt][r4] + bs);
        float x = x_res[(size_t)gr * 64 + n];
        xv[nt][r4] = x;
        val[nt][r4] = dyt_f(g, s2d, wd, bd) + x;
      }
    }
    // row L2-norm: rows of a quad live entirely in that quad's 16 lanes
    float inv[4];
    #pragma unroll
    for (int r4 = 0; r4 < 4; ++r4) {
      float s2 = 0.f;
      #pragma unroll
      for (int nt = 0; nt < 4; ++nt) s2 += val[nt][r4] * val[nt][r4];
      s2 += __shfl_xor(s2, 1, 64);
      s2 += __shfl_xor(s2, 2, 64);
      s2 += __shfl_xor(s2, 4, 64);
      s2 += __shfl_xor(s2, 8, 64);
      inv[r4] = 1.0f / (sqrtf(s2) + 1e-10f);
    }
    float sa1 = 2.0f * a1a[0];
    #pragma unroll
    for (int nt = 0; nt < 4; ++nt) {
      int n = nt * 16 + col;
      float wzx = a1w[n], bzx = a1b[n], wzz = a1w[64 + n], bzz = a1b[64 + n];
      #pragma unroll
      for (int r4 = 0; r4 < 4; ++r4) {
        int row = quad * 4 + r4, gr = row0 + row;
        float zv = val[nt][r4] * inv[r4];
        if (gr < M) zn_bf[(size_t)gr * 64 + n] = f2bf(zv);
        H[hb + row][64 + n] = f2bf(dyt_f(zv, sa1, wzz, bzz));
        H[hb + row][n]      = f2bf(dyt_f(xv[nt][r4], sa1, wzx, bzx));
      }
    }
    __builtin_amdgcn_fence(__ATOMIC_ACQ_REL, "wavefront");
  }

  // ---- aa1 (K=128), aa2 (K=256), aa3 (K=256, adyt2 epilogue) ----
  wgemm<128, 256, false>(H, hb, wa1, ba1, quad, col, nullptr, nullptr, nullptr);
  wgemm<256, 256, false>(H, hb, wa2, ba2, quad, col, nullptr, nullptr, nullptr);
  wgemm<256, 256, true >(H, hb, wa3, ba3, quad, col, a2w, a2b, a2a);

  // ---- aa4 (K=256, N=20 padded 32) + log_softmax ----
  {
    f4_t a4[2];
    a4[0] = (f4_t)0.f; a4[1] = (f4_t)0.f;
    const unsigned short* hp = &H[hb + col][quad * 8];
    const unsigned short* wp = wa4 + col * 32 + quad * 8;
    #pragma unroll
    for (int s = 0; s < 8; ++s) {
      bf8_t am = *(const bf8_t*)(hp + s * 32);
      #pragma unroll
      for (int nt = 0; nt < 2; ++nt) {
        bf8_t b = *(const bf8_t*)(wp + (s * 32 + nt * 16) * 32);
        a4[nt] = __builtin_amdgcn_mfma_f32_16x16x32_bf16(am, b, a4[nt], 0, 0, 0);
      }
    }
    float val[2][4];
    #pragma unroll
    for (int nt = 0; nt < 2; ++nt) {
      int n = nt * 16 + col;
      float bsv = (n < 20) ? ba4[n] : 0.f;
      #pragma unroll
      for (int r4 = 0; r4 < 4; ++r4) val[nt][r4] = a4[nt][r4] + bsv;
    }
    bool v1 = (col < 4);
    #pragma unroll
    for (int r4 = 0; r4 < 4; ++r4) {
      float m = val[0][r4];
      if (v1) m = fmaxf(m, val[1][r4]);
      m = fmaxf(m, __shfl_xor(m, 1, 64));
      m = fmaxf(m, __shfl_xor(m, 2, 64));
      m = fmaxf(m, __shfl_xor(m, 4, 64));
      m = fmaxf(m, __shfl_xor(m, 8, 64));
      float se = __expf(val[0][r4] - m) + (v1 ? __expf(val[1][r4] - m) : 0.f);
      se += __shfl_xor(se, 1, 64);
      se += __shfl_xor(se, 2, 64);
      se += __shfl_xor(se, 4, 64);
      se += __shfl_xor(se, 8, 64);
      float ls = __logf(se) + m;
      int row = row0 + quad * 4 + r4;
      if (row < M) {
        out[(size_t)row * 20 + col] = val[0][r4] - ls;
        if (v1) out[(size_t)row * 20 + 16 + col] = val[1][r4] - ls;
      }
    }
  }
}

// ---------------- fused edge head (prefetching, barrier-free) ----------------
__global__ __launch_bounds__(256) void k_edge(
    const unsigned short* __restrict__ zn_bf,
    const int* __restrict__ ci, const int* __restrict__ cj,
    const unsigned short* __restrict__ w1t, const float* __restrict__ b1,
    const unsigned short* __restrict__ w2t, const float* __restrict__ b2,
    const float* __restrict__ w3, const float* __restrict__ b3,
    float* __restrict__ out, int M) {
  __shared__ unsigned short h1s[4][16][136];
  int lane = threadIdx.x & 63, wave = threadIdx.x >> 6;
  int quad = lane >> 4, col = lane & 15;
  unsigned short (*h1)[136] = h1s[wave];
  int ntiles = (M + 63) >> 6;
  float b3v = b3[0];

  int tile = blockIdx.x;
  bf8_t afrag[4];
  if (tile < ntiles) {
    int r = tile * 64 + wave * 16 + col; if (r >= M) r = M - 1;
    const unsigned short* p0 = zn_bf + (size_t)ci[r] * 64;
    const unsigned short* p1 = zn_bf + (size_t)cj[r] * 64;
    afrag[0] = *(const bf8_t*)(p0 + quad * 8);
    afrag[1] = *(const bf8_t*)(p0 + 32 + quad * 8);
    afrag[2] = *(const bf8_t*)(p1 + quad * 8);
    afrag[3] = *(const bf8_t*)(p1 + 32 + quad * 8);
  }

  for (; tile < ntiles; tile += gridDim.x) {
    f4_t acc[8];
    #pragma unroll
    for (int nt = 0; nt < 8; ++nt) acc[nt] = (f4_t)0.f;
    #pragma unroll
    for (int s = 0; s < 4; ++s) {
      int kf = s * 32 + quad * 8;
      #pragma unroll
      for (int nt = 0; nt < 8; ++nt) {
        bf8_t b = *(const bf8_t*)(w1t + (size_t)(nt * 16 + col) * 128 + kf);
        acc[nt] = __builtin_amdgcn_mfma_f32_16x16x32_bf16(afrag[s], b, acc[nt], 0, 0, 0);
      }
    }

    int nxt = tile + gridDim.x;
    bf8_t nfrag[4];
    bool has_next = (nxt < ntiles);
    if (has_next) {
      int r = nxt * 64 + wave * 16 + col; if (r >= M) r = M - 1;
      const unsigned short* p0 = zn_bf + (size_t)ci[r] * 64;
      const unsigned short* p1 = zn_bf + (size_t)cj[r] * 64;
      nfrag[0] = *(const bf8_t*)(p0 + quad * 8);
      nfrag[1] = *(const bf8_t*)(p0 + 32 + quad * 8);
      nfrag[2] = *(const bf8_t*)(p1 + quad * 8);
      nfrag[3] = *(const bf8_t*)(p1 + 32 + quad * 8);
    }

    #pragma unroll
    for (int nt = 0; nt < 8; ++nt) {
      float bs = b1[nt * 16 + col];
      #pragma unroll
      for (int r4 = 0; r4 < 4; ++r4)
        h1[quad * 4 + r4][nt * 16 + col] = f2bf(gelu_f(acc[nt][r4] + bs));
    }

    f4_t a2[8];
    #pragma unroll
    for (int nt = 0; nt < 8; ++nt) a2[nt] = (f4_t)0.f;
    #pragma unroll
    for (int s = 0; s < 4; ++s) {
      int kc = s * 32 + quad * 8;
      bf8_t a0 = *(const bf8_t*)&h1[col][kc];
      #pragma unroll
      for (int nt = 0; nt < 8; ++nt) {
        bf8_t b = *(const bf8_t*)(w2t + (size_t)(nt * 16 + col) * 128 + kc);
        a2[nt] = __builtin_amdgcn_mfma_f32_16x16x32_bf16(a0, b, a2[nt], 0, 0, 0);
      }
    }
    float p[4] = {0.f, 0.f, 0.f, 0.f};
    #pragma unroll
    for (int nt = 0; nt < 8; ++nt) {
      float bs = b2[nt * 16 + col];
      float wv = w3[nt * 16 + col];
      #pragma unroll
      for (int r4 = 0; r4 < 4; ++r4)
        p[r4] += gelu_f(a2[nt][r4] + bs) * wv;
    }
    #pragma unroll
    for (int r4 = 0; r4 < 4; ++r4) {
      float s = p[r4];
      s += __shfl_xor(s, 1, 64);
      s += __shfl_xor(s, 2, 64);
      s += __shfl_xor(s, 4, 64);
      s += __shfl_xor(s, 8, 64);
      if (col == 0) {
        int row = tile * 64 + wave * 16 + quad * 4 + r4;
        if (row < M) out[row] = __builtin_amdgcn_rcpf(1.0f + __expf(-(s + b3v)));
      }
    }

    if (has_next) {
      afrag[0] = nfrag[0]; afrag[1] = nfrag[1];
      afrag[2] = nfrag[2]; afrag[3] = nfrag[3];
    }
  }
}

// ---------------- launcher ----------------
extern "C" void kernel_launch(void* const* d_in, const int* in_sizes, int n_in,
                              void* d_out, int out_size, void* d_ws, size_t ws_size,
                              hipStream_t stream) {
  const float* x_res  = (const float*)d_in[0];
  const float* Wl     = (const float*)d_in[1];
  const float* bl     = (const float*)d_in[2];
  const float* Wr     = (const float*)d_in[3];
  const float* gn_w   = (const float*)d_in[4];
  const float* gn_b   = (const float*)d_in[5];
  const float* gn_ms  = (const float*)d_in[6];
  const float* dyt1_w = (const float*)d_in[7];
  const float* dyt1_b = (const float*)d_in[8];
  const float* dyt1_a = (const float*)d_in[9];
  const float* lin1_w = (const float*)d_in[10];
  const float* lin1_b = (const float*)d_in[11];
  const float* lin2_w = (const float*)d_in[12];
  const float* lin2_b = (const float*)d_in[13];
  const float* lin3_w = (const float*)d_in[14];
  const float* lin3_b = (const float*)d_in[15];
  const float* dyt2_w = (const float*)d_in[16];
  const float* dyt2_b = (const float*)d_in[17];
  const float* dyt2_a = (const float*)d_in[18];
  const float* adyt1_w = (const float*)d_in[19];
  const float* adyt1_b = (const float*)d_in[20];
  const float* adyt1_a = (const float*)d_in[21];
  const float* aa1_w  = (const float*)d_in[22];
  const float* aa1_b  = (const float*)d_in[23];
  const float* aa2_w  = (const float*)d_in[24];
  const float* aa2_b  = (const float*)d_in[25];
  const float* aa3_w  = (const float*)d_in[26];
  const float* aa3_b  = (const float*)d_in[27];
  const float* adyt2_w = (const float*)d_in[28];
  const float* adyt2_b = (const float*)d_in[29];
  const float* adyt2_a = (const float*)d_in[30];
  const float* aa4_w  = (const float*)d_in[31];
  const float* aa4_b  = (const float*)d_in[32];
  const float* c1_w   = (const float*)d_in[33];
  const float* c1_b   = (const float*)d_in[34];
  const float* c2_w   = (const float*)d_in[35];
  const float* c2_b   = (const float*)d_in[36];
  const float* c3_w   = (const float*)d_in[37];
  const float* c3_b   = (const float*)d_in[38];
  const int*   edge   = (const int*)d_in[39];
  const int*   contact = (const int*)d_in[40];

  const size_t N = (size_t)Nn;
  const size_t ws_floats = ws_size / 4;

  float* ws    = (float*)d_ws;
  float* rdeg  = ws;
  float* hbuf  = rdeg + N;
  unsigned short* z_bf  = (unsigned short*)(hbuf + 64 * N);
  unsigned short* zn_bf = z_bf + 192 * N;
  float* stats = (float*)(zn_bf + 64 * N);
  unsigned short* wt_sage = (unsigned short*)(stats + 256);
  unsigned short* wt_lin1 = wt_sage + 3 * 64 * 128;
  unsigned short* wt_lin2 = wt_lin1 + 256 * 192;
  unsigned short* wt_lin3 = wt_lin2 + 256 * 256;
  unsigned short* wt_aa1  = wt_lin3 + 64 * 256;
  unsigned short* wt_aa2  = wt_aa1 + 256 * 128;
  unsigned short* wt_aa3  = wt_aa2 + 256 * 256;
  unsigned short* wt_aa4  = wt_aa3 + 256 * 256;
  unsigned short* wt_c1   = wt_aa4 + 32 * 256;
  unsigned short* wt_c2   = wt_c1 + 128 * 128;
  unsigned short* wt_end  = wt_c2 + 128 * 128;
  float* pool  = (float*)((((uintptr_t)wt_end + 15) & ~(uintptr_t)15));
  const size_t persist = (size_t)(pool - ws);

  const size_t gnn_need = 32 * N + N + (N + 1) + N + (size_t)Ee + 256;
  if (ws_floats < persist + gnn_need) return;

  unsigned short* agg_bf = (unsigned short*)pool;
  int* cnt     = (int*)(pool + 32 * N);
  int* rowptr  = cnt + N;
  int* cursor  = rowptr + N + 1;
  int* colidx  = cursor + N;
  int* bsum    = colidx + Ee;

  const int* esrc = edge;
  const int* edst = edge + Ee;

  // ---- CSR build ----
  hipMemsetAsync(cnt, 0, N * sizeof(int), stream);
  k_degi<<<(Ee + 255) / 256, 256, 0, stream>>>(edst, cnt, Ee);
  k_rdeg<<<(Nn + 255) / 256, 256, 0, stream>>>(cnt, rdeg, Nn);
  const int nb = (Nn + 1023) / 1024;
  k_scan1<<<nb, 256, 0, stream>>>(cnt, cursor, bsum, Nn);
  k_scan2<<<1, 256, 0, stream>>>(bsum, nb);
  k_scan3<<<(Nn + 255) / 256, 256, 0, stream>>>(cursor, bsum, rowptr, cursor, Nn, Ee);
  k_fill<<<(Ee + 255) / 256, 256, 0, stream>>>(esrc, edst, cursor, colidx, Ee);

  // ---- weight prep ----
  k_wtsage<<<(3 * 64 * 128 + 255) / 256, 256, 0, stream>>>(Wl, Wr, wt_sage);
  // node-pipeline weights in blocked [(k>>5)*N + n][k&31] layout
  k_wt3<<<(192 * 256 + 255) / 256, 256, 0, stream>>>(lin1_w, wt_lin1, 256, 256, 192 * 256);
  k_wt3<<<(256 * 256 + 255) / 256, 256, 0, stream>>>(lin2_w, wt_lin2, 256, 256, 256 * 256);
  k_wt3<<<(256 * 64 + 255) / 256, 256, 0, stream>>>(lin3_w, wt_lin3, 64, 64, 256 * 64);
  k_wt3<<<(128 * 256 + 255) / 256, 256, 0, stream>>>(aa1_w, wt_aa1, 256, 256, 128 * 256);
  k_wt3<<<(256 * 256 + 255) / 256, 256, 0, stream>>>(aa2_w, wt_aa2, 256, 256, 256 * 256);
  k_wt3<<<(256 * 256 + 255) / 256, 256, 0, stream>>>(aa3_w, wt_aa3, 256, 256, 256 * 256);
  k_wt3<<<(256 * 32 + 255) / 256, 256, 0, stream>>>(aa4_w, wt_aa4, 32, 20, 256 * 32);
  // edge-head weights keep the [n][k] layout
  k_wt2<<<(128 * 128 + 255) / 256, 256, 0, stream>>>(c1_w, wt_c1, 128, 128, 128 * 128);
  k_wt2<<<(128 * 128 + 255) / 256, 256, 0, stream>>>(c2_w, wt_c2, 128, 128, 128 * 128);

  // xb = bf16(x_res) in zn_bf slot
  k_cvt<<<(int)((N * 64 + 255) / 256), 256, 0, stream>>>(x_res, zn_bf, (int)(N * 64));

  // ---- GNN phase ----
  for (int l = 0; l < 3; ++l) {
    const unsigned short* xi = (l == 0) ? zn_bf : (z_bf + (size_t)(l - 1) * 64);
    int ldx = (l == 0) ? 64 : 192;
    hipMemsetAsync(stats, 0, 128 * sizeof(float), stream);
    k_gather<<<(Nn + 3) / 4, 256, 0, stream>>>(xi, ldx, rowptr, colidx, rdeg, agg_bf, Nn);
    mgemm<4><<<dim3((Nn + 127) / 128, 1), 256, 0, stream>>>(
        agg_bf, 64, xi, ldx, 64, 1,
        wt_sage + (size_t)l * 8192, bl + l * 64, hbuf, 64, 0, 1, Nn, 128, 64);
    k_stats<<<1024, 256, 0, stream>>>(hbuf, stats, Nn);
    k_statfin<<<1, 64, 0, stream>>>(stats, gn_ms + l * 64, Nn);
    k_norm<<<(Nn * 64) / 256, 256, 0, stream>>>(hbuf, stats, gn_w + l * 64, gn_b + l * 64,
                                                z_bf + (size_t)l * 64,
                                                (l > 0) ? (z_bf + (size_t)(l - 1) * 64) : nullptr, Nn);
  }

  // ---- wave-private fused node pipeline (zero barriers) ----
  k_node<<<(Nn + 63) / 64, 256, 0, stream>>>(
      z_bf, x_res,
      dyt1_w, dyt1_b, dyt1_a, wt_lin1, lin1_b, wt_lin2, lin2_b, wt_lin3, lin3_b,
      dyt2_w, dyt2_b, dyt2_a,
      adyt1_w, adyt1_b, adyt1_a, wt_aa1, aa1_b, wt_aa2, aa2_b, wt_aa3, aa3_b,
      adyt2_w, adyt2_b, adyt2_a, wt_aa4, aa4_b,
      zn_bf, (float*)d_out, Nn);

  // ---- fused edge head ----
  float* eout = (float*)d_out + (size_t)Nn * 20;
  k_edge<<<2048, 256, 0, stream>>>(zn_bf, contact, contact + EPp,
      wt_c1, c1_b, wt_c2, c2_b, c3_w, c3_b, eout, EPp);
}

// Round 2
// 1839.111 us; speedup vs baseline: 1.0507x; 1.0218x over previous
//
#include <hip/hip_runtime.h>
#include <cstdint>
#include <cstddef>

// ---------------- problem constants ----------------
constexpr int Nn  = 200000;
constexpr int Ee  = 1600000;
constexpr int EPp = 1000000;

typedef __attribute__((ext_vector_type(8))) short bf8_t;
typedef __attribute__((ext_vector_type(4))) float f4_t;

__device__ inline unsigned short f2bf(float f) {
  union { float f; unsigned u; } v; v.f = f;
  unsigned r = v.u + 0x7FFFu + ((v.u >> 16) & 1u);
  return (unsigned short)(r >> 16);
}
__device__ inline float bf2f(unsigned short u) {
  union { unsigned u; float f; } v; v.u = ((unsigned)u) << 16;
  return v.f;
}
// tanh-form GELU, algebraically reduced: 0.5v(1+tanh(u)) = v*(1-r), r=1/(e^{2u}+1)
__device__ inline float gelu_f(float v) {
  float u = v * fmaf(0.0356774081f, v * v, 0.7978845608f);
  float r = __builtin_amdgcn_rcpf(__expf(u + u) + 1.0f);
  return fmaf(-v, r, v);
}
// dyt: w*tanh(a x)+b with s2 = 2*a prefolded: tanh = 1-2r
__device__ inline float dyt_f(float x, float s2, float w, float b) {
  float r = __builtin_amdgcn_rcpf(__expf(s2 * x) + 1.0f);
  return fmaf(w, fmaf(-2.0f, r, 1.0f), b);
}

// ---------------- degree / CSR build ----------------

__global__ __launch_bounds__(256) void k_degi(const int* __restrict__ dst,
                                              int* __restrict__ cnt, int E) {
  int i = blockIdx.x * 256 + threadIdx.x;
  if (i < E) atomicAdd(&cnt[dst[i]], 1);
}

__global__ __launch_bounds__(256) void k_rdeg(const int* __restrict__ cnt,
                                              float* __restrict__ rdeg, int n) {
  int i = blockIdx.x * 256 + threadIdx.x;
  if (i < n) rdeg[i] = 1.0f / (float)(cnt[i] > 1 ? cnt[i] : 1);
}

__global__ __launch_bounds__(256) void k_scan1(const int* __restrict__ in,
                                               int* __restrict__ out,
                                               int* __restrict__ bsum, int n) {
  __shared__ int sd[256];
  int t = threadIdx.x;
  int base = blockIdx.x * 1024 + t * 4;
  int v[4]; int ts = 0;
  #pragma unroll
  for (int j = 0; j < 4; ++j) { v[j] = (base + j < n) ? in[base + j] : 0; ts += v[j]; }
  sd[t] = ts; __syncthreads();
  for (int off = 1; off < 256; off <<= 1) {
    int x = (t >= off) ? sd[t - off] : 0;
    __syncthreads();
    sd[t] += x;
    __syncthreads();
  }
  int excl = sd[t] - ts;
  #pragma unroll
  for (int j = 0; j < 4; ++j) { if (base + j < n) out[base + j] = excl; excl += v[j]; }
  if (t == 255) bsum[blockIdx.x] = sd[255];
}

__global__ void k_scan2(int* bsum, int nb) {
  __shared__ int sd[256];
  int t = threadIdx.x;
  int v = (t < nb) ? bsum[t] : 0;
  sd[t] = v; __syncthreads();
  for (int off = 1; off < 256; off <<= 1) {
    int x = (t >= off) ? sd[t - off] : 0;
    __syncthreads();
    sd[t] += x;
    __syncthreads();
  }
  if (t < nb) bsum[t] = sd[t] - v;
}

__global__ __launch_bounds__(256) void k_scan3(const int* __restrict__ part,
                                               const int* __restrict__ bsum,
                                               int* __restrict__ rowptr,
                                               int* __restrict__ cursor,
                                               int n, int total) {
  int i = blockIdx.x * 256 + threadIdx.x;
  if (i == 0) rowptr[n] = total;
  if (i < n) { int v = part[i] + bsum[i >> 10]; rowptr[i] = v; cursor[i] = v; }
}

__global__ __launch_bounds__(256) void k_fill(const int* __restrict__ src,
                                              const int* __restrict__ dst,
                                              int* __restrict__ cursor,
                                              int* __restrict__ colidx, int E) {
  int e = blockIdx.x * 256 + threadIdx.x;
  if (e >= E) return;
  int pos = atomicAdd(&cursor[dst[e]], 1);
  colidx[pos] = src[e];
}

// gather-mean over bf16 features: one wave per node, 8 groups of 8 lanes
__global__ __launch_bounds__(256) void k_gather(const unsigned short* __restrict__ x, int ldx,
                                                const int* __restrict__ rowptr,
                                                const int* __restrict__ colidx,
                                                const float* __restrict__ rdeg,
                                                unsigned short* __restrict__ agg, int n) {
  int wave = threadIdx.x >> 6, lane = threadIdx.x & 63;
  int node = blockIdx.x * 4 + wave;
  if (node >= n) return;
  int grp = lane >> 3, c = (lane & 7) * 8;
  int r0 = rowptr[node], r1 = rowptr[node + 1];
  float s[8] = {0.f, 0.f, 0.f, 0.f, 0.f, 0.f, 0.f, 0.f};
  for (int j = r0 + grp; j < r1; j += 8) {
    bf8_t v = *(const bf8_t*)(x + (size_t)colidx[j] * ldx + c);
    #pragma unroll
    for (int jj = 0; jj < 8; ++jj) s[jj] += bf2f((unsigned short)v[jj]);
  }
  #pragma unroll
  for (int jj = 0; jj < 8; ++jj) {
    s[jj] += __shfl_xor(s[jj], 8, 64);
    s[jj] += __shfl_xor(s[jj], 16, 64);
    s[jj] += __shfl_xor(s[jj], 32, 64);
  }
  if (grp == 0) {
    float r = rdeg[node];
    bf8_t o;
    #pragma unroll
    for (int jj = 0; jj < 8; ++jj) o[jj] = (short)f2bf(s[jj] * r);
    *(bf8_t*)(agg + (size_t)node * 64 + c) = o;
  }
}

// ---------------- misc small kernels ----------------

__global__ __launch_bounds__(256) void k_cvt(const float* __restrict__ in,
                                             unsigned short* __restrict__ out, int n) {
  int i = blockIdx.x * 256 + threadIdx.x;
  if (i < n) out[i] = f2bf(in[i]);
}

__global__ __launch_bounds__(256) void k_wt2(const float* __restrict__ W,
                                             unsigned short* __restrict__ Wt,
                                             int K, int N, int total) {
  int i = blockIdx.x * 256 + threadIdx.x;
  if (i >= total) return;
  int n = i / K, k = i - n * K;
  float v = (n < N) ? W[(size_t)k * N + n] : 0.f;
  Wt[i] = f2bf(v);
}

// blocked layout for the wave-private node pipeline:
// Wt[((k>>5)*Np + n)*32 + (k&31)] = W[k][n]   (zero-padded for n >= Nr)
__global__ __launch_bounds__(256) void k_wt3(const float* __restrict__ W,
                                             unsigned short* __restrict__ Wt,
                                             int Np, int Nr, int total) {
  int i = blockIdx.x * 256 + threadIdx.x;
  if (i >= total) return;
  int kin = i & 31;
  int j = i >> 5;
  int n = j % Np, kb = j / Np;
  int k = kb * 32 + kin;
  float v = (n < Nr) ? W[(size_t)k * Nr + n] : 0.f;
  Wt[i] = f2bf(v);
}

__global__ __launch_bounds__(256) void k_wtsage(const float* __restrict__ Wl,
                                                const float* __restrict__ Wr,
                                                unsigned short* __restrict__ Wt) {
  int i = blockIdx.x * 256 + threadIdx.x;
  if (i >= 3 * 64 * 128) return;
  int l = i >> 13, r = i & 8191, n = r >> 7, k = r & 127;
  float v = (k < 64) ? Wl[l * 4096 + k * 64 + n] : Wr[l * 4096 + (k - 64) * 64 + n];
  Wt[i] = f2bf(v);
}

__global__ __launch_bounds__(256) void k_stats(const float* __restrict__ h,
                                               float* __restrict__ stats, int n) {
  int lane = threadIdx.x & 63, grp = threadIdx.x >> 6;
  float s = 0.f, s2 = 0.f;
  for (int r = blockIdx.x * 4 + grp; r < n; r += gridDim.x * 4) {
    float v = h[(size_t)r * 64 + lane];
    s += v; s2 += v * v;
  }
  __shared__ float l1[4][64], l2[4][64];
  l1[grp][lane] = s; l2[grp][lane] = s2;
  __syncthreads();
  if (grp == 0) {
    s  = l1[0][lane] + l1[1][lane] + l1[2][lane] + l1[3][lane];
    s2 = l2[0][lane] + l2[1][lane] + l2[2][lane] + l2[3][lane];
    atomicAdd(&stats[lane], s);
    atomicAdd(&stats[64 + lane], s2);
  }
}

__global__ void k_statfin(float* stats, const float* __restrict__ ms_, int n) {
  int d = threadIdx.x;
  if (d < 64) {
    float invn = 1.0f / (float)n;
    float m  = stats[d] * invn;
    float e2 = stats[64 + d] * invn;
    float ms = ms_[d];
    float var = e2 - (2.0f * ms - ms * ms) * m * m;
    stats[128 + d] = ms * m;
    stats[192 + d] = rsqrtf(var + 1e-5f);
  }
}

__global__ __launch_bounds__(256) void k_norm(const float* __restrict__ h,
                                              const float* __restrict__ stats,
                                              const float* __restrict__ w,
                                              const float* __restrict__ b,
                                              unsigned short* __restrict__ zcol,
                                              const unsigned short* __restrict__ prev, int n) {
  int i = blockIdx.x * 256 + threadIdx.x;
  if (i >= n * 64) return;
  int r = i >> 6, d = i & 63;
  float v = (h[i] - stats[128 + d]) * stats[192 + d] * w[d] + b[d];
  if (prev) v += bf2f(prev[(size_t)r * 192 + d]);
  zcol[(size_t)r * 192 + d] = f2bf(v);
}

// ---------------- generic bf16 MFMA GEMM (barrier-free, for SAGE) ----------------
template <int NT>
__global__ __launch_bounds__(256) void mgemm(
    const void* __restrict__ A1, int lda1,
    const void* __restrict__ A2, int lda2, int K1, int a_bf16,
    const unsigned short* __restrict__ Wt,
    const float* __restrict__ bias,
    void* __restrict__ Cout, int ldc, int c_bf16, int act,
    int M, int K, int N) {
  int lane = threadIdx.x & 63, wave = threadIdx.x >> 6;
  int quad = lane >> 4, col = lane & 15;
  int row0 = blockIdx.x * 128 + wave * 32;
  int n_base = blockIdx.y * NT * 16;

  f4_t acc[2][NT];
  #pragma unroll
  for (int mt = 0; mt < 2; ++mt)
    #pragma unroll
    for (int nt = 0; nt < NT; ++nt) acc[mt][nt] = (f4_t)0.f;

  int gm[2];
  gm[0] = row0 + col;      if (gm[0] >= M) gm[0] = M - 1;
  gm[1] = row0 + 16 + col; if (gm[1] >= M) gm[1] = M - 1;

  for (int kc0 = 0; kc0 < K; kc0 += 32) {
    int kc = kc0 + quad * 8;
    bf8_t a[2];
    #pragma unroll
    for (int mt = 0; mt < 2; ++mt) {
      const void* src; size_t off;
      if (kc < K1) { src = A1; off = (size_t)gm[mt] * lda1 + kc; }
      else         { src = A2; off = (size_t)gm[mt] * lda2 + kc - K1; }
      if (a_bf16) {
        a[mt] = *(const bf8_t*)((const unsigned short*)src + off);
      } else {
        const float* p = (const float*)src + off;
        float4 f0 = *(const float4*)p;
        float4 f1 = *(const float4*)(p + 4);
        float ff[8] = {f0.x, f0.y, f0.z, f0.w, f1.x, f1.y, f1.z, f1.w};
        #pragma unroll
        for (int j = 0; j < 8; ++j) a[mt][j] = (short)f2bf(ff[j]);
      }
    }
    #pragma unroll
    for (int nt = 0; nt < NT; ++nt) {
      bf8_t b = *(const bf8_t*)(Wt + (size_t)(n_base + nt * 16 + col) * K + kc);
      acc[0][nt] = __builtin_amdgcn_mfma_f32_16x16x32_bf16(a[0], b, acc[0][nt], 0, 0, 0);
      acc[1][nt] = __builtin_amdgcn_mfma_f32_16x16x32_bf16(a[1], b, acc[1][nt], 0, 0, 0);
    }
  }

  #pragma unroll
  for (int nt = 0; nt < NT; ++nt) {
    int n = n_base + nt * 16 + col;
    float bs = (bias && n < N) ? bias[n] : 0.f;
    #pragma unroll
    for (int mt = 0; mt < 2; ++mt)
      #pragma unroll
      for (int r = 0; r < 4; ++r) {
        int row = row0 + mt * 16 + quad * 4 + r;
        if (row >= M || n >= N) continue;
        float v = acc[mt][nt][r] + bs;
        if (act) v = gelu_f(v);
        if (c_bf16) ((unsigned short*)Cout)[(size_t)row * ldc + n] = f2bf(v);
        else        ((float*)Cout)[(size_t)row * ldc + n] = v;
      }
  }
}

// ---------------- wave-private fused node pipeline (ZERO barriers) ----------
// Block = 128 thr = 2 independent waves (small blocks -> more blocks/CU).
// Wave w owns 16 rows and its private LDS slab. Each wave computes ALL output
// columns of every layer for its own rows -> no cross-wave sharing, no
// __syncthreads anywhere.
// KEY (round 2): register-rotated b-prefetch. The k-loop keeps all NTI
// b-fragments of the NEXT k-step in flight (64 VGPRs) by reloading bcur[nt]
// immediately after the MFMA that consumes it. This raises outstanding
// vmem loads per wave from ~3 to ~16, hiding the ~200cy L2 latency that
// bound round 1 (VGPR=84 left no room for load pipelining).
template <int K, int NN, bool DYT>
__device__ inline void wgemm(unsigned short (*H)[264], int hb,
                             const unsigned short* __restrict__ W,
                             const float* __restrict__ bias,
                             int quad, int col,
                             const float* __restrict__ aw,
                             const float* __restrict__ ab,
                             const float* __restrict__ aal) {
  constexpr int KS = K >> 5, NTI = NN >> 4;
  f4_t acc[NTI];
#pragma unroll
  for (int nt = 0; nt < NTI; ++nt) acc[nt] = (f4_t)0.f;
  const unsigned short* hp = &H[hb + col][quad * 8];
  const unsigned short* wp = W + col * 32 + quad * 8;
  bf8_t bcur[NTI];
#pragma unroll
  for (int nt = 0; nt < NTI; ++nt)
    bcur[nt] = *(const bf8_t*)(wp + (size_t)(nt * 16) * 32);
#pragma unroll
  for (int s = 0; s < KS; ++s) {
    bf8_t am = *(const bf8_t*)(hp + s * 32);   // 1 LDS read feeds NTI MFMAs
#pragma unroll
    for (int nt = 0; nt < NTI; ++nt) {
      bf8_t b = bcur[nt];
      if (s + 1 < KS)                           // rotate: reload slot for s+1
        bcur[nt] = *(const bf8_t*)(wp + (size_t)((s + 1) * NN + nt * 16) * 32);
      acc[nt] = __builtin_amdgcn_mfma_f32_16x16x32_bf16(am, b, acc[nt], 0, 0, 0);
    }
  }
  float sa = DYT ? (2.0f * aal[0]) : 0.f;
  // wavefront-scope fence: zero-cost; orders this wave's LDS reads (k-loop)
  // before the epilogue's LDS writes (WAR) at compiler level.
  __builtin_amdgcn_fence(__ATOMIC_ACQ_REL, "wavefront");
#pragma unroll
  for (int nt = 0; nt < NTI; ++nt) {
    int n = nt * 16 + col;
    float bs = bias[n];
    float w_ = DYT ? aw[n] : 0.f;
    float b_ = DYT ? ab[n] : 0.f;
#pragma unroll
    for (int r4 = 0; r4 < 4; ++r4) {
      float v = gelu_f(acc[nt][r4] + bs);
      if (DYT) v = dyt_f(v, sa, w_, b_);
      H[hb + quad * 4 + r4][n] = f2bf(v);
    }
  }
  // order epilogue writes before the next phase's LDS reads (RAW).
  __builtin_amdgcn_fence(__ATOMIC_ACQ_REL, "wavefront");
}

__global__ __launch_bounds__(128, 3) void k_node(
    const unsigned short* __restrict__ z_bf,
    const float* __restrict__ x_res,
    const float* __restrict__ d1w, const float* __restrict__ d1b, const float* __restrict__ d1a,
    const unsigned short* __restrict__ wt1, const float* __restrict__ b1,
    const unsigned short* __restrict__ wt2, const float* __restrict__ b2,
    const unsigned short* __restrict__ wt3, const float* __restrict__ b3,
    const float* __restrict__ d2w, const float* __restrict__ d2b, const float* __restrict__ d2a,
    const float* __restrict__ a1w, const float* __restrict__ a1b, const float* __restrict__ a1a,
    const unsigned short* __restrict__ wa1, const float* __restrict__ ba1,
    const unsigned short* __restrict__ wa2, const float* __restrict__ ba2,
    const unsigned short* __restrict__ wa3, const float* __restrict__ ba3,
    const float* __restrict__ a2w, const float* __restrict__ a2b, const float* __restrict__ a2a,
    const unsigned short* __restrict__ wa4, const float* __restrict__ ba4,
    unsigned short* __restrict__ zn_bf,
    float* __restrict__ out, int M) {
  __shared__ unsigned short H[32][264];   // 2 x wave-private 16-row slabs
  int t = threadIdx.x;
  int lane = t & 63, wave = t >> 6;
  int quad = lane >> 4, col = lane & 15;
  int hb = wave * 16;                     // this wave's private H row base
  int row0 = blockIdx.x * 32 + hb;        // global row of wave-local row 0

  // ---- stage H[hb..hb+16) = dyt1(z rows) (wave-private) ----
  {
    int row = lane >> 2, part = lane & 3;
    int gr = row0 + row; if (gr >= M) gr = M - 1;
    const unsigned short* zp = z_bf + (size_t)gr * 192 + part * 48;
    float s1 = 2.0f * d1a[0];
    #pragma unroll
    for (int j = 0; j < 6; ++j) {
      bf8_t v = *(const bf8_t*)(zp + j * 8);
      int k0 = part * 48 + j * 8;
      #pragma unroll
      for (int jj = 0; jj < 8; ++jj) {
        float f = bf2f((unsigned short)v[jj]);
        v[jj] = (short)f2bf(dyt_f(f, s1, d1w[k0 + jj], d1b[k0 + jj]));
      }
      *(bf8_t*)&H[hb + row][k0] = v;
    }
  }
  __builtin_amdgcn_fence(__ATOMIC_ACQ_REL, "wavefront");

  // ---- lin1 (K=192), lin2 (K=256) ----
  wgemm<192, 256, false>(H, hb, wt1, b1, quad, col, nullptr, nullptr, nullptr);
  wgemm<256, 256, false>(H, hb, wt2, b2, quad, col, nullptr, nullptr, nullptr);

  // ---- lin3 (K=256, N=64) + dyt2 + resid + rownorm + adyt1, all in regs ----
  {
    f4_t a3[4];
    #pragma unroll
    for (int nt = 0; nt < 4; ++nt) a3[nt] = (f4_t)0.f;
    const unsigned short* hp = &H[hb + col][quad * 8];
    const unsigned short* wp = wt3 + col * 32 + quad * 8;
    bf8_t bc[4];
    #pragma unroll
    for (int nt = 0; nt < 4; ++nt)
      bc[nt] = *(const bf8_t*)(wp + (size_t)(nt * 16) * 32);
    #pragma unroll
    for (int s = 0; s < 8; ++s) {
      bf8_t am = *(const bf8_t*)(hp + s * 32);
      #pragma unroll
      for (int nt = 0; nt < 4; ++nt) {
        bf8_t b = bc[nt];
        if (s + 1 < 8)
          bc[nt] = *(const bf8_t*)(wp + (size_t)((s + 1) * 64 + nt * 16) * 32);
        a3[nt] = __builtin_amdgcn_mfma_f32_16x16x32_bf16(am, b, a3[nt], 0, 0, 0);
      }
    }
    __builtin_amdgcn_fence(__ATOMIC_ACQ_REL, "wavefront");
    float s2d = 2.0f * d2a[0];
    float val[4][4], xv[4][4];
    #pragma unroll
    for (int nt = 0; nt < 4; ++nt) {
      int n = nt * 16 + col;
      float bs = b3[n], wd = d2w[n], bd = d2b[n];
      #pragma unroll
      for (int r4 = 0; r4 < 4; ++r4) {
        int gr = row0 + quad * 4 + r4; if (gr >= M) gr = M - 1;
        float g = gelu_f(a3[nt][r4] + bs);
        float x = x_res[(size_t)gr * 64 + n];
        xv[nt][r4] = x;
        val[nt][r4] = dyt_f(g, s2d, wd, bd) + x;
      }
    }
    // row L2-norm: rows of a quad live entirely in that quad's 16 lanes
    float inv[4];
    #pragma unroll
    for (int r4 = 0; r4 < 4; ++r4) {
      float s2 = 0.f;
      #pragma unroll
      for (int nt = 0; nt < 4; ++nt) s2 += val[nt][r4] * val[nt][r4];
      s2 += __shfl_xor(s2, 1, 64);
      s2 += __shfl_xor(s2, 2, 64);
      s2 += __shfl_xor(s2, 4, 64);
      s2 += __shfl_xor(s2, 8, 64);
      inv[r4] = 1.0f / (sqrtf(s2) + 1e-10f);
    }
    float sa1 = 2.0f * a1a[0];
    #pragma unroll
    for (int nt = 0; nt < 4; ++nt) {
      int n = nt * 16 + col;
      float wzx = a1w[n], bzx = a1b[n], wzz = a1w[64 + n], bzz = a1b[64 + n];
      #pragma unroll
      for (int r4 = 0; r4 < 4; ++r4) {
        int row = quad * 4 + r4, gr = row0 + row;
        float zv = val[nt][r4] * inv[r4];
        if (gr < M) zn_bf[(size_t)gr * 64 + n] = f2bf(zv);
        H[hb + row][64 + n] = f2bf(dyt_f(zv, sa1, wzz, bzz));
        H[hb + row][n]      = f2bf(dyt_f(xv[nt][r4], sa1, wzx, bzx));
      }
    }
    __builtin_amdgcn_fence(__ATOMIC_ACQ_REL, "wavefront");
  }

  // ---- aa1 (K=128), aa2 (K=256), aa3 (K=256, adyt2 epilogue) ----
  wgemm<128, 256, false>(H, hb, wa1, ba1, quad, col, nullptr, nullptr, nullptr);
  wgemm<256, 256, false>(H, hb, wa2, ba2, quad, col, nullptr, nullptr, nullptr);
  wgemm<256, 256, true >(H, hb, wa3, ba3, quad, col, a2w, a2b, a2a);

  // ---- aa4 (K=256, N=20 padded 32) + log_softmax ----
  {
    f4_t a4[2];
    a4[0] = (f4_t)0.f; a4[1] = (f4_t)0.f;
    const unsigned short* hp = &H[hb + col][quad * 8];
    const unsigned short* wp = wa4 + col * 32 + quad * 8;
    bf8_t bc[2];
    bc[0] = *(const bf8_t*)(wp);
    bc[1] = *(const bf8_t*)(wp + (size_t)16 * 32);
    #pragma unroll
    for (int s = 0; s < 8; ++s) {
      bf8_t am = *(const bf8_t*)(hp + s * 32);
      #pragma unroll
      for (int nt = 0; nt < 2; ++nt) {
        bf8_t b = bc[nt];
        if (s + 1 < 8)
          bc[nt] = *(const bf8_t*)(wp + (size_t)((s + 1) * 32 + nt * 16) * 32);
        a4[nt] = __builtin_amdgcn_mfma_f32_16x16x32_bf16(am, b, a4[nt], 0, 0, 0);
      }
    }
    float val[2][4];
    #pragma unroll
    for (int nt = 0; nt < 2; ++nt) {
      int n = nt * 16 + col;
      float bsv = (n < 20) ? ba4[n] : 0.f;
      #pragma unroll
      for (int r4 = 0; r4 < 4; ++r4) val[nt][r4] = a4[nt][r4] + bsv;
    }
    bool v1 = (col < 4);
    #pragma unroll
    for (int r4 = 0; r4 < 4; ++r4) {
      float m = val[0][r4];
      if (v1) m = fmaxf(m, val[1][r4]);
      m = fmaxf(m, __shfl_xor(m, 1, 64));
      m = fmaxf(m, __shfl_xor(m, 2, 64));
      m = fmaxf(m, __shfl_xor(m, 4, 64));
      m = fmaxf(m, __shfl_xor(m, 8, 64));
      float se = __expf(val[0][r4] - m) + (v1 ? __expf(val[1][r4] - m) : 0.f);
      se += __shfl_xor(se, 1, 64);
      se += __shfl_xor(se, 2, 64);
      se += __shfl_xor(se, 4, 64);
      se += __shfl_xor(se, 8, 64);
      float ls = __logf(se) + m;
      int row = row0 + quad * 4 + r4;
      if (row < M) {
        out[(size_t)row * 20 + col] = val[0][r4] - ls;
        if (v1) out[(size_t)row * 20 + 16 + col] = val[1][r4] - ls;
      }
    }
  }
}

// ---------------- fused edge head (prefetching, barrier-free) ----------------
__global__ __launch_bounds__(256) void k_edge(
    const unsigned short* __restrict__ zn_bf,
    const int* __restrict__ ci, const int* __restrict__ cj,
    const unsigned short* __restrict__ w1t, const float* __restrict__ b1,
    const unsigned short* __restrict__ w2t, const float* __restrict__ b2,
    const float* __restrict__ w3, const float* __restrict__ b3,
    float* __restrict__ out, int M) {
  __shared__ unsigned short h1s[4][16][136];
  int lane = threadIdx.x & 63, wave = threadIdx.x >> 6;
  int quad = lane >> 4, col = lane & 15;
  unsigned short (*h1)[136] = h1s[wave];
  int ntiles = (M + 63) >> 6;
  float b3v = b3[0];

  int tile = blockIdx.x;
  bf8_t afrag[4];
  if (tile < ntiles) {
    int r = tile * 64 + wave * 16 + col; if (r >= M) r = M - 1;
    const unsigned short* p0 = zn_bf + (size_t)ci[r] * 64;
    const unsigned short* p1 = zn_bf + (size_t)cj[r] * 64;
    afrag[0] = *(const bf8_t*)(p0 + quad * 8);
    afrag[1] = *(const bf8_t*)(p0 + 32 + quad * 8);
    afrag[2] = *(const bf8_t*)(p1 + quad * 8);
    afrag[3] = *(const bf8_t*)(p1 + 32 + quad * 8);
  }

  for (; tile < ntiles; tile += gridDim.x) {
    f4_t acc[8];
    #pragma unroll
    for (int nt = 0; nt < 8; ++nt) acc[nt] = (f4_t)0.f;
    #pragma unroll
    for (int s = 0; s < 4; ++s) {
      int kf = s * 32 + quad * 8;
      #pragma unroll
      for (int nt = 0; nt < 8; ++nt) {
        bf8_t b = *(const bf8_t*)(w1t + (size_t)(nt * 16 + col) * 128 + kf);
        acc[nt] = __builtin_amdgcn_mfma_f32_16x16x32_bf16(afrag[s], b, acc[nt], 0, 0, 0);
      }
    }

    int nxt = tile + gridDim.x;
    bf8_t nfrag[4];
    bool has_next = (nxt < ntiles);
    if (has_next) {
      int r = nxt * 64 + wave * 16 + col; if (r >= M) r = M - 1;
      const unsigned short* p0 = zn_bf + (size_t)ci[r] * 64;
      const unsigned short* p1 = zn_bf + (size_t)cj[r] * 64;
      nfrag[0] = *(const bf8_t*)(p0 + quad * 8);
      nfrag[1] = *(const bf8_t*)(p0 + 32 + quad * 8);
      nfrag[2] = *(const bf8_t*)(p1 + quad * 8);
      nfrag[3] = *(const bf8_t*)(p1 + 32 + quad * 8);
    }

    #pragma unroll
    for (int nt = 0; nt < 8; ++nt) {
      float bs = b1[nt * 16 + col];
      #pragma unroll
      for (int r4 = 0; r4 < 4; ++r4)
        h1[quad * 4 + r4][nt * 16 + col] = f2bf(gelu_f(acc[nt][r4] + bs));
    }

    f4_t a2[8];
    #pragma unroll
    for (int nt = 0; nt < 8; ++nt) a2[nt] = (f4_t)0.f;
    #pragma unroll
    for (int s = 0; s < 4; ++s) {
      int kc = s * 32 + quad * 8;
      bf8_t a0 = *(const bf8_t*)&h1[col][kc];
      #pragma unroll
      for (int nt = 0; nt < 8; ++nt) {
        bf8_t b = *(const bf8_t*)(w2t + (size_t)(nt * 16 + col) * 128 + kc);
        a2[nt] = __builtin_amdgcn_mfma_f32_16x16x32_bf16(a0, b, a2[nt], 0, 0, 0);
      }
    }
    float p[4] = {0.f, 0.f, 0.f, 0.f};
    #pragma unroll
    for (int nt = 0; nt < 8; ++nt) {
      float bs = b2[nt * 16 + col];
      float wv = w3[nt * 16 + col];
      #pragma unroll
      for (int r4 = 0; r4 < 4; ++r4)
        p[r4] += gelu_f(a2[nt][r4] + bs) * wv;
    }
    #pragma unroll
    for (int r4 = 0; r4 < 4; ++r4) {
      float s = p[r4];
      s += __shfl_xor(s, 1, 64);
      s += __shfl_xor(s, 2, 64);
      s += __shfl_xor(s, 4, 64);
      s += __shfl_xor(s, 8, 64);
      if (col == 0) {
        int row = tile * 64 + wave * 16 + quad * 4 + r4;
        if (row < M) out[row] = __builtin_amdgcn_rcpf(1.0f + __expf(-(s + b3v)));
      }
    }

    if (has_next) {
      afrag[0] = nfrag[0]; afrag[1] = nfrag[1];
      afrag[2] = nfrag[2]; afrag[3] = nfrag[3];
    }
  }
}

// ---------------- launcher ----------------
extern "C" void kernel_launch(void* const* d_in, const int* in_sizes, int n_in,
                              void* d_out, int out_size, void* d_ws, size_t ws_size,
                              hipStream_t stream) {
  const float* x_res  = (const float*)d_in[0];
  const float* Wl     = (const float*)d_in[1];
  const float* bl     = (const float*)d_in[2];
  const float* Wr     = (const float*)d_in[3];
  const float* gn_w   = (const float*)d_in[4];
  const float* gn_b   = (const float*)d_in[5];
  const float* gn_ms  = (const float*)d_in[6];
  const float* dyt1_w = (const float*)d_in[7];
  const float* dyt1_b = (const float*)d_in[8];
  const float* dyt1_a = (const float*)d_in[9];
  const float* lin1_w = (const float*)d_in[10];
  const float* lin1_b = (const float*)d_in[11];
  const float* lin2_w = (const float*)d_in[12];
  const float* lin2_b = (const float*)d_in[13];
  const float* lin3_w = (const float*)d_in[14];
  const float* lin3_b = (const float*)d_in[15];
  const float* dyt2_w = (const float*)d_in[16];
  const float* dyt2_b = (const float*)d_in[17];
  const float* dyt2_a = (const float*)d_in[18];
  const float* adyt1_w = (const float*)d_in[19];
  const float* adyt1_b = (const float*)d_in[20];
  const float* adyt1_a = (const float*)d_in[21];
  const float* aa1_w  = (const float*)d_in[22];
  const float* aa1_b  = (const float*)d_in[23];
  const float* aa2_w  = (const float*)d_in[24];
  const float* aa2_b  = (const float*)d_in[25];
  const float* aa3_w  = (const float*)d_in[26];
  const float* aa3_b  = (const float*)d_in[27];
  const float* adyt2_w = (const float*)d_in[28];
  const float* adyt2_b = (const float*)d_in[29];
  const float* adyt2_a = (const float*)d_in[30];
  const float* aa4_w  = (const float*)d_in[31];
  const float* aa4_b  = (const float*)d_in[32];
  const float* c1_w   = (const float*)d_in[33];
  const float* c1_b   = (const float*)d_in[34];
  const float* c2_w   = (const float*)d_in[35];
  const float* c2_b   = (const float*)d_in[36];
  const float* c3_w   = (const float*)d_in[37];
  const float* c3_b   = (const float*)d_in[38];
  const int*   edge   = (const int*)d_in[39];
  const int*   contact = (const int*)d_in[40];

  const size_t N = (size_t)Nn;
  const size_t ws_floats = ws_size / 4;

  float* ws    = (float*)d_ws;
  float* rdeg  = ws;
  float* hbuf  = rdeg + N;
  unsigned short* z_bf  = (unsigned short*)(hbuf + 64 * N);
  unsigned short* zn_bf = z_bf + 192 * N;
  float* stats = (float*)(zn_bf + 64 * N);
  unsigned short* wt_sage = (unsigned short*)(stats + 256);
  unsigned short* wt_lin1 = wt_sage + 3 * 64 * 128;
  unsigned short* wt_lin2 = wt_lin1 + 256 * 192;
  unsigned short* wt_lin3 = wt_lin2 + 256 * 256;
  unsigned short* wt_aa1  = wt_lin3 + 64 * 256;
  unsigned short* wt_aa2  = wt_aa1 + 256 * 128;
  unsigned short* wt_aa3  = wt_aa2 + 256 * 256;
  unsigned short* wt_aa4  = wt_aa3 + 256 * 256;
  unsigned short* wt_c1   = wt_aa4 + 32 * 256;
  unsigned short* wt_c2   = wt_c1 + 128 * 128;
  unsigned short* wt_end  = wt_c2 + 128 * 128;
  float* pool  = (float*)((((uintptr_t)wt_end + 15) & ~(uintptr_t)15));
  const size_t persist = (size_t)(pool - ws);

  const size_t gnn_need = 32 * N + N + (N + 1) + N + (size_t)Ee + 256;
  if (ws_floats < persist + gnn_need) return;

  unsigned short* agg_bf = (unsigned short*)pool;
  int* cnt     = (int*)(pool + 32 * N);
  int* rowptr  = cnt + N;
  int* cursor  = rowptr + N + 1;
  int* colidx  = cursor + N;
  int* bsum    = colidx + Ee;

  const int* esrc = edge;
  const int* edst = edge + Ee;

  // ---- CSR build ----
  hipMemsetAsync(cnt, 0, N * sizeof(int), stream);
  k_degi<<<(Ee + 255) / 256, 256, 0, stream>>>(edst, cnt, Ee);
  k_rdeg<<<(Nn + 255) / 256, 256, 0, stream>>>(cnt, rdeg, Nn);
  const int nb = (Nn + 1023) / 1024;
  k_scan1<<<nb, 256, 0, stream>>>(cnt, cursor, bsum, Nn);
  k_scan2<<<1, 256, 0, stream>>>(bsum, nb);
  k_scan3<<<(Nn + 255) / 256, 256, 0, stream>>>(cursor, bsum, rowptr, cursor, Nn, Ee);
  k_fill<<<(Ee + 255) / 256, 256, 0, stream>>>(esrc, edst, cursor, colidx, Ee);

  // ---- weight prep ----
  k_wtsage<<<(3 * 64 * 128 + 255) / 256, 256, 0, stream>>>(Wl, Wr, wt_sage);
  // node-pipeline weights in blocked [(k>>5)*N + n][k&31] layout
  k_wt3<<<(192 * 256 + 255) / 256, 256, 0, stream>>>(lin1_w, wt_lin1, 256, 256, 192 * 256);
  k_wt3<<<(256 * 256 + 255) / 256, 256, 0, stream>>>(lin2_w, wt_lin2, 256, 256, 256 * 256);
  k_wt3<<<(256 * 64 + 255) / 256, 256, 0, stream>>>(lin3_w, wt_lin3, 64, 64, 256 * 64);
  k_wt3<<<(128 * 256 + 255) / 256, 256, 0, stream>>>(aa1_w, wt_aa1, 256, 256, 128 * 256);
  k_wt3<<<(256 * 256 + 255) / 256, 256, 0, stream>>>(aa2_w, wt_aa2, 256, 256, 256 * 256);
  k_wt3<<<(256 * 256 + 255) / 256, 256, 0, stream>>>(aa3_w, wt_aa3, 256, 256, 256 * 256);
  k_wt3<<<(256 * 32 + 255) / 256, 256, 0, stream>>>(aa4_w, wt_aa4, 32, 20, 256 * 32);
  // edge-head weights keep the [n][k] layout
  k_wt2<<<(128 * 128 + 255) / 256, 256, 0, stream>>>(c1_w, wt_c1, 128, 128, 128 * 128);
  k_wt2<<<(128 * 128 + 255) / 256, 256, 0, stream>>>(c2_w, wt_c2, 128, 128, 128 * 128);

  // xb = bf16(x_res) in zn_bf slot
  k_cvt<<<(int)((N * 64 + 255) / 256), 256, 0, stream>>>(x_res, zn_bf, (int)(N * 64));

  // ---- GNN phase ----
  for (int l = 0; l < 3; ++l) {
    const unsigned short* xi = (l == 0) ? zn_bf : (z_bf + (size_t)(l - 1) * 64);
    int ldx = (l == 0) ? 64 : 192;
    hipMemsetAsync(stats, 0, 128 * sizeof(float), stream);
    k_gather<<<(Nn + 3) / 4, 256, 0, stream>>>(xi, ldx, rowptr, colidx, rdeg, agg_bf, Nn);
    mgemm<4><<<dim3((Nn + 127) / 128, 1), 256, 0, stream>>>(
        agg_bf, 64, xi, ldx, 64, 1,
        wt_sage + (size_t)l * 8192, bl + l * 64, hbuf, 64, 0, 1, Nn, 128, 64);
    k_stats<<<1024, 256, 0, stream>>>(hbuf, stats, Nn);
    k_statfin<<<1, 64, 0, stream>>>(stats, gn_ms + l * 64, Nn);
    k_norm<<<(Nn * 64) / 256, 256, 0, stream>>>(hbuf, stats, gn_w + l * 64, gn_b + l * 64,
                                                z_bf + (size_t)l * 64,
                                                (l > 0) ? (z_bf + (size_t)(l - 1) * 64) : nullptr, Nn);
  }

  // ---- wave-private fused node pipeline (zero barriers, 2-wave blocks) ----
  k_node<<<(Nn + 31) / 32, 128, 0, stream>>>(
      z_bf, x_res,
      dyt1_w, dyt1_b, dyt1_a, wt_lin1, lin1_b, wt_lin2, lin2_b, wt_lin3, lin3_b,
      dyt2_w, dyt2_b, dyt2_a,
      adyt1_w, adyt1_b, adyt1_a, wt_aa1, aa1_b, wt_aa2, aa2_b, wt_aa3, aa3_b,
      adyt2_w, adyt2_b, adyt2_a, wt_aa4, aa4_b,
      zn_bf, (float*)d_out, Nn);

  // ---- fused edge head ----
  float* eout = (float*)d_out + (size_t)Nn * 20;
  k_edge<<<2048, 256, 0, stream>>>(zn_bf, contact, contact + EPp,
      wt_c1, c1_b, wt_c2, c2_b, c3_w, c3_b, eout, EPp);
}

// Round 3
// 1547.018 us; speedup vs baseline: 1.2491x; 1.1888x over previous
//
#include <hip/hip_runtime.h>
#include <cstdint>
#include <cstddef>

// ---------------- problem constants ----------------
constexpr int Nn  = 200000;
constexpr int Ee  = 1600000;
constexpr int EPp = 1000000;

typedef __attribute__((ext_vector_type(8))) short bf8_t;
typedef __attribute__((ext_vector_type(4))) float f4_t;

__device__ inline unsigned short f2bf(float f) {
  union { float f; unsigned u; } v; v.f = f;
  unsigned r = v.u + 0x7FFFu + ((v.u >> 16) & 1u);
  return (unsigned short)(r >> 16);
}
__device__ inline float bf2f(unsigned short u) {
  union { unsigned u; float f; } v; v.u = ((unsigned)u) << 16;
  return v.f;
}
// tanh-form GELU, algebraically reduced: 0.5v(1+tanh(u)) = v*(1-r), r=1/(e^{2u}+1)
__device__ inline float gelu_f(float v) {
  float u = v * fmaf(0.0356774081f, v * v, 0.7978845608f);
  float r = __builtin_amdgcn_rcpf(__expf(u + u) + 1.0f);
  return fmaf(-v, r, v);
}
// dyt: w*tanh(a x)+b with s2 = 2*a prefolded: tanh = 1-2r
__device__ inline float dyt_f(float x, float s2, float w, float b) {
  float r = __builtin_amdgcn_rcpf(__expf(s2 * x) + 1.0f);
  return fmaf(w, fmaf(-2.0f, r, 1.0f), b);
}

// ---------------- degree / CSR build ----------------

__global__ __launch_bounds__(256) void k_degi(const int* __restrict__ dst,
                                              int* __restrict__ cnt, int E) {
  int i = blockIdx.x * 256 + threadIdx.x;
  if (i < E) atomicAdd(&cnt[dst[i]], 1);
}

__global__ __launch_bounds__(256) void k_rdeg(const int* __restrict__ cnt,
                                              float* __restrict__ rdeg, int n) {
  int i = blockIdx.x * 256 + threadIdx.x;
  if (i < n) rdeg[i] = 1.0f / (float)(cnt[i] > 1 ? cnt[i] : 1);
}

__global__ __launch_bounds__(256) void k_scan1(const int* __restrict__ in,
                                               int* __restrict__ out,
                                               int* __restrict__ bsum, int n) {
  __shared__ int sd[256];
  int t = threadIdx.x;
  int base = blockIdx.x * 1024 + t * 4;
  int v[4]; int ts = 0;
  #pragma unroll
  for (int j = 0; j < 4; ++j) { v[j] = (base + j < n) ? in[base + j] : 0; ts += v[j]; }
  sd[t] = ts; __syncthreads();
  for (int off = 1; off < 256; off <<= 1) {
    int x = (t >= off) ? sd[t - off] : 0;
    __syncthreads();
    sd[t] += x;
    __syncthreads();
  }
  int excl = sd[t] - ts;
  #pragma unroll
  for (int j = 0; j < 4; ++j) { if (base + j < n) out[base + j] = excl; excl += v[j]; }
  if (t == 255) bsum[blockIdx.x] = sd[255];
}

__global__ void k_scan2(int* bsum, int nb) {
  __shared__ int sd[256];
  int t = threadIdx.x;
  int v = (t < nb) ? bsum[t] : 0;
  sd[t] = v; __syncthreads();
  for (int off = 1; off < 256; off <<= 1) {
    int x = (t >= off) ? sd[t - off] : 0;
    __syncthreads();
    sd[t] += x;
    __syncthreads();
  }
  if (t < nb) bsum[t] = sd[t] - v;
}

__global__ __launch_bounds__(256) void k_scan3(const int* __restrict__ part,
                                               const int* __restrict__ bsum,
                                               int* __restrict__ rowptr,
                                               int* __restrict__ cursor,
                                               int n, int total) {
  int i = blockIdx.x * 256 + threadIdx.x;
  if (i == 0) rowptr[n] = total;
  if (i < n) { int v = part[i] + bsum[i >> 10]; rowptr[i] = v; cursor[i] = v; }
}

__global__ __launch_bounds__(256) void k_fill(const int* __restrict__ src,
                                              const int* __restrict__ dst,
                                              int* __restrict__ cursor,
                                              int* __restrict__ colidx, int E) {
  int e = blockIdx.x * 256 + threadIdx.x;
  if (e >= E) return;
  int pos = atomicAdd(&cursor[dst[e]], 1);
  colidx[pos] = src[e];
}

// gather-mean over bf16 features: one wave per node, 8 groups of 8 lanes
__global__ __launch_bounds__(256) void k_gather(const unsigned short* __restrict__ x, int ldx,
                                                const int* __restrict__ rowptr,
                                                const int* __restrict__ colidx,
                                                const float* __restrict__ rdeg,
                                                unsigned short* __restrict__ agg, int n) {
  int wave = threadIdx.x >> 6, lane = threadIdx.x & 63;
  int node = blockIdx.x * 4 + wave;
  if (node >= n) return;
  int grp = lane >> 3, c = (lane & 7) * 8;
  int r0 = rowptr[node], r1 = rowptr[node + 1];
  float s[8] = {0.f, 0.f, 0.f, 0.f, 0.f, 0.f, 0.f, 0.f};
  for (int j = r0 + grp; j < r1; j += 8) {
    bf8_t v = *(const bf8_t*)(x + (size_t)colidx[j] * ldx + c);
    #pragma unroll
    for (int jj = 0; jj < 8; ++jj) s[jj] += bf2f((unsigned short)v[jj]);
  }
  #pragma unroll
  for (int jj = 0; jj < 8; ++jj) {
    s[jj] += __shfl_xor(s[jj], 8, 64);
    s[jj] += __shfl_xor(s[jj], 16, 64);
    s[jj] += __shfl_xor(s[jj], 32, 64);
  }
  if (grp == 0) {
    float r = rdeg[node];
    bf8_t o;
    #pragma unroll
    for (int jj = 0; jj < 8; ++jj) o[jj] = (short)f2bf(s[jj] * r);
    *(bf8_t*)(agg + (size_t)node * 64 + c) = o;
  }
}

// ---------------- misc small kernels ----------------

__global__ __launch_bounds__(256) void k_cvt(const float* __restrict__ in,
                                             unsigned short* __restrict__ out, int n) {
  int i = blockIdx.x * 256 + threadIdx.x;
  if (i < n) out[i] = f2bf(in[i]);
}

__global__ __launch_bounds__(256) void k_wt2(const float* __restrict__ W,
                                             unsigned short* __restrict__ Wt,
                                             int K, int N, int total) {
  int i = blockIdx.x * 256 + threadIdx.x;
  if (i >= total) return;
  int n = i / K, k = i - n * K;
  float v = (n < N) ? W[(size_t)k * N + n] : 0.f;
  Wt[i] = f2bf(v);
}

// blocked layout for the node pipeline:
// Wt[((k>>5)*Np + n)*32 + (k&31)] = W[k][n]   (zero-padded for n >= Nr)
__global__ __launch_bounds__(256) void k_wt3(const float* __restrict__ W,
                                             unsigned short* __restrict__ Wt,
                                             int Np, int Nr, int total) {
  int i = blockIdx.x * 256 + threadIdx.x;
  if (i >= total) return;
  int kin = i & 31;
  int j = i >> 5;
  int n = j % Np, kb = j / Np;
  int k = kb * 32 + kin;
  float v = (n < Nr) ? W[(size_t)k * Nr + n] : 0.f;
  Wt[i] = f2bf(v);
}

__global__ __launch_bounds__(256) void k_wtsage(const float* __restrict__ Wl,
                                                const float* __restrict__ Wr,
                                                unsigned short* __restrict__ Wt) {
  int i = blockIdx.x * 256 + threadIdx.x;
  if (i >= 3 * 64 * 128) return;
  int l = i >> 13, r = i & 8191, n = r >> 7, k = r & 127;
  float v = (k < 64) ? Wl[l * 4096 + k * 64 + n] : Wr[l * 4096 + (k - 64) * 64 + n];
  Wt[i] = f2bf(v);
}

__global__ __launch_bounds__(256) void k_stats(const float* __restrict__ h,
                                               float* __restrict__ stats, int n) {
  int lane = threadIdx.x & 63, grp = threadIdx.x >> 6;
  float s = 0.f, s2 = 0.f;
  for (int r = blockIdx.x * 4 + grp; r < n; r += gridDim.x * 4) {
    float v = h[(size_t)r * 64 + lane];
    s += v; s2 += v * v;
  }
  __shared__ float l1[4][64], l2[4][64];
  l1[grp][lane] = s; l2[grp][lane] = s2;
  __syncthreads();
  if (grp == 0) {
    s  = l1[0][lane] + l1[1][lane] + l1[2][lane] + l1[3][lane];
    s2 = l2[0][lane] + l2[1][lane] + l2[2][lane] + l2[3][lane];
    atomicAdd(&stats[lane], s);
    atomicAdd(&stats[64 + lane], s2);
  }
}

__global__ void k_statfin(float* stats, const float* __restrict__ ms_, int n) {
  int d = threadIdx.x;
  if (d < 64) {
    float invn = 1.0f / (float)n;
    float m  = stats[d] * invn;
    float e2 = stats[64 + d] * invn;
    float ms = ms_[d];
    float var = e2 - (2.0f * ms - ms * ms) * m * m;
    stats[128 + d] = ms * m;
    stats[192 + d] = rsqrtf(var + 1e-5f);
  }
}

__global__ __launch_bounds__(256) void k_norm(const float* __restrict__ h,
                                              const float* __restrict__ stats,
                                              const float* __restrict__ w,
                                              const float* __restrict__ b,
                                              unsigned short* __restrict__ zcol,
                                              const unsigned short* __restrict__ prev, int n) {
  int i = blockIdx.x * 256 + threadIdx.x;
  if (i >= n * 64) return;
  int r = i >> 6, d = i & 63;
  float v = (h[i] - stats[128 + d]) * stats[192 + d] * w[d] + b[d];
  if (prev) v += bf2f(prev[(size_t)r * 192 + d]);
  zcol[(size_t)r * 192 + d] = f2bf(v);
}

// ---------------- generic bf16 MFMA GEMM (barrier-free, for SAGE) ----------------
template <int NT>
__global__ __launch_bounds__(256) void mgemm(
    const void* __restrict__ A1, int lda1,
    const void* __restrict__ A2, int lda2, int K1, int a_bf16,
    const unsigned short* __restrict__ Wt,
    const float* __restrict__ bias,
    void* __restrict__ Cout, int ldc, int c_bf16, int act,
    int M, int K, int N) {
  int lane = threadIdx.x & 63, wave = threadIdx.x >> 6;
  int quad = lane >> 4, col = lane & 15;
  int row0 = blockIdx.x * 128 + wave * 32;
  int n_base = blockIdx.y * NT * 16;

  f4_t acc[2][NT];
  #pragma unroll
  for (int mt = 0; mt < 2; ++mt)
    #pragma unroll
    for (int nt = 0; nt < NT; ++nt) acc[mt][nt] = (f4_t)0.f;

  int gm[2];
  gm[0] = row0 + col;      if (gm[0] >= M) gm[0] = M - 1;
  gm[1] = row0 + 16 + col; if (gm[1] >= M) gm[1] = M - 1;

  for (int kc0 = 0; kc0 < K; kc0 += 32) {
    int kc = kc0 + quad * 8;
    bf8_t a[2];
    #pragma unroll
    for (int mt = 0; mt < 2; ++mt) {
      const void* src; size_t off;
      if (kc < K1) { src = A1; off = (size_t)gm[mt] * lda1 + kc; }
      else         { src = A2; off = (size_t)gm[mt] * lda2 + kc - K1; }
      if (a_bf16) {
        a[mt] = *(const bf8_t*)((const unsigned short*)src + off);
      } else {
        const float* p = (const float*)src + off;
        float4 f0 = *(const float4*)p;
        float4 f1 = *(const float4*)(p + 4);
        float ff[8] = {f0.x, f0.y, f0.z, f0.w, f1.x, f1.y, f1.z, f1.w};
        #pragma unroll
        for (int j = 0; j < 8; ++j) a[mt][j] = (short)f2bf(ff[j]);
      }
    }
    #pragma unroll
    for (int nt = 0; nt < NT; ++nt) {
      bf8_t b = *(const bf8_t*)(Wt + (size_t)(n_base + nt * 16 + col) * K + kc);
      acc[0][nt] = __builtin_amdgcn_mfma_f32_16x16x32_bf16(a[0], b, acc[0][nt], 0, 0, 0);
      acc[1][nt] = __builtin_amdgcn_mfma_f32_16x16x32_bf16(a[1], b, acc[1][nt], 0, 0, 0);
    }
  }

  #pragma unroll
  for (int nt = 0; nt < NT; ++nt) {
    int n = n_base + nt * 16 + col;
    float bs = (bias && n < N) ? bias[n] : 0.f;
    #pragma unroll
    for (int mt = 0; mt < 2; ++mt)
      #pragma unroll
      for (int r = 0; r < 4; ++r) {
        int row = row0 + mt * 16 + quad * 4 + r;
        if (row >= M || n >= N) continue;
        float v = acc[mt][nt][r] + bs;
        if (act) v = gelu_f(v);
        if (c_bf16) ((unsigned short*)Cout)[(size_t)row * ldc + n] = f2bf(v);
        else        ((float*)Cout)[(size_t)row * ldc + n] = v;
      }
  }
}

// ---------------- block-cooperative fused node pipeline ----------------
// Block = 256 thr = 4 waves = 64 rows; wave w owns output cols [64w,64w+64).
// Block reads each weight once per 64 rows (1.9 GB L2 traffic total, 4x less
// than wave-private). __launch_bounds__(256,4) caps VGPR at 128 -> 4 blocks/CU
// -> 16 waves/CU; 16 waves x 4-deep b-prefetch = 64KB in flight/CU >> the 11KB
// BW*latency product, so the k-loop is L2-BW-bound, not latency-bound.
template <int K, bool DYT>
__device__ inline void node_gemm(unsigned short (*H)[264],
                                 const unsigned short* __restrict__ W,
                                 const float* __restrict__ bias,
                                 int wave, int quad, int col,
                                 const float* __restrict__ a2w,
                                 const float* __restrict__ a2b,
                                 const float* __restrict__ aal) {
  constexpr int KS = K >> 5;
  f4_t acc[4][4];
  #pragma unroll
  for (int mt = 0; mt < 4; ++mt)
    #pragma unroll
    for (int nt = 0; nt < 4; ++nt) acc[mt][nt] = (f4_t)0.f;

  // b(s,nt) at wp + (s*256 + nt*16)*32  (blocked layout, Np=256)
  const unsigned short* wp = W + (size_t)(wave * 64 + col) * 32 + quad * 8;
  bf8_t bc[4];
  #pragma unroll
  for (int nt = 0; nt < 4; ++nt)
    bc[nt] = *(const bf8_t*)(wp + (size_t)(nt * 16) * 32);

  #pragma unroll
  for (int s = 0; s < KS; ++s) {
    bf8_t am[4];
    #pragma unroll
    for (int mt = 0; mt < 4; ++mt)
      am[mt] = *(const bf8_t*)&H[mt * 16 + col][s * 32 + quad * 8];
    bf8_t bn[4];
    if (s + 1 < KS) {
      #pragma unroll
      for (int nt = 0; nt < 4; ++nt)
        bn[nt] = *(const bf8_t*)(wp + (size_t)((s + 1) * 256 + nt * 16) * 32);
    }
    #pragma unroll
    for (int nt = 0; nt < 4; ++nt)
      #pragma unroll
      for (int mt = 0; mt < 4; ++mt)
        acc[mt][nt] = __builtin_amdgcn_mfma_f32_16x16x32_bf16(am[mt], bc[nt], acc[mt][nt], 0, 0, 0);
    if (s + 1 < KS) {
      #pragma unroll
      for (int nt = 0; nt < 4; ++nt) bc[nt] = bn[nt];
    }
  }
  __syncthreads();   // all reads of H complete before epilogue writes
  float sa = DYT ? (2.0f * aal[0]) : 0.f;
  #pragma unroll
  for (int nt = 0; nt < 4; ++nt) {
    int n = wave * 64 + nt * 16 + col;
    float bs = bias[n];
    float w_ = DYT ? a2w[n] : 0.f;
    float b_ = DYT ? a2b[n] : 0.f;
    #pragma unroll
    for (int mt = 0; mt < 4; ++mt)
      #pragma unroll
      for (int r4 = 0; r4 < 4; ++r4) {
        float v = gelu_f(acc[mt][nt][r4] + bs);
        if (DYT) v = dyt_f(v, sa, w_, b_);
        H[mt * 16 + quad * 4 + r4][n] = f2bf(v);
      }
  }
  __syncthreads();
}

__global__ __launch_bounds__(256, 4) void k_node(
    const unsigned short* __restrict__ z_bf,
    const float* __restrict__ x_res,
    const float* __restrict__ d1w, const float* __restrict__ d1b, const float* __restrict__ d1a,
    const unsigned short* __restrict__ wt1, const float* __restrict__ b1,
    const unsigned short* __restrict__ wt2, const float* __restrict__ b2,
    const unsigned short* __restrict__ wt3, const float* __restrict__ b3,
    const float* __restrict__ d2w, const float* __restrict__ d2b, const float* __restrict__ d2a,
    const float* __restrict__ a1w, const float* __restrict__ a1b, const float* __restrict__ a1a,
    const unsigned short* __restrict__ wa1, const float* __restrict__ ba1,
    const unsigned short* __restrict__ wa2, const float* __restrict__ ba2,
    const unsigned short* __restrict__ wa3, const float* __restrict__ ba3,
    const float* __restrict__ a2w, const float* __restrict__ a2b, const float* __restrict__ a2a,
    const unsigned short* __restrict__ wa4, const float* __restrict__ ba4,
    unsigned short* __restrict__ zn_bf,
    float* __restrict__ out, int M) {
  __shared__ unsigned short H[64][264];   // 33.8 KB
  __shared__ float fscr[64 * 4 + 64];     // rownorm partials + inv norms
  int t = threadIdx.x;
  int lane = t & 63, wave = t >> 6;
  int quad = lane >> 4, col = lane & 15;
  int brow = blockIdx.x * 64;

  // ---- stage H = dyt1(z rows) ----
  {
    int row = t >> 2, part = t & 3;
    int gr = brow + row; if (gr >= M) gr = M - 1;
    const unsigned short* zp = z_bf + (size_t)gr * 192 + part * 48;
    float s1 = 2.0f * d1a[0];
    #pragma unroll
    for (int j = 0; j < 6; ++j) {
      bf8_t v = *(const bf8_t*)(zp + j * 8);
      int k0 = part * 48 + j * 8;
      #pragma unroll
      for (int jj = 0; jj < 8; ++jj) {
        float f = bf2f((unsigned short)v[jj]);
        v[jj] = (short)f2bf(dyt_f(f, s1, d1w[k0 + jj], d1b[k0 + jj]));
      }
      *(bf8_t*)&H[row][k0] = v;
    }
  }
  __syncthreads();

  // ---- lin1 (K=192), lin2 (K=256) ----
  node_gemm<192, false>(H, wt1, b1, wave, quad, col, nullptr, nullptr, nullptr);
  node_gemm<256, false>(H, wt2, b2, wave, quad, col, nullptr, nullptr, nullptr);

  // ---- lin3 (K=256, N=64; wave w owns n-tile w) + dyt2 + resid + rownorm + adyt1 ----
  {
    f4_t a3[4];
    #pragma unroll
    for (int mt = 0; mt < 4; ++mt) a3[mt] = (f4_t)0.f;
    const unsigned short* wp3 = wt3 + (size_t)(wave * 16 + col) * 32 + quad * 8;
    bf8_t bc = *(const bf8_t*)(wp3);
    #pragma unroll
    for (int s = 0; s < 8; ++s) {
      bf8_t am[4];
      #pragma unroll
      for (int mt = 0; mt < 4; ++mt)
        am[mt] = *(const bf8_t*)&H[mt * 16 + col][s * 32 + quad * 8];
      bf8_t bn;
      if (s + 1 < 8) bn = *(const bf8_t*)(wp3 + (size_t)((s + 1) * 64) * 32);
      #pragma unroll
      for (int mt = 0; mt < 4; ++mt)
        a3[mt] = __builtin_amdgcn_mfma_f32_16x16x32_bf16(am[mt], bc, a3[mt], 0, 0, 0);
      if (s + 1 < 8) bc = bn;
    }
    __syncthreads();                     // all lin3 reads of H complete
    // vv (fp32) overlaid into H's storage ([64][66] floats)
    float* fb = (float*)H;
    float s2d = 2.0f * d2a[0];
    int n = wave * 16 + col;
    float bsn = b3[n], wd = d2w[n], bd = d2b[n];
    #pragma unroll
    for (int mt = 0; mt < 4; ++mt)
      #pragma unroll
      for (int r4 = 0; r4 < 4; ++r4) {
        int row = mt * 16 + quad * 4 + r4;
        int gr = brow + row; if (gr >= M) gr = M - 1;
        float g = gelu_f(a3[mt][r4] + bsn);
        float x = x_res[(size_t)gr * 64 + n];
        fb[row * 66 + n] = dyt_f(g, s2d, wd, bd) + x;
      }
    __syncthreads();
    // each thread owns (row = t>>2, cols q*16..q*16+15): read to REGISTERS
    int row = t >> 2, q = t & 3;
    float vreg[16];
    float s2 = 0.f;
    #pragma unroll
    for (int c16 = 0; c16 < 16; ++c16) {
      vreg[c16] = fb[row * 66 + q * 16 + c16];
      s2 += vreg[c16] * vreg[c16];
    }
    fscr[row * 4 + q] = s2;
    __syncthreads();
    if (t < 64)
      fscr[256 + t] = 1.0f / (sqrtf(fscr[t * 4] + fscr[t * 4 + 1] + fscr[t * 4 + 2] + fscr[t * 4 + 3]) + 1e-10f);
    __syncthreads();                     // all fb reads complete; inv ready
    // write adyt1([x_res, zn]) into H (bf16 view) from registers; write zn_bf
    float sa1 = 2.0f * a1a[0];
    float inv = fscr[256 + row];
    int gr = brow + row;
    int grc = (gr >= M) ? (M - 1) : gr;
    #pragma unroll
    for (int c16 = 0; c16 < 16; ++c16) {
      int c = q * 16 + c16;
      float zv = vreg[c16] * inv;
      if (gr < M) zn_bf[(size_t)gr * 64 + c] = f2bf(zv);
      float x = x_res[(size_t)grc * 64 + c];
      H[row][64 + c] = f2bf(dyt_f(zv, sa1, a1w[64 + c], a1b[64 + c]));
      H[row][c]      = f2bf(dyt_f(x,  sa1, a1w[c],      a1b[c]));
    }
    __syncthreads();
  }

  // ---- aa1 (K=128), aa2 (K=256), aa3 (K=256, adyt2 epilogue) ----
  node_gemm<128, false>(H, wa1, ba1, wave, quad, col, nullptr, nullptr, nullptr);
  node_gemm<256, false>(H, wa2, ba2, wave, quad, col, nullptr, nullptr, nullptr);
  node_gemm<256, true >(H, wa3, ba3, wave, quad, col, a2w, a2b, a2a);

  // ---- aa4 (K=256, N=20 padded 32; wave w owns m-tile w) + log_softmax ----
  {
    f4_t a4[2];
    a4[0] = (f4_t)0.f; a4[1] = (f4_t)0.f;
    const unsigned short* wp4 = wa4 + (size_t)col * 32 + quad * 8;
    bf8_t bc[2];
    bc[0] = *(const bf8_t*)(wp4);
    bc[1] = *(const bf8_t*)(wp4 + (size_t)(16) * 32);
    #pragma unroll
    for (int s = 0; s < 8; ++s) {
      bf8_t am = *(const bf8_t*)&H[wave * 16 + col][s * 32 + quad * 8];
      bf8_t bn[2];
      if (s + 1 < 8) {
        bn[0] = *(const bf8_t*)(wp4 + (size_t)((s + 1) * 32) * 32);
        bn[1] = *(const bf8_t*)(wp4 + (size_t)((s + 1) * 32 + 16) * 32);
      }
      #pragma unroll
      for (int nt = 0; nt < 2; ++nt)
        a4[nt] = __builtin_amdgcn_mfma_f32_16x16x32_bf16(am, bc[nt], a4[nt], 0, 0, 0);
      if (s + 1 < 8) { bc[0] = bn[0]; bc[1] = bn[1]; }
    }
    float val[2][4];
    #pragma unroll
    for (int nt = 0; nt < 2; ++nt) {
      int n = nt * 16 + col;
      float bsv = (n < 20) ? ba4[n] : 0.f;
      #pragma unroll
      for (int r4 = 0; r4 < 4; ++r4) val[nt][r4] = a4[nt][r4] + bsv;
    }
    bool v1 = (col < 4);
    #pragma unroll
    for (int r4 = 0; r4 < 4; ++r4) {
      float m = val[0][r4];
      if (v1) m = fmaxf(m, val[1][r4]);
      m = fmaxf(m, __shfl_xor(m, 1, 64));
      m = fmaxf(m, __shfl_xor(m, 2, 64));
      m = fmaxf(m, __shfl_xor(m, 4, 64));
      m = fmaxf(m, __shfl_xor(m, 8, 64));
      float se = __expf(val[0][r4] - m) + (v1 ? __expf(val[1][r4] - m) : 0.f);
      se += __shfl_xor(se, 1, 64);
      se += __shfl_xor(se, 2, 64);
      se += __shfl_xor(se, 4, 64);
      se += __shfl_xor(se, 8, 64);
      float ls = __logf(se) + m;
      int row = brow + wave * 16 + quad * 4 + r4;
      if (row < M) {
        out[(size_t)row * 20 + col] = val[0][r4] - ls;
        if (v1) out[(size_t)row * 20 + 16 + col] = val[1][r4] - ls;
      }
    }
  }
}

// ---------------- fused edge head (prefetching, barrier-free) ----------------
__global__ __launch_bounds__(256) void k_edge(
    const unsigned short* __restrict__ zn_bf,
    const int* __restrict__ ci, const int* __restrict__ cj,
    const unsigned short* __restrict__ w1t, const float* __restrict__ b1,
    const unsigned short* __restrict__ w2t, const float* __restrict__ b2,
    const float* __restrict__ w3, const float* __restrict__ b3,
    float* __restrict__ out, int M) {
  __shared__ unsigned short h1s[4][16][136];
  int lane = threadIdx.x & 63, wave = threadIdx.x >> 6;
  int quad = lane >> 4, col = lane & 15;
  unsigned short (*h1)[136] = h1s[wave];
  int ntiles = (M + 63) >> 6;
  float b3v = b3[0];

  int tile = blockIdx.x;
  bf8_t afrag[4];
  if (tile < ntiles) {
    int r = tile * 64 + wave * 16 + col; if (r >= M) r = M - 1;
    const unsigned short* p0 = zn_bf + (size_t)ci[r] * 64;
    const unsigned short* p1 = zn_bf + (size_t)cj[r] * 64;
    afrag[0] = *(const bf8_t*)(p0 + quad * 8);
    afrag[1] = *(const bf8_t*)(p0 + 32 + quad * 8);
    afrag[2] = *(const bf8_t*)(p1 + quad * 8);
    afrag[3] = *(const bf8_t*)(p1 + 32 + quad * 8);
  }

  for (; tile < ntiles; tile += gridDim.x) {
    f4_t acc[8];
    #pragma unroll
    for (int nt = 0; nt < 8; ++nt) acc[nt] = (f4_t)0.f;
    #pragma unroll
    for (int s = 0; s < 4; ++s) {
      int kf = s * 32 + quad * 8;
      #pragma unroll
      for (int nt = 0; nt < 8; ++nt) {
        bf8_t b = *(const bf8_t*)(w1t + (size_t)(nt * 16 + col) * 128 + kf);
        acc[nt] = __builtin_amdgcn_mfma_f32_16x16x32_bf16(afrag[s], b, acc[nt], 0, 0, 0);
      }
    }

    int nxt = tile + gridDim.x;
    bf8_t nfrag[4];
    bool has_next = (nxt < ntiles);
    if (has_next) {
      int r = nxt * 64 + wave * 16 + col; if (r >= M) r = M - 1;
      const unsigned short* p0 = zn_bf + (size_t)ci[r] * 64;
      const unsigned short* p1 = zn_bf + (size_t)cj[r] * 64;
      nfrag[0] = *(const bf8_t*)(p0 + quad * 8);
      nfrag[1] = *(const bf8_t*)(p0 + 32 + quad * 8);
      nfrag[2] = *(const bf8_t*)(p1 + quad * 8);
      nfrag[3] = *(const bf8_t*)(p1 + 32 + quad * 8);
    }

    #pragma unroll
    for (int nt = 0; nt < 8; ++nt) {
      float bs = b1[nt * 16 + col];
      #pragma unroll
      for (int r4 = 0; r4 < 4; ++r4)
        h1[quad * 4 + r4][nt * 16 + col] = f2bf(gelu_f(acc[nt][r4] + bs));
    }

    f4_t a2[8];
    #pragma unroll
    for (int nt = 0; nt < 8; ++nt) a2[nt] = (f4_t)0.f;
    #pragma unroll
    for (int s = 0; s < 4; ++s) {
      int kc = s * 32 + quad * 8;
      bf8_t a0 = *(const bf8_t*)&h1[col][kc];
      #pragma unroll
      for (int nt = 0; nt < 8; ++nt) {
        bf8_t b = *(const bf8_t*)(w2t + (size_t)(nt * 16 + col) * 128 + kc);
        a2[nt] = __builtin_amdgcn_mfma_f32_16x16x32_bf16(a0, b, a2[nt], 0, 0, 0);
      }
    }
    float p[4] = {0.f, 0.f, 0.f, 0.f};
    #pragma unroll
    for (int nt = 0; nt < 8; ++nt) {
      float bs = b2[nt * 16 + col];
      float wv = w3[nt * 16 + col];
      #pragma unroll
      for (int r4 = 0; r4 < 4; ++r4)
        p[r4] += gelu_f(a2[nt][r4] + bs) * wv;
    }
    #pragma unroll
    for (int r4 = 0; r4 < 4; ++r4) {
      float s = p[r4];
      s += __shfl_xor(s, 1, 64);
      s += __shfl_xor(s, 2, 64);
      s += __shfl_xor(s, 4, 64);
      s += __shfl_xor(s, 8, 64);
      if (col == 0) {
        int row = tile * 64 + wave * 16 + quad * 4 + r4;
        if (row < M) out[row] = __builtin_amdgcn_rcpf(1.0f + __expf(-(s + b3v)));
      }
    }

    if (has_next) {
      afrag[0] = nfrag[0]; afrag[1] = nfrag[1];
      afrag[2] = nfrag[2]; afrag[3] = nfrag[3];
    }
  }
}

// ---------------- launcher ----------------
extern "C" void kernel_launch(void* const* d_in, const int* in_sizes, int n_in,
                              void* d_out, int out_size, void* d_ws, size_t ws_size,
                              hipStream_t stream) {
  const float* x_res  = (const float*)d_in[0];
  const float* Wl     = (const float*)d_in[1];
  const float* bl     = (const float*)d_in[2];
  const float* Wr     = (const float*)d_in[3];
  const float* gn_w   = (const float*)d_in[4];
  const float* gn_b   = (const float*)d_in[5];
  const float* gn_ms  = (const float*)d_in[6];
  const float* dyt1_w = (const float*)d_in[7];
  const float* dyt1_b = (const float*)d_in[8];
  const float* dyt1_a = (const float*)d_in[9];
  const float* lin1_w = (const float*)d_in[10];
  const float* lin1_b = (const float*)d_in[11];
  const float* lin2_w = (const float*)d_in[12];
  const float* lin2_b = (const float*)d_in[13];
  const float* lin3_w = (const float*)d_in[14];
  const float* lin3_b = (const float*)d_in[15];
  const float* dyt2_w = (const float*)d_in[16];
  const float* dyt2_b = (const float*)d_in[17];
  const float* dyt2_a = (const float*)d_in[18];
  const float* adyt1_w = (const float*)d_in[19];
  const float* adyt1_b = (const float*)d_in[20];
  const float* adyt1_a = (const float*)d_in[21];
  const float* aa1_w  = (const float*)d_in[22];
  const float* aa1_b  = (const float*)d_in[23];
  const float* aa2_w  = (const float*)d_in[24];
  const float* aa2_b  = (const float*)d_in[25];
  const float* aa3_w  = (const float*)d_in[26];
  const float* aa3_b  = (const float*)d_in[27];
  const float* adyt2_w = (const float*)d_in[28];
  const float* adyt2_b = (const float*)d_in[29];
  const float* adyt2_a = (const float*)d_in[30];
  const float* aa4_w  = (const float*)d_in[31];
  const float* aa4_b  = (const float*)d_in[32];
  const float* c1_w   = (const float*)d_in[33];
  const float* c1_b   = (const float*)d_in[34];
  const float* c2_w   = (const float*)d_in[35];
  const float* c2_b   = (const float*)d_in[36];
  const float* c3_w   = (const float*)d_in[37];
  const float* c3_b   = (const float*)d_in[38];
  const int*   edge   = (const int*)d_in[39];
  const int*   contact = (const int*)d_in[40];

  const size_t N = (size_t)Nn;
  const size_t ws_floats = ws_size / 4;

  float* ws    = (float*)d_ws;
  float* rdeg  = ws;
  float* hbuf  = rdeg + N;
  unsigned short* z_bf  = (unsigned short*)(hbuf + 64 * N);
  unsigned short* zn_bf = z_bf + 192 * N;
  float* stats = (float*)(zn_bf + 64 * N);
  unsigned short* wt_sage = (unsigned short*)(stats + 256);
  unsigned short* wt_lin1 = wt_sage + 3 * 64 * 128;
  unsigned short* wt_lin2 = wt_lin1 + 256 * 192;
  unsigned short* wt_lin3 = wt_lin2 + 256 * 256;
  unsigned short* wt_aa1  = wt_lin3 + 64 * 256;
  unsigned short* wt_aa2  = wt_aa1 + 256 * 128;
  unsigned short* wt_aa3  = wt_aa2 + 256 * 256;
  unsigned short* wt_aa4  = wt_aa3 + 256 * 256;
  unsigned short* wt_c1   = wt_aa4 + 32 * 256;
  unsigned short* wt_c2   = wt_c1 + 128 * 128;
  unsigned short* wt_end  = wt_c2 + 128 * 128;
  float* pool  = (float*)((((uintptr_t)wt_end + 15) & ~(uintptr_t)15));
  const size_t persist = (size_t)(pool - ws);

  const size_t gnn_need = 32 * N + N + (N + 1) + N + (size_t)Ee + 256;
  if (ws_floats < persist + gnn_need) return;

  unsigned short* agg_bf = (unsigned short*)pool;
  int* cnt     = (int*)(pool + 32 * N);
  int* rowptr  = cnt + N;
  int* cursor  = rowptr + N + 1;
  int* colidx  = cursor + N;
  int* bsum    = colidx + Ee;

  const int* esrc = edge;
  const int* edst = edge + Ee;

  // ---- CSR build ----
  hipMemsetAsync(cnt, 0, N * sizeof(int), stream);
  k_degi<<<(Ee + 255) / 256, 256, 0, stream>>>(edst, cnt, Ee);
  k_rdeg<<<(Nn + 255) / 256, 256, 0, stream>>>(cnt, rdeg, Nn);
  const int nb = (Nn + 1023) / 1024;
  k_scan1<<<nb, 256, 0, stream>>>(cnt, cursor, bsum, Nn);
  k_scan2<<<1, 256, 0, stream>>>(bsum, nb);
  k_scan3<<<(Nn + 255) / 256, 256, 0, stream>>>(cursor, bsum, rowptr, cursor, Nn, Ee);
  k_fill<<<(Ee + 255) / 256, 256, 0, stream>>>(esrc, edst, cursor, colidx, Ee);

  // ---- weight prep ----
  k_wtsage<<<(3 * 64 * 128 + 255) / 256, 256, 0, stream>>>(Wl, Wr, wt_sage);
  // node-pipeline weights in blocked [(k>>5)*Np + n][k&31] layout
  k_wt3<<<(192 * 256 + 255) / 256, 256, 0, stream>>>(lin1_w, wt_lin1, 256, 256, 192 * 256);
  k_wt3<<<(256 * 256 + 255) / 256, 256, 0, stream>>>(lin2_w, wt_lin2, 256, 256, 256 * 256);
  k_wt3<<<(256 * 64 + 255) / 256, 256, 0, stream>>>(lin3_w, wt_lin3, 64, 64, 256 * 64);
  k_wt3<<<(128 * 256 + 255) / 256, 256, 0, stream>>>(aa1_w, wt_aa1, 256, 256, 128 * 256);
  k_wt3<<<(256 * 256 + 255) / 256, 256, 0, stream>>>(aa2_w, wt_aa2, 256, 256, 256 * 256);
  k_wt3<<<(256 * 256 + 255) / 256, 256, 0, stream>>>(aa3_w, wt_aa3, 256, 256, 256 * 256);
  k_wt3<<<(256 * 32 + 255) / 256, 256, 0, stream>>>(aa4_w, wt_aa4, 32, 20, 256 * 32);
  // edge-head weights keep the [n][k] layout
  k_wt2<<<(128 * 128 + 255) / 256, 256, 0, stream>>>(c1_w, wt_c1, 128, 128, 128 * 128);
  k_wt2<<<(128 * 128 + 255) / 256, 256, 0, stream>>>(c2_w, wt_c2, 128, 128, 128 * 128);

  // xb = bf16(x_res) in zn_bf slot
  k_cvt<<<(int)((N * 64 + 255) / 256), 256, 0, stream>>>(x_res, zn_bf, (int)(N * 64));

  // ---- GNN phase ----
  for (int l = 0; l < 3; ++l) {
    const unsigned short* xi = (l == 0) ? zn_bf : (z_bf + (size_t)(l - 1) * 64);
    int ldx = (l == 0) ? 64 : 192;
    hipMemsetAsync(stats, 0, 128 * sizeof(float), stream);
    k_gather<<<(Nn + 3) / 4, 256, 0, stream>>>(xi, ldx, rowptr, colidx, rdeg, agg_bf, Nn);
    mgemm<4><<<dim3((Nn + 127) / 128, 1), 256, 0, stream>>>(
        agg_bf, 64, xi, ldx, 64, 1,
        wt_sage + (size_t)l * 8192, bl + l * 64, hbuf, 64, 0, 1, Nn, 128, 64);
    k_stats<<<1024, 256, 0, stream>>>(hbuf, stats, Nn);
    k_statfin<<<1, 64, 0, stream>>>(stats, gn_ms + l * 64, Nn);
    k_norm<<<(Nn * 64) / 256, 256, 0, stream>>>(hbuf, stats, gn_w + l * 64, gn_b + l * 64,
                                                z_bf + (size_t)l * 64,
                                                (l > 0) ? (z_bf + (size_t)(l - 1) * 64) : nullptr, Nn);
  }

  // ---- block-cooperative fused node pipeline ----
  k_node<<<(Nn + 63) / 64, 256, 0, stream>>>(
      z_bf, x_res,
      dyt1_w, dyt1_b, dyt1_a, wt_lin1, lin1_b, wt_lin2, lin2_b, wt_lin3, lin3_b,
      dyt2_w, dyt2_b, dyt2_a,
      adyt1_w, adyt1_b, adyt1_a, wt_aa1, aa1_b, wt_aa2, aa2_b, wt_aa3, aa3_b,
      adyt2_w, adyt2_b, adyt2_a, wt_aa4, aa4_b,
      zn_bf, (float*)d_out, Nn);

  // ---- fused edge head ----
  float* eout = (float*)d_out + (size_t)Nn * 20;
  k_edge<<<2048, 256, 0, stream>>>(zn_bf, contact, contact + EPp,
      wt_c1, c1_b, wt_c2, c2_b, c3_w, c3_b, eout, EPp);
}

// Round 4
// 1543.163 us; speedup vs baseline: 1.2522x; 1.0025x over previous
//
#include <hip/hip_runtime.h>
#include <cstdint>
#include <cstddef>

// ---------------- problem constants ----------------
constexpr int Nn  = 200000;
constexpr int Ee  = 1600000;
constexpr int EPp = 1000000;

typedef __attribute__((ext_vector_type(8))) short bf8_t;
typedef __attribute__((ext_vector_type(4))) float f4_t;

__device__ inline unsigned short f2bf(float f) {
  union { float f; unsigned u; } v; v.f = f;
  unsigned r = v.u + 0x7FFFu + ((v.u >> 16) & 1u);
  return (unsigned short)(r >> 16);
}
__device__ inline float bf2f(unsigned short u) {
  union { unsigned u; float f; } v; v.u = ((unsigned)u) << 16;
  return v.f;
}
// tanh-form GELU, algebraically reduced: 0.5v(1+tanh(u)) = v*(1-r), r=1/(e^{2u}+1)
__device__ inline float gelu_f(float v) {
  float u = v * fmaf(0.0356774081f, v * v, 0.7978845608f);
  float r = __builtin_amdgcn_rcpf(__expf(u + u) + 1.0f);
  return fmaf(-v, r, v);
}
// dyt: w*tanh(a x)+b with s2 = 2*a prefolded: tanh = 1-2r
__device__ inline float dyt_f(float x, float s2, float w, float b) {
  float r = __builtin_amdgcn_rcpf(__expf(s2 * x) + 1.0f);
  return fmaf(w, fmaf(-2.0f, r, 1.0f), b);
}

// ---------------- degree / CSR build ----------------

__global__ __launch_bounds__(256) void k_degi(const int* __restrict__ dst,
                                              int* __restrict__ cnt, int E) {
  int i = blockIdx.x * 256 + threadIdx.x;
  if (i < E) atomicAdd(&cnt[dst[i]], 1);
}

__global__ __launch_bounds__(256) void k_rdeg(const int* __restrict__ cnt,
                                              float* __restrict__ rdeg, int n) {
  int i = blockIdx.x * 256 + threadIdx.x;
  if (i < n) rdeg[i] = 1.0f / (float)(cnt[i] > 1 ? cnt[i] : 1);
}

__global__ __launch_bounds__(256) void k_scan1(const int* __restrict__ in,
                                               int* __restrict__ out,
                                               int* __restrict__ bsum, int n) {
  __shared__ int sd[256];
  int t = threadIdx.x;
  int base = blockIdx.x * 1024 + t * 4;
  int v[4]; int ts = 0;
  #pragma unroll
  for (int j = 0; j < 4; ++j) { v[j] = (base + j < n) ? in[base + j] : 0; ts += v[j]; }
  sd[t] = ts; __syncthreads();
  for (int off = 1; off < 256; off <<= 1) {
    int x = (t >= off) ? sd[t - off] : 0;
    __syncthreads();
    sd[t] += x;
    __syncthreads();
  }
  int excl = sd[t] - ts;
  #pragma unroll
  for (int j = 0; j < 4; ++j) { if (base + j < n) out[base + j] = excl; excl += v[j]; }
  if (t == 255) bsum[blockIdx.x] = sd[255];
}

__global__ void k_scan2(int* bsum, int nb) {
  __shared__ int sd[256];
  int t = threadIdx.x;
  int v = (t < nb) ? bsum[t] : 0;
  sd[t] = v; __syncthreads();
  for (int off = 1; off < 256; off <<= 1) {
    int x = (t >= off) ? sd[t - off] : 0;
    __syncthreads();
    sd[t] += x;
    __syncthreads();
  }
  if (t < nb) bsum[t] = sd[t] - v;
}

__global__ __launch_bounds__(256) void k_scan3(const int* __restrict__ part,
                                               const int* __restrict__ bsum,
                                               int* __restrict__ rowptr,
                                               int* __restrict__ cursor,
                                               int n, int total) {
  int i = blockIdx.x * 256 + threadIdx.x;
  if (i == 0) rowptr[n] = total;
  if (i < n) { int v = part[i] + bsum[i >> 10]; rowptr[i] = v; cursor[i] = v; }
}

__global__ __launch_bounds__(256) void k_fill(const int* __restrict__ src,
                                              const int* __restrict__ dst,
                                              int* __restrict__ cursor,
                                              int* __restrict__ colidx, int E) {
  int e = blockIdx.x * 256 + threadIdx.x;
  if (e >= E) return;
  int pos = atomicAdd(&cursor[dst[e]], 1);
  colidx[pos] = src[e];
}

// gather-mean over bf16 features: one wave per node, 8 groups of 8 lanes
__global__ __launch_bounds__(256) void k_gather(const unsigned short* __restrict__ x, int ldx,
                                                const int* __restrict__ rowptr,
                                                const int* __restrict__ colidx,
                                                const float* __restrict__ rdeg,
                                                unsigned short* __restrict__ agg, int n) {
  int wave = threadIdx.x >> 6, lane = threadIdx.x & 63;
  int node = blockIdx.x * 4 + wave;
  if (node >= n) return;
  int grp = lane >> 3, c = (lane & 7) * 8;
  int r0 = rowptr[node], r1 = rowptr[node + 1];
  float s[8] = {0.f, 0.f, 0.f, 0.f, 0.f, 0.f, 0.f, 0.f};
  for (int j = r0 + grp; j < r1; j += 8) {
    bf8_t v = *(const bf8_t*)(x + (size_t)colidx[j] * ldx + c);
    #pragma unroll
    for (int jj = 0; jj < 8; ++jj) s[jj] += bf2f((unsigned short)v[jj]);
  }
  #pragma unroll
  for (int jj = 0; jj < 8; ++jj) {
    s[jj] += __shfl_xor(s[jj], 8, 64);
    s[jj] += __shfl_xor(s[jj], 16, 64);
    s[jj] += __shfl_xor(s[jj], 32, 64);
  }
  if (grp == 0) {
    float r = rdeg[node];
    bf8_t o;
    #pragma unroll
    for (int jj = 0; jj < 8; ++jj) o[jj] = (short)f2bf(s[jj] * r);
    *(bf8_t*)(agg + (size_t)node * 64 + c) = o;
  }
}

// ---------------- misc small kernels ----------------

__global__ __launch_bounds__(256) void k_cvt(const float* __restrict__ in,
                                             unsigned short* __restrict__ out, int n) {
  int i = blockIdx.x * 256 + threadIdx.x;
  if (i < n) out[i] = f2bf(in[i]);
}

__global__ __launch_bounds__(256) void k_wt2(const float* __restrict__ W,
                                             unsigned short* __restrict__ Wt,
                                             int K, int N, int total) {
  int i = blockIdx.x * 256 + threadIdx.x;
  if (i >= total) return;
  int n = i / K, k = i - n * K;
  float v = (n < N) ? W[(size_t)k * N + n] : 0.f;
  Wt[i] = f2bf(v);
}

// blocked layout for the node pipeline:
// Wt[((k>>5)*Np + n)*32 + (k&31)] = W[k][n]   (zero-padded for n >= Nr)
__global__ __launch_bounds__(256) void k_wt3(const float* __restrict__ W,
                                             unsigned short* __restrict__ Wt,
                                             int Np, int Nr, int total) {
  int i = blockIdx.x * 256 + threadIdx.x;
  if (i >= total) return;
  int kin = i & 31;
  int j = i >> 5;
  int n = j % Np, kb = j / Np;
  int k = kb * 32 + kin;
  float v = (n < Nr) ? W[(size_t)k * Nr + n] : 0.f;
  Wt[i] = f2bf(v);
}

__global__ __launch_bounds__(256) void k_wtsage(const float* __restrict__ Wl,
                                                const float* __restrict__ Wr,
                                                unsigned short* __restrict__ Wt) {
  int i = blockIdx.x * 256 + threadIdx.x;
  if (i >= 3 * 64 * 128) return;
  int l = i >> 13, r = i & 8191, n = r >> 7, k = r & 127;
  float v = (k < 64) ? Wl[l * 4096 + k * 64 + n] : Wr[l * 4096 + (k - 64) * 64 + n];
  Wt[i] = f2bf(v);
}

__global__ __launch_bounds__(256) void k_stats(const float* __restrict__ h,
                                               float* __restrict__ stats, int n) {
  int lane = threadIdx.x & 63, grp = threadIdx.x >> 6;
  float s = 0.f, s2 = 0.f;
  for (int r = blockIdx.x * 4 + grp; r < n; r += gridDim.x * 4) {
    float v = h[(size_t)r * 64 + lane];
    s += v; s2 += v * v;
  }
  __shared__ float l1[4][64], l2[4][64];
  l1[grp][lane] = s; l2[grp][lane] = s2;
  __syncthreads();
  if (grp == 0) {
    s  = l1[0][lane] + l1[1][lane] + l1[2][lane] + l1[3][lane];
    s2 = l2[0][lane] + l2[1][lane] + l2[2][lane] + l2[3][lane];
    atomicAdd(&stats[lane], s);
    atomicAdd(&stats[64 + lane], s2);
  }
}

__global__ void k_statfin(float* stats, const float* __restrict__ ms_, int n) {
  int d = threadIdx.x;
  if (d < 64) {
    float invn = 1.0f / (float)n;
    float m  = stats[d] * invn;
    float e2 = stats[64 + d] * invn;
    float ms = ms_[d];
    float var = e2 - (2.0f * ms - ms * ms) * m * m;
    stats[128 + d] = ms * m;
    stats[192 + d] = rsqrtf(var + 1e-5f);
  }
}

__global__ __launch_bounds__(256) void k_norm(const float* __restrict__ h,
                                              const float* __restrict__ stats,
                                              const float* __restrict__ w,
                                              const float* __restrict__ b,
                                              unsigned short* __restrict__ zcol,
                                              const unsigned short* __restrict__ prev, int n) {
  int i = blockIdx.x * 256 + threadIdx.x;
  if (i >= n * 64) return;
  int r = i >> 6, d = i & 63;
  float v = (h[i] - stats[128 + d]) * stats[192 + d] * w[d] + b[d];
  if (prev) v += bf2f(prev[(size_t)r * 192 + d]);
  zcol[(size_t)r * 192 + d] = f2bf(v);
}

// ---------------- generic bf16 MFMA GEMM (barrier-free, for SAGE) ----------------
template <int NT>
__global__ __launch_bounds__(256) void mgemm(
    const void* __restrict__ A1, int lda1,
    const void* __restrict__ A2, int lda2, int K1, int a_bf16,
    const unsigned short* __restrict__ Wt,
    const float* __restrict__ bias,
    void* __restrict__ Cout, int ldc, int c_bf16, int act,
    int M, int K, int N) {
  int lane = threadIdx.x & 63, wave = threadIdx.x >> 6;
  int quad = lane >> 4, col = lane & 15;
  int row0 = blockIdx.x * 128 + wave * 32;
  int n_base = blockIdx.y * NT * 16;

  f4_t acc[2][NT];
  #pragma unroll
  for (int mt = 0; mt < 2; ++mt)
    #pragma unroll
    for (int nt = 0; nt < NT; ++nt) acc[mt][nt] = (f4_t)0.f;

  int gm[2];
  gm[0] = row0 + col;      if (gm[0] >= M) gm[0] = M - 1;
  gm[1] = row0 + 16 + col; if (gm[1] >= M) gm[1] = M - 1;

  for (int kc0 = 0; kc0 < K; kc0 += 32) {
    int kc = kc0 + quad * 8;
    bf8_t a[2];
    #pragma unroll
    for (int mt = 0; mt < 2; ++mt) {
      const void* src; size_t off;
      if (kc < K1) { src = A1; off = (size_t)gm[mt] * lda1 + kc; }
      else         { src = A2; off = (size_t)gm[mt] * lda2 + kc - K1; }
      if (a_bf16) {
        a[mt] = *(const bf8_t*)((const unsigned short*)src + off);
      } else {
        const float* p = (const float*)src + off;
        float4 f0 = *(const float4*)p;
        float4 f1 = *(const float4*)(p + 4);
        float ff[8] = {f0.x, f0.y, f0.z, f0.w, f1.x, f1.y, f1.z, f1.w};
        #pragma unroll
        for (int j = 0; j < 8; ++j) a[mt][j] = (short)f2bf(ff[j]);
      }
    }
    #pragma unroll
    for (int nt = 0; nt < NT; ++nt) {
      bf8_t b = *(const bf8_t*)(Wt + (size_t)(n_base + nt * 16 + col) * K + kc);
      acc[0][nt] = __builtin_amdgcn_mfma_f32_16x16x32_bf16(a[0], b, acc[0][nt], 0, 0, 0);
      acc[1][nt] = __builtin_amdgcn_mfma_f32_16x16x32_bf16(a[1], b, acc[1][nt], 0, 0, 0);
    }
  }

  #pragma unroll
  for (int nt = 0; nt < NT; ++nt) {
    int n = n_base + nt * 16 + col;
    float bs = (bias && n < N) ? bias[n] : 0.f;
    #pragma unroll
    for (int mt = 0; mt < 2; ++mt)
      #pragma unroll
      for (int r = 0; r < 4; ++r) {
        int row = row0 + mt * 16 + quad * 4 + r;
        if (row >= M || n >= N) continue;
        float v = acc[mt][nt][r] + bs;
        if (act) v = gelu_f(v);
        if (c_bf16) ((unsigned short*)Cout)[(size_t)row * ldc + n] = f2bf(v);
        else        ((float*)Cout)[(size_t)row * ldc + n] = v;
      }
  }
}

// ---------------- block-cooperative fused node pipeline ----------------
// Block = 256 thr = 4 waves = 64 rows; wave w owns output cols [64w,64w+64).
// Block reads each weight once per 64 rows (1.9 GB L2 traffic total).
// __launch_bounds__(256,3): reg cap 170. Round-3's (256,4) cap of 128 forced
// the compiler to spill ~625 B/thread to scratch (+500 MB HBM round-trips:
// FETCH 255 MB / WRITE 413 MB at VGPR_Count=64+64 AGPR). At cap 170 the live
// set (64 AGPR acc + ~100 VGPR) fits; 12 waves/CU x 4-deep prefetch = 48KB
// in flight/CU still >> the ~11KB BW*latency product for the L2 weight
// stream, so the k-loop stays bandwidth-fed.
template <int K, bool DYT>
__device__ inline void node_gemm(unsigned short (*H)[264],
                                 const unsigned short* __restrict__ W,
                                 const float* __restrict__ bias,
                                 int wave, int quad, int col,
                                 const float* __restrict__ a2w,
                                 const float* __restrict__ a2b,
                                 const float* __restrict__ aal) {
  constexpr int KS = K >> 5;
  f4_t acc[4][4];
  #pragma unroll
  for (int mt = 0; mt < 4; ++mt)
    #pragma unroll
    for (int nt = 0; nt < 4; ++nt) acc[mt][nt] = (f4_t)0.f;

  // b(s,nt) at wp + (s*256 + nt*16)*32  (blocked layout, Np=256)
  const unsigned short* wp = W + (size_t)(wave * 64 + col) * 32 + quad * 8;
  bf8_t bc[4];
  #pragma unroll
  for (int nt = 0; nt < 4; ++nt)
    bc[nt] = *(const bf8_t*)(wp + (size_t)(nt * 16) * 32);

  #pragma unroll
  for (int s = 0; s < KS; ++s) {
    bf8_t am[4];
    #pragma unroll
    for (int mt = 0; mt < 4; ++mt)
      am[mt] = *(const bf8_t*)&H[mt * 16 + col][s * 32 + quad * 8];
    bf8_t bn[4];
    if (s + 1 < KS) {
      #pragma unroll
      for (int nt = 0; nt < 4; ++nt)
        bn[nt] = *(const bf8_t*)(wp + (size_t)((s + 1) * 256 + nt * 16) * 32);
    }
    #pragma unroll
    for (int nt = 0; nt < 4; ++nt)
      #pragma unroll
      for (int mt = 0; mt < 4; ++mt)
        acc[mt][nt] = __builtin_amdgcn_mfma_f32_16x16x32_bf16(am[mt], bc[nt], acc[mt][nt], 0, 0, 0);
    if (s + 1 < KS) {
      #pragma unroll
      for (int nt = 0; nt < 4; ++nt) bc[nt] = bn[nt];
    }
  }
  __syncthreads();   // all reads of H complete before epilogue writes
  float sa = DYT ? (2.0f * aal[0]) : 0.f;
  #pragma unroll
  for (int nt = 0; nt < 4; ++nt) {
    int n = wave * 64 + nt * 16 + col;
    float bs = bias[n];
    float w_ = DYT ? a2w[n] : 0.f;
    float b_ = DYT ? a2b[n] : 0.f;
    #pragma unroll
    for (int mt = 0; mt < 4; ++mt)
      #pragma unroll
      for (int r4 = 0; r4 < 4; ++r4) {
        float v = gelu_f(acc[mt][nt][r4] + bs);
        if (DYT) v = dyt_f(v, sa, w_, b_);
        H[mt * 16 + quad * 4 + r4][n] = f2bf(v);
      }
  }
  __syncthreads();
}

__global__ __launch_bounds__(256, 3) void k_node(
    const unsigned short* __restrict__ z_bf,
    const float* __restrict__ x_res,
    const float* __restrict__ d1w, const float* __restrict__ d1b, const float* __restrict__ d1a,
    const unsigned short* __restrict__ wt1, const float* __restrict__ b1,
    const unsigned short* __restrict__ wt2, const float* __restrict__ b2,
    const unsigned short* __restrict__ wt3, const float* __restrict__ b3,
    const float* __restrict__ d2w, const float* __restrict__ d2b, const float* __restrict__ d2a,
    const float* __restrict__ a1w, const float* __restrict__ a1b, const float* __restrict__ a1a,
    const unsigned short* __restrict__ wa1, const float* __restrict__ ba1,
    const unsigned short* __restrict__ wa2, const float* __restrict__ ba2,
    const unsigned short* __restrict__ wa3, const float* __restrict__ ba3,
    const float* __restrict__ a2w, const float* __restrict__ a2b, const float* __restrict__ a2a,
    const unsigned short* __restrict__ wa4, const float* __restrict__ ba4,
    unsigned short* __restrict__ zn_bf,
    float* __restrict__ out, int M) {
  __shared__ unsigned short H[64][264];   // 33.8 KB
  __shared__ float fscr[64 * 4 + 64];     // rownorm partials + inv norms
  int t = threadIdx.x;
  int lane = t & 63, wave = t >> 6;
  int quad = lane >> 4, col = lane & 15;
  int brow = blockIdx.x * 64;

  // ---- stage H = dyt1(z rows) ----
  {
    int row = t >> 2, part = t & 3;
    int gr = brow + row; if (gr >= M) gr = M - 1;
    const unsigned short* zp = z_bf + (size_t)gr * 192 + part * 48;
    float s1 = 2.0f * d1a[0];
    #pragma unroll
    for (int j = 0; j < 6; ++j) {
      bf8_t v = *(const bf8_t*)(zp + j * 8);
      int k0 = part * 48 + j * 8;
      #pragma unroll
      for (int jj = 0; jj < 8; ++jj) {
        float f = bf2f((unsigned short)v[jj]);
        v[jj] = (short)f2bf(dyt_f(f, s1, d1w[k0 + jj], d1b[k0 + jj]));
      }
      *(bf8_t*)&H[row][k0] = v;
    }
  }
  __syncthreads();

  // ---- lin1 (K=192), lin2 (K=256) ----
  node_gemm<192, false>(H, wt1, b1, wave, quad, col, nullptr, nullptr, nullptr);
  node_gemm<256, false>(H, wt2, b2, wave, quad, col, nullptr, nullptr, nullptr);

  // ---- lin3 (K=256, N=64; wave w owns n-tile w) + dyt2 + resid + rownorm + adyt1 ----
  {
    f4_t a3[4];
    #pragma unroll
    for (int mt = 0; mt < 4; ++mt) a3[mt] = (f4_t)0.f;
    const unsigned short* wp3 = wt3 + (size_t)(wave * 16 + col) * 32 + quad * 8;
    bf8_t bc = *(const bf8_t*)(wp3);
    #pragma unroll
    for (int s = 0; s < 8; ++s) {
      bf8_t am[4];
      #pragma unroll
      for (int mt = 0; mt < 4; ++mt)
        am[mt] = *(const bf8_t*)&H[mt * 16 + col][s * 32 + quad * 8];
      bf8_t bn;
      if (s + 1 < 8) bn = *(const bf8_t*)(wp3 + (size_t)((s + 1) * 64) * 32);
      #pragma unroll
      for (int mt = 0; mt < 4; ++mt)
        a3[mt] = __builtin_amdgcn_mfma_f32_16x16x32_bf16(am[mt], bc, a3[mt], 0, 0, 0);
      if (s + 1 < 8) bc = bn;
    }
    __syncthreads();                     // all lin3 reads of H complete
    // vv (fp32) overlaid into H's storage ([64][66] floats)
    float* fb = (float*)H;
    float s2d = 2.0f * d2a[0];
    int n = wave * 16 + col;
    float bsn = b3[n], wd = d2w[n], bd = d2b[n];
    #pragma unroll
    for (int mt = 0; mt < 4; ++mt)
      #pragma unroll
      for (int r4 = 0; r4 < 4; ++r4) {
        int row = mt * 16 + quad * 4 + r4;
        int gr = brow + row; if (gr >= M) gr = M - 1;
        float g = gelu_f(a3[mt][r4] + bsn);
        float x = x_res[(size_t)gr * 64 + n];
        fb[row * 66 + n] = dyt_f(g, s2d, wd, bd) + x;
      }
    __syncthreads();
    // each thread owns (row = t>>2, cols q*16..q*16+15): read to REGISTERS
    int row = t >> 2, q = t & 3;
    float vreg[16];
    float s2 = 0.f;
    #pragma unroll
    for (int c16 = 0; c16 < 16; ++c16) {
      vreg[c16] = fb[row * 66 + q * 16 + c16];
      s2 += vreg[c16] * vreg[c16];
    }
    fscr[row * 4 + q] = s2;
    __syncthreads();
    if (t < 64)
      fscr[256 + t] = 1.0f / (sqrtf(fscr[t * 4] + fscr[t * 4 + 1] + fscr[t * 4 + 2] + fscr[t * 4 + 3]) + 1e-10f);
    __syncthreads();                     // all fb reads complete; inv ready
    // write adyt1([x_res, zn]) into H (bf16 view) from registers; write zn_bf
    float sa1 = 2.0f * a1a[0];
    float inv = fscr[256 + row];
    int gr = brow + row;
    int grc = (gr >= M) ? (M - 1) : gr;
    #pragma unroll
    for (int c16 = 0; c16 < 16; ++c16) {
      int c = q * 16 + c16;
      float zv = vreg[c16] * inv;
      if (gr < M) zn_bf[(size_t)gr * 64 + c] = f2bf(zv);
      float x = x_res[(size_t)grc * 64 + c];
      H[row][64 + c] = f2bf(dyt_f(zv, sa1, a1w[64 + c], a1b[64 + c]));
      H[row][c]      = f2bf(dyt_f(x,  sa1, a1w[c],      a1b[c]));
    }
    __syncthreads();
  }

  // ---- aa1 (K=128), aa2 (K=256), aa3 (K=256, adyt2 epilogue) ----
  node_gemm<128, false>(H, wa1, ba1, wave, quad, col, nullptr, nullptr, nullptr);
  node_gemm<256, false>(H, wa2, ba2, wave, quad, col, nullptr, nullptr, nullptr);
  node_gemm<256, true >(H, wa3, ba3, wave, quad, col, a2w, a2b, a2a);

  // ---- aa4 (K=256, N=20 padded 32; wave w owns m-tile w) + log_softmax ----
  {
    f4_t a4[2];
    a4[0] = (f4_t)0.f; a4[1] = (f4_t)0.f;
    const unsigned short* wp4 = wa4 + (size_t)col * 32 + quad * 8;
    bf8_t bc[2];
    bc[0] = *(const bf8_t*)(wp4);
    bc[1] = *(const bf8_t*)(wp4 + (size_t)(16) * 32);
    #pragma unroll
    for (int s = 0; s < 8; ++s) {
      bf8_t am = *(const bf8_t*)&H[wave * 16 + col][s * 32 + quad * 8];
      bf8_t bn[2];
      if (s + 1 < 8) {
        bn[0] = *(const bf8_t*)(wp4 + (size_t)((s + 1) * 32) * 32);
        bn[1] = *(const bf8_t*)(wp4 + (size_t)((s + 1) * 32 + 16) * 32);
      }
      #pragma unroll
      for (int nt = 0; nt < 2; ++nt)
        a4[nt] = __builtin_amdgcn_mfma_f32_16x16x32_bf16(am, bc[nt], a4[nt], 0, 0, 0);
      if (s + 1 < 8) { bc[0] = bn[0]; bc[1] = bn[1]; }
    }
    float val[2][4];
    #pragma unroll
    for (int nt = 0; nt < 2; ++nt) {
      int n = nt * 16 + col;
      float bsv = (n < 20) ? ba4[n] : 0.f;
      #pragma unroll
      for (int r4 = 0; r4 < 4; ++r4) val[nt][r4] = a4[nt][r4] + bsv;
    }
    bool v1 = (col < 4);
    #pragma unroll
    for (int r4 = 0; r4 < 4; ++r4) {
      float m = val[0][r4];
      if (v1) m = fmaxf(m, val[1][r4]);
      m = fmaxf(m, __shfl_xor(m, 1, 64));
      m = fmaxf(m, __shfl_xor(m, 2, 64));
      m = fmaxf(m, __shfl_xor(m, 4, 64));
      m = fmaxf(m, __shfl_xor(m, 8, 64));
      float se = __expf(val[0][r4] - m) + (v1 ? __expf(val[1][r4] - m) : 0.f);
      se += __shfl_xor(se, 1, 64);
      se += __shfl_xor(se, 2, 64);
      se += __shfl_xor(se, 4, 64);
      se += __shfl_xor(se, 8, 64);
      float ls = __logf(se) + m;
      int row = brow + wave * 16 + quad * 4 + r4;
      if (row < M) {
        out[(size_t)row * 20 + col] = val[0][r4] - ls;
        if (v1) out[(size_t)row * 20 + 16 + col] = val[1][r4] - ls;
      }
    }
  }
}

// ---------------- fused edge head (prefetching, barrier-free) ----------------
__global__ __launch_bounds__(256) void k_edge(
    const unsigned short* __restrict__ zn_bf,
    const int* __restrict__ ci, const int* __restrict__ cj,
    const unsigned short* __restrict__ w1t, const float* __restrict__ b1,
    const unsigned short* __restrict__ w2t, const float* __restrict__ b2,
    const float* __restrict__ w3, const float* __restrict__ b3,
    float* __restrict__ out, int M) {
  __shared__ unsigned short h1s[4][16][136];
  int lane = threadIdx.x & 63, wave = threadIdx.x >> 6;
  int quad = lane >> 4, col = lane & 15;
  unsigned short (*h1)[136] = h1s[wave];
  int ntiles = (M + 63) >> 6;
  float b3v = b3[0];

  int tile = blockIdx.x;
  bf8_t afrag[4];
  if (tile < ntiles) {
    int r = tile * 64 + wave * 16 + col; if (r >= M) r = M - 1;
    const unsigned short* p0 = zn_bf + (size_t)ci[r] * 64;
    const unsigned short* p1 = zn_bf + (size_t)cj[r] * 64;
    afrag[0] = *(const bf8_t*)(p0 + quad * 8);
    afrag[1] = *(const bf8_t*)(p0 + 32 + quad * 8);
    afrag[2] = *(const bf8_t*)(p1 + quad * 8);
    afrag[3] = *(const bf8_t*)(p1 + 32 + quad * 8);
  }

  for (; tile < ntiles; tile += gridDim.x) {
    f4_t acc[8];
    #pragma unroll
    for (int nt = 0; nt < 8; ++nt) acc[nt] = (f4_t)0.f;
    #pragma unroll
    for (int s = 0; s < 4; ++s) {
      int kf = s * 32 + quad * 8;
      #pragma unroll
      for (int nt = 0; nt < 8; ++nt) {
        bf8_t b = *(const bf8_t*)(w1t + (size_t)(nt * 16 + col) * 128 + kf);
        acc[nt] = __builtin_amdgcn_mfma_f32_16x16x32_bf16(afrag[s], b, acc[nt], 0, 0, 0);
      }
    }

    int nxt = tile + gridDim.x;
    bf8_t nfrag[4];
    bool has_next = (nxt < ntiles);
    if (has_next) {
      int r = nxt * 64 + wave * 16 + col; if (r >= M) r = M - 1;
      const unsigned short* p0 = zn_bf + (size_t)ci[r] * 64;
      const unsigned short* p1 = zn_bf + (size_t)cj[r] * 64;
      nfrag[0] = *(const bf8_t*)(p0 + quad * 8);
      nfrag[1] = *(const bf8_t*)(p0 + 32 + quad * 8);
      nfrag[2] = *(const bf8_t*)(p1 + quad * 8);
      nfrag[3] = *(const bf8_t*)(p1 + 32 + quad * 8);
    }

    #pragma unroll
    for (int nt = 0; nt < 8; ++nt) {
      float bs = b1[nt * 16 + col];
      #pragma unroll
      for (int r4 = 0; r4 < 4; ++r4)
        h1[quad * 4 + r4][nt * 16 + col] = f2bf(gelu_f(acc[nt][r4] + bs));
    }

    f4_t a2[8];
    #pragma unroll
    for (int nt = 0; nt < 8; ++nt) a2[nt] = (f4_t)0.f;
    #pragma unroll
    for (int s = 0; s < 4; ++s) {
      int kc = s * 32 + quad * 8;
      bf8_t a0 = *(const bf8_t*)&h1[col][kc];
      #pragma unroll
      for (int nt = 0; nt < 8; ++nt) {
        bf8_t b = *(const bf8_t*)(w2t + (size_t)(nt * 16 + col) * 128 + kc);
        a2[nt] = __builtin_amdgcn_mfma_f32_16x16x32_bf16(a0, b, a2[nt], 0, 0, 0);
      }
    }
    float p[4] = {0.f, 0.f, 0.f, 0.f};
    #pragma unroll
    for (int nt = 0; nt < 8; ++nt) {
      float bs = b2[nt * 16 + col];
      float wv = w3[nt * 16 + col];
      #pragma unroll
      for (int r4 = 0; r4 < 4; ++r4)
        p[r4] += gelu_f(a2[nt][r4] + bs) * wv;
    }
    #pragma unroll
    for (int r4 = 0; r4 < 4; ++r4) {
      float s = p[r4];
      s += __shfl_xor(s, 1, 64);
      s += __shfl_xor(s, 2, 64);
      s += __shfl_xor(s, 4, 64);
      s += __shfl_xor(s, 8, 64);
      if (col == 0) {
        int row = tile * 64 + wave * 16 + quad * 4 + r4;
        if (row < M) out[row] = __builtin_amdgcn_rcpf(1.0f + __expf(-(s + b3v)));
      }
    }

    if (has_next) {
      afrag[0] = nfrag[0]; afrag[1] = nfrag[1];
      afrag[2] = nfrag[2]; afrag[3] = nfrag[3];
    }
  }
}

// ---------------- launcher ----------------
extern "C" void kernel_launch(void* const* d_in, const int* in_sizes, int n_in,
                              void* d_out, int out_size, void* d_ws, size_t ws_size,
                              hipStream_t stream) {
  const float* x_res  = (const float*)d_in[0];
  const float* Wl     = (const float*)d_in[1];
  const float* bl     = (const float*)d_in[2];
  const float* Wr     = (const float*)d_in[3];
  const float* gn_w   = (const float*)d_in[4];
  const float* gn_b   = (const float*)d_in[5];
  const float* gn_ms  = (const float*)d_in[6];
  const float* dyt1_w = (const float*)d_in[7];
  const float* dyt1_b = (const float*)d_in[8];
  const float* dyt1_a = (const float*)d_in[9];
  const float* lin1_w = (const float*)d_in[10];
  const float* lin1_b = (const float*)d_in[11];
  const float* lin2_w = (const float*)d_in[12];
  const float* lin2_b = (const float*)d_in[13];
  const float* lin3_w = (const float*)d_in[14];
  const float* lin3_b = (const float*)d_in[15];
  const float* dyt2_w = (const float*)d_in[16];
  const float* dyt2_b = (const float*)d_in[17];
  const float* dyt2_a = (const float*)d_in[18];
  const float* adyt1_w = (const float*)d_in[19];
  const float* adyt1_b = (const float*)d_in[20];
  const float* adyt1_a = (const float*)d_in[21];
  const float* aa1_w  = (const float*)d_in[22];
  const float* aa1_b  = (const float*)d_in[23];
  const float* aa2_w  = (const float*)d_in[24];
  const float* aa2_b  = (const float*)d_in[25];
  const float* aa3_w  = (const float*)d_in[26];
  const float* aa3_b  = (const float*)d_in[27];
  const float* adyt2_w = (const float*)d_in[28];
  const float* adyt2_b = (const float*)d_in[29];
  const float* adyt2_a = (const float*)d_in[30];
  const float* aa4_w  = (const float*)d_in[31];
  const float* aa4_b  = (const float*)d_in[32];
  const float* c1_w   = (const float*)d_in[33];
  const float* c1_b   = (const float*)d_in[34];
  const float* c2_w   = (const float*)d_in[35];
  const float* c2_b   = (const float*)d_in[36];
  const float* c3_w   = (const float*)d_in[37];
  const float* c3_b   = (const float*)d_in[38];
  const int*   edge   = (const int*)d_in[39];
  const int*   contact = (const int*)d_in[40];

  const size_t N = (size_t)Nn;
  const size_t ws_floats = ws_size / 4;

  float* ws    = (float*)d_ws;
  float* rdeg  = ws;
  float* hbuf  = rdeg + N;
  unsigned short* z_bf  = (unsigned short*)(hbuf + 64 * N);
  unsigned short* zn_bf = z_bf + 192 * N;
  float* stats = (float*)(zn_bf + 64 * N);
  unsigned short* wt_sage = (unsigned short*)(stats + 256);
  unsigned short* wt_lin1 = wt_sage + 3 * 64 * 128;
  unsigned short* wt_lin2 = wt_lin1 + 256 * 192;
  unsigned short* wt_lin3 = wt_lin2 + 256 * 256;
  unsigned short* wt_aa1  = wt_lin3 + 64 * 256;
  unsigned short* wt_aa2  = wt_aa1 + 256 * 128;
  unsigned short* wt_aa3  = wt_aa2 + 256 * 256;
  unsigned short* wt_aa4  = wt_aa3 + 256 * 256;
  unsigned short* wt_c1   = wt_aa4 + 32 * 256;
  unsigned short* wt_c2   = wt_c1 + 128 * 128;
  unsigned short* wt_end  = wt_c2 + 128 * 128;
  float* pool  = (float*)((((uintptr_t)wt_end + 15) & ~(uintptr_t)15));
  const size_t persist = (size_t)(pool - ws);

  const size_t gnn_need = 32 * N + N + (N + 1) + N + (size_t)Ee + 256;
  if (ws_floats < persist + gnn_need) return;

  unsigned short* agg_bf = (unsigned short*)pool;
  int* cnt     = (int*)(pool + 32 * N);
  int* rowptr  = cnt + N;
  int* cursor  = rowptr + N + 1;
  int* colidx  = cursor + N;
  int* bsum    = colidx + Ee;

  const int* esrc = edge;
  const int* edst = edge + Ee;

  // ---- CSR build ----
  hipMemsetAsync(cnt, 0, N * sizeof(int), stream);
  k_degi<<<(Ee + 255) / 256, 256, 0, stream>>>(edst, cnt, Ee);
  k_rdeg<<<(Nn + 255) / 256, 256, 0, stream>>>(cnt, rdeg, Nn);
  const int nb = (Nn + 1023) / 1024;
  k_scan1<<<nb, 256, 0, stream>>>(cnt, cursor, bsum, Nn);
  k_scan2<<<1, 256, 0, stream>>>(bsum, nb);
  k_scan3<<<(Nn + 255) / 256, 256, 0, stream>>>(cursor, bsum, rowptr, cursor, Nn, Ee);
  k_fill<<<(Ee + 255) / 256, 256, 0, stream>>>(esrc, edst, cursor, colidx, Ee);

  // ---- weight prep ----
  k_wtsage<<<(3 * 64 * 128 + 255) / 256, 256, 0, stream>>>(Wl, Wr, wt_sage);
  // node-pipeline weights in blocked [(k>>5)*Np + n][k&31] layout
  k_wt3<<<(192 * 256 + 255) / 256, 256, 0, stream>>>(lin1_w, wt_lin1, 256, 256, 192 * 256);
  k_wt3<<<(256 * 256 + 255) / 256, 256, 0, stream>>>(lin2_w, wt_lin2, 256, 256, 256 * 256);
  k_wt3<<<(256 * 64 + 255) / 256, 256, 0, stream>>>(lin3_w, wt_lin3, 64, 64, 256 * 64);
  k_wt3<<<(128 * 256 + 255) / 256, 256, 0, stream>>>(aa1_w, wt_aa1, 256, 256, 128 * 256);
  k_wt3<<<(256 * 256 + 255) / 256, 256, 0, stream>>>(aa2_w, wt_aa2, 256, 256, 256 * 256);
  k_wt3<<<(256 * 256 + 255) / 256, 256, 0, stream>>>(aa3_w, wt_aa3, 256, 256, 256 * 256);
  k_wt3<<<(256 * 32 + 255) / 256, 256, 0, stream>>>(aa4_w, wt_aa4, 32, 20, 256 * 32);
  // edge-head weights keep the [n][k] layout
  k_wt2<<<(128 * 128 + 255) / 256, 256, 0, stream>>>(c1_w, wt_c1, 128, 128, 128 * 128);
  k_wt2<<<(128 * 128 + 255) / 256, 256, 0, stream>>>(c2_w, wt_c2, 128, 128, 128 * 128);

  // xb = bf16(x_res) in zn_bf slot
  k_cvt<<<(int)((N * 64 + 255) / 256), 256, 0, stream>>>(x_res, zn_bf, (int)(N * 64));

  // ---- GNN phase ----
  for (int l = 0; l < 3; ++l) {
    const unsigned short* xi = (l == 0) ? zn_bf : (z_bf + (size_t)(l - 1) * 64);
    int ldx = (l == 0) ? 64 : 192;
    hipMemsetAsync(stats, 0, 128 * sizeof(float), stream);
    k_gather<<<(Nn + 3) / 4, 256, 0, stream>>>(xi, ldx, rowptr, colidx, rdeg, agg_bf, Nn);
    mgemm<4><<<dim3((Nn + 127) / 128, 1), 256, 0, stream>>>(
        agg_bf, 64, xi, ldx, 64, 1,
        wt_sage + (size_t)l * 8192, bl + l * 64, hbuf, 64, 0, 1, Nn, 128, 64);
    k_stats<<<1024, 256, 0, stream>>>(hbuf, stats, Nn);
    k_statfin<<<1, 64, 0, stream>>>(stats, gn_ms + l * 64, Nn);
    k_norm<<<(Nn * 64) / 256, 256, 0, stream>>>(hbuf, stats, gn_w + l * 64, gn_b + l * 64,
                                                z_bf + (size_t)l * 64,
                                                (l > 0) ? (z_bf + (size_t)(l - 1) * 64) : nullptr, Nn);
  }

  // ---- block-cooperative fused node pipeline ----
  k_node<<<(Nn + 63) / 64, 256, 0, stream>>>(
      z_bf, x_res,
      dyt1_w, dyt1_b, dyt1_a, wt_lin1, lin1_b, wt_lin2, lin2_b, wt_lin3, lin3_b,
      dyt2_w, dyt2_b, dyt2_a,
      adyt1_w, adyt1_b, adyt1_a, wt_aa1, aa1_b, wt_aa2, aa2_b, wt_aa3, aa3_b,
      adyt2_w, adyt2_b, adyt2_a, wt_aa4, aa4_b,
      zn_bf, (float*)d_out, Nn);

  // ---- fused edge head ----
  float* eout = (float*)d_out + (size_t)Nn * 20;
  k_edge<<<2048, 256, 0, stream>>>(zn_bf, contact, contact + EPp,
      wt_c1, c1_b, wt_c2, c2_b, c3_w, c3_b, eout, EPp);
}

// Round 5
// 1479.013 us; speedup vs baseline: 1.3065x; 1.0434x over previous
//
#include <hip/hip_runtime.h>
#include <cstdint>
#include <cstddef>

// ---------------- problem constants ----------------
constexpr int Nn  = 200000;
constexpr int Ee  = 1600000;
constexpr int EPp = 1000000;

typedef __attribute__((ext_vector_type(8))) short bf8_t;
typedef __attribute__((ext_vector_type(4))) float f4_t;

__device__ inline unsigned short f2bf(float f) {
  union { float f; unsigned u; } v; v.f = f;
  unsigned r = v.u + 0x7FFFu + ((v.u >> 16) & 1u);
  return (unsigned short)(r >> 16);
}
__device__ inline float bf2f(unsigned short u) {
  union { unsigned u; float f; } v; v.u = ((unsigned)u) << 16;
  return v.f;
}
// tanh-form GELU, algebraically reduced: 0.5v(1+tanh(u)) = v*(1-r), r=1/(e^{2u}+1)
__device__ inline float gelu_f(float v) {
  float u = v * fmaf(0.0356774081f, v * v, 0.7978845608f);
  float r = __builtin_amdgcn_rcpf(__expf(u + u) + 1.0f);
  return fmaf(-v, r, v);
}
// dyt: w*tanh(a x)+b with s2 = 2*a prefolded: tanh = 1-2r
__device__ inline float dyt_f(float x, float s2, float w, float b) {
  float r = __builtin_amdgcn_rcpf(__expf(s2 * x) + 1.0f);
  return fmaf(w, fmaf(-2.0f, r, 1.0f), b);
}

// ---------------- degree / CSR build ----------------

__global__ __launch_bounds__(256) void k_degi(const int* __restrict__ dst,
                                              int* __restrict__ cnt, int E) {
  int i = blockIdx.x * 256 + threadIdx.x;
  if (i < E) atomicAdd(&cnt[dst[i]], 1);
}

__global__ __launch_bounds__(256) void k_rdeg(const int* __restrict__ cnt,
                                              float* __restrict__ rdeg, int n) {
  int i = blockIdx.x * 256 + threadIdx.x;
  if (i < n) rdeg[i] = 1.0f / (float)(cnt[i] > 1 ? cnt[i] : 1);
}

__global__ __launch_bounds__(256) void k_scan1(const int* __restrict__ in,
                                               int* __restrict__ out,
                                               int* __restrict__ bsum, int n) {
  __shared__ int sd[256];
  int t = threadIdx.x;
  int base = blockIdx.x * 1024 + t * 4;
  int v[4]; int ts = 0;
  #pragma unroll
  for (int j = 0; j < 4; ++j) { v[j] = (base + j < n) ? in[base + j] : 0; ts += v[j]; }
  sd[t] = ts; __syncthreads();
  for (int off = 1; off < 256; off <<= 1) {
    int x = (t >= off) ? sd[t - off] : 0;
    __syncthreads();
    sd[t] += x;
    __syncthreads();
  }
  int excl = sd[t] - ts;
  #pragma unroll
  for (int j = 0; j < 4; ++j) { if (base + j < n) out[base + j] = excl; excl += v[j]; }
  if (t == 255) bsum[blockIdx.x] = sd[255];
}

__global__ void k_scan2(int* bsum, int nb) {
  __shared__ int sd[256];
  int t = threadIdx.x;
  int v = (t < nb) ? bsum[t] : 0;
  sd[t] = v; __syncthreads();
  for (int off = 1; off < 256; off <<= 1) {
    int x = (t >= off) ? sd[t - off] : 0;
    __syncthreads();
    sd[t] += x;
    __syncthreads();
  }
  if (t < nb) bsum[t] = sd[t] - v;
}

__global__ __launch_bounds__(256) void k_scan3(const int* __restrict__ part,
                                               const int* __restrict__ bsum,
                                               int* __restrict__ rowptr,
                                               int* __restrict__ cursor,
                                               int n, int total) {
  int i = blockIdx.x * 256 + threadIdx.x;
  if (i == 0) rowptr[n] = total;
  if (i < n) { int v = part[i] + bsum[i >> 10]; rowptr[i] = v; cursor[i] = v; }
}

__global__ __launch_bounds__(256) void k_fill(const int* __restrict__ src,
                                              const int* __restrict__ dst,
                                              int* __restrict__ cursor,
                                              int* __restrict__ colidx, int E) {
  int e = blockIdx.x * 256 + threadIdx.x;
  if (e >= E) return;
  int pos = atomicAdd(&cursor[dst[e]], 1);
  colidx[pos] = src[e];
}

// gather-mean over bf16 features: one wave per node, 8 groups of 8 lanes
__global__ __launch_bounds__(256) void k_gather(const unsigned short* __restrict__ x, int ldx,
                                                const int* __restrict__ rowptr,
                                                const int* __restrict__ colidx,
                                                const float* __restrict__ rdeg,
                                                unsigned short* __restrict__ agg, int n) {
  int wave = threadIdx.x >> 6, lane = threadIdx.x & 63;
  int node = blockIdx.x * 4 + wave;
  if (node >= n) return;
  int grp = lane >> 3, c = (lane & 7) * 8;
  int r0 = rowptr[node], r1 = rowptr[node + 1];
  float s[8] = {0.f, 0.f, 0.f, 0.f, 0.f, 0.f, 0.f, 0.f};
  for (int j = r0 + grp; j < r1; j += 8) {
    bf8_t v = *(const bf8_t*)(x + (size_t)colidx[j] * ldx + c);
    #pragma unroll
    for (int jj = 0; jj < 8; ++jj) s[jj] += bf2f((unsigned short)v[jj]);
  }
  #pragma unroll
  for (int jj = 0; jj < 8; ++jj) {
    s[jj] += __shfl_xor(s[jj], 8, 64);
    s[jj] += __shfl_xor(s[jj], 16, 64);
    s[jj] += __shfl_xor(s[jj], 32, 64);
  }
  if (grp == 0) {
    float r = rdeg[node];
    bf8_t o;
    #pragma unroll
    for (int jj = 0; jj < 8; ++jj) o[jj] = (short)f2bf(s[jj] * r);
    *(bf8_t*)(agg + (size_t)node * 64 + c) = o;
  }
}

// ---------------- misc small kernels ----------------

__global__ __launch_bounds__(256) void k_cvt(const float* __restrict__ in,
                                             unsigned short* __restrict__ out, int n) {
  int i = blockIdx.x * 256 + threadIdx.x;
  if (i < n) out[i] = f2bf(in[i]);
}

__global__ __launch_bounds__(256) void k_wt2(const float* __restrict__ W,
                                             unsigned short* __restrict__ Wt,
                                             int K, int N, int total) {
  int i = blockIdx.x * 256 + threadIdx.x;
  if (i >= total) return;
  int n = i / K, k = i - n * K;
  float v = (n < N) ? W[(size_t)k * N + n] : 0.f;
  Wt[i] = f2bf(v);
}

// blocked layout for the node pipeline:
// Wt[((k>>5)*Np + n)*32 + (k&31)] = W[k][n]   (zero-padded for n >= Nr)
__global__ __launch_bounds__(256) void k_wt3(const float* __restrict__ W,
                                             unsigned short* __restrict__ Wt,
                                             int Np, int Nr, int total) {
  int i = blockIdx.x * 256 + threadIdx.x;
  if (i >= total) return;
  int kin = i & 31;
  int j = i >> 5;
  int n = j % Np, kb = j / Np;
  int k = kb * 32 + kin;
  float v = (n < Nr) ? W[(size_t)k * Nr + n] : 0.f;
  Wt[i] = f2bf(v);
}

__global__ __launch_bounds__(256) void k_wtsage(const float* __restrict__ Wl,
                                                const float* __restrict__ Wr,
                                                unsigned short* __restrict__ Wt) {
  int i = blockIdx.x * 256 + threadIdx.x;
  if (i >= 3 * 64 * 128) return;
  int l = i >> 13, r = i & 8191, n = r >> 7, k = r & 127;
  float v = (k < 64) ? Wl[l * 4096 + k * 64 + n] : Wr[l * 4096 + (k - 64) * 64 + n];
  Wt[i] = f2bf(v);
}

__global__ __launch_bounds__(256) void k_stats(const float* __restrict__ h,
                                               float* __restrict__ stats, int n) {
  int lane = threadIdx.x & 63, grp = threadIdx.x >> 6;
  float s = 0.f, s2 = 0.f;
  for (int r = blockIdx.x * 4 + grp; r < n; r += gridDim.x * 4) {
    float v = h[(size_t)r * 64 + lane];
    s += v; s2 += v * v;
  }
  __shared__ float l1[4][64], l2[4][64];
  l1[grp][lane] = s; l2[grp][lane] = s2;
  __syncthreads();
  if (grp == 0) {
    s  = l1[0][lane] + l1[1][lane] + l1[2][lane] + l1[3][lane];
    s2 = l2[0][lane] + l2[1][lane] + l2[2][lane] + l2[3][lane];
    atomicAdd(&stats[lane], s);
    atomicAdd(&stats[64 + lane], s2);
  }
}

__global__ void k_statfin(float* stats, const float* __restrict__ ms_, int n) {
  int d = threadIdx.x;
  if (d < 64) {
    float invn = 1.0f / (float)n;
    float m  = stats[d] * invn;
    float e2 = stats[64 + d] * invn;
    float ms = ms_[d];
    float var = e2 - (2.0f * ms - ms * ms) * m * m;
    stats[128 + d] = ms * m;
    stats[192 + d] = rsqrtf(var + 1e-5f);
  }
}

__global__ __launch_bounds__(256) void k_norm(const float* __restrict__ h,
                                              const float* __restrict__ stats,
                                              const float* __restrict__ w,
                                              const float* __restrict__ b,
                                              unsigned short* __restrict__ zcol,
                                              const unsigned short* __restrict__ prev, int n) {
  int i = blockIdx.x * 256 + threadIdx.x;
  if (i >= n * 64) return;
  int r = i >> 6, d = i & 63;
  float v = (h[i] - stats[128 + d]) * stats[192 + d] * w[d] + b[d];
  if (prev) v += bf2f(prev[(size_t)r * 192 + d]);
  zcol[(size_t)r * 192 + d] = f2bf(v);
}

// ---------------- generic bf16 MFMA GEMM (barrier-free, for SAGE) ----------------
template <int NT>
__global__ __launch_bounds__(256) void mgemm(
    const void* __restrict__ A1, int lda1,
    const void* __restrict__ A2, int lda2, int K1, int a_bf16,
    const unsigned short* __restrict__ Wt,
    const float* __restrict__ bias,
    void* __restrict__ Cout, int ldc, int c_bf16, int act,
    int M, int K, int N) {
  int lane = threadIdx.x & 63, wave = threadIdx.x >> 6;
  int quad = lane >> 4, col = lane & 15;
  int row0 = blockIdx.x * 128 + wave * 32;
  int n_base = blockIdx.y * NT * 16;

  f4_t acc[2][NT];
  #pragma unroll
  for (int mt = 0; mt < 2; ++mt)
    #pragma unroll
    for (int nt = 0; nt < NT; ++nt) acc[mt][nt] = (f4_t)0.f;

  int gm[2];
  gm[0] = row0 + col;      if (gm[0] >= M) gm[0] = M - 1;
  gm[1] = row0 + 16 + col; if (gm[1] >= M) gm[1] = M - 1;

  for (int kc0 = 0; kc0 < K; kc0 += 32) {
    int kc = kc0 + quad * 8;
    bf8_t a[2];
    #pragma unroll
    for (int mt = 0; mt < 2; ++mt) {
      const void* src; size_t off;
      if (kc < K1) { src = A1; off = (size_t)gm[mt] * lda1 + kc; }
      else         { src = A2; off = (size_t)gm[mt] * lda2 + kc - K1; }
      if (a_bf16) {
        a[mt] = *(const bf8_t*)((const unsigned short*)src + off);
      } else {
        const float* p = (const float*)src + off;
        float4 f0 = *(const float4*)p;
        float4 f1 = *(const float4*)(p + 4);
        float ff[8] = {f0.x, f0.y, f0.z, f0.w, f1.x, f1.y, f1.z, f1.w};
        #pragma unroll
        for (int j = 0; j < 8; ++j) a[mt][j] = (short)f2bf(ff[j]);
      }
    }
    #pragma unroll
    for (int nt = 0; nt < NT; ++nt) {
      bf8_t b = *(const bf8_t*)(Wt + (size_t)(n_base + nt * 16 + col) * K + kc);
      acc[0][nt] = __builtin_amdgcn_mfma_f32_16x16x32_bf16(a[0], b, acc[0][nt], 0, 0, 0);
      acc[1][nt] = __builtin_amdgcn_mfma_f32_16x16x32_bf16(a[1], b, acc[1][nt], 0, 0, 0);
    }
  }

  #pragma unroll
  for (int nt = 0; nt < NT; ++nt) {
    int n = n_base + nt * 16 + col;
    float bs = (bias && n < N) ? bias[n] : 0.f;
    #pragma unroll
    for (int mt = 0; mt < 2; ++mt)
      #pragma unroll
      for (int r = 0; r < 4; ++r) {
        int row = row0 + mt * 16 + quad * 4 + r;
        if (row >= M || n >= N) continue;
        float v = acc[mt][nt][r] + bs;
        if (act) v = gelu_f(v);
        if (c_bf16) ((unsigned short*)Cout)[(size_t)row * ldc + n] = f2bf(v);
        else        ((float*)Cout)[(size_t)row * ldc + n] = v;
      }
  }
}

// ---------------- block-cooperative fused node pipeline ----------------
// Block = 256 thr = 4 waves = 64 rows; wave w owns output cols [64w,64w+64).
// Block reads each weight once per 64 rows (1.9 GB L2 traffic total).
// SPILL FIX (round 5): the k-loop carries `#pragma unroll 2` instead of full
// unroll. Full unroll let the scheduler hoist ALL weight loads (up to 128
// VGPRs of b-data) above the MFMAs -> guaranteed spill at any reasonable cap
// (rounds 2-4: 150-400 MB of scratch traffic). The loop back-edge bounds the
// live window to 2 iterations (32 VGPRs of b): 64 acc + 32 b + 16 am + misc
// fits the (256,3) cap of ~168 with no scratch.
template <int K, bool DYT>
__device__ inline void node_gemm(unsigned short (*H)[264],
                                 const unsigned short* __restrict__ W,
                                 const float* __restrict__ bias,
                                 int wave, int quad, int col,
                                 const float* __restrict__ a2w,
                                 const float* __restrict__ a2b,
                                 const float* __restrict__ aal) {
  constexpr int KS = K >> 5;
  f4_t acc[4][4];
  #pragma unroll
  for (int mt = 0; mt < 4; ++mt)
    #pragma unroll
    for (int nt = 0; nt < 4; ++nt) acc[mt][nt] = (f4_t)0.f;

  // b(s,nt) at wp + (s*256 + nt*16)*32  (blocked layout, Np=256)
  const unsigned short* wp = W + (size_t)(wave * 64 + col) * 32 + quad * 8;
  bf8_t bc[4];
  #pragma unroll
  for (int nt = 0; nt < 4; ++nt)
    bc[nt] = *(const bf8_t*)(wp + (size_t)(nt * 16) * 32);

  #pragma unroll 2
  for (int s = 0; s < KS; ++s) {
    bf8_t am[4];
    #pragma unroll
    for (int mt = 0; mt < 4; ++mt)
      am[mt] = *(const bf8_t*)&H[mt * 16 + col][s * 32 + quad * 8];
    bf8_t bn[4];
    if (s + 1 < KS) {
      #pragma unroll
      for (int nt = 0; nt < 4; ++nt)
        bn[nt] = *(const bf8_t*)(wp + (size_t)((s + 1) * 256 + nt * 16) * 32);
    }
    #pragma unroll
    for (int nt = 0; nt < 4; ++nt)
      #pragma unroll
      for (int mt = 0; mt < 4; ++mt)
        acc[mt][nt] = __builtin_amdgcn_mfma_f32_16x16x32_bf16(am[mt], bc[nt], acc[mt][nt], 0, 0, 0);
    if (s + 1 < KS) {
      #pragma unroll
      for (int nt = 0; nt < 4; ++nt) bc[nt] = bn[nt];
    }
  }
  __syncthreads();   // all reads of H complete before epilogue writes
  float sa = DYT ? (2.0f * aal[0]) : 0.f;
  #pragma unroll
  for (int nt = 0; nt < 4; ++nt) {
    int n = wave * 64 + nt * 16 + col;
    float bs = bias[n];
    float w_ = DYT ? a2w[n] : 0.f;
    float b_ = DYT ? a2b[n] : 0.f;
    #pragma unroll
    for (int mt = 0; mt < 4; ++mt)
      #pragma unroll
      for (int r4 = 0; r4 < 4; ++r4) {
        float v = gelu_f(acc[mt][nt][r4] + bs);
        if (DYT) v = dyt_f(v, sa, w_, b_);
        H[mt * 16 + quad * 4 + r4][n] = f2bf(v);
      }
  }
  __syncthreads();
}

__global__ __launch_bounds__(256, 3) void k_node(
    const unsigned short* __restrict__ z_bf,
    const float* __restrict__ x_res,
    const float* __restrict__ d1w, const float* __restrict__ d1b, const float* __restrict__ d1a,
    const unsigned short* __restrict__ wt1, const float* __restrict__ b1,
    const unsigned short* __restrict__ wt2, const float* __restrict__ b2,
    const unsigned short* __restrict__ wt3, const float* __restrict__ b3,
    const float* __restrict__ d2w, const float* __restrict__ d2b, const float* __restrict__ d2a,
    const float* __restrict__ a1w, const float* __restrict__ a1b, const float* __restrict__ a1a,
    const unsigned short* __restrict__ wa1, const float* __restrict__ ba1,
    const unsigned short* __restrict__ wa2, const float* __restrict__ ba2,
    const unsigned short* __restrict__ wa3, const float* __restrict__ ba3,
    const float* __restrict__ a2w, const float* __restrict__ a2b, const float* __restrict__ a2a,
    const unsigned short* __restrict__ wa4, const float* __restrict__ ba4,
    unsigned short* __restrict__ zn_bf,
    float* __restrict__ out, int M) {
  __shared__ unsigned short H[64][264];   // 33.8 KB
  __shared__ float fscr[64 * 4 + 64];     // rownorm partials + inv norms
  int t = threadIdx.x;
  int lane = t & 63, wave = t >> 6;
  int quad = lane >> 4, col = lane & 15;
  int brow = blockIdx.x * 64;

  // ---- stage H = dyt1(z rows) ----
  {
    int row = t >> 2, part = t & 3;
    int gr = brow + row; if (gr >= M) gr = M - 1;
    const unsigned short* zp = z_bf + (size_t)gr * 192 + part * 48;
    float s1 = 2.0f * d1a[0];
    #pragma unroll
    for (int j = 0; j < 6; ++j) {
      bf8_t v = *(const bf8_t*)(zp + j * 8);
      int k0 = part * 48 + j * 8;
      #pragma unroll
      for (int jj = 0; jj < 8; ++jj) {
        float f = bf2f((unsigned short)v[jj]);
        v[jj] = (short)f2bf(dyt_f(f, s1, d1w[k0 + jj], d1b[k0 + jj]));
      }
      *(bf8_t*)&H[row][k0] = v;
    }
  }
  __syncthreads();

  // ---- lin1 (K=192), lin2 (K=256) ----
  node_gemm<192, false>(H, wt1, b1, wave, quad, col, nullptr, nullptr, nullptr);
  node_gemm<256, false>(H, wt2, b2, wave, quad, col, nullptr, nullptr, nullptr);

  // ---- lin3 (K=256, N=64; wave w owns n-tile w) + dyt2 + resid + rownorm + adyt1 ----
  {
    f4_t a3[4];
    #pragma unroll
    for (int mt = 0; mt < 4; ++mt) a3[mt] = (f4_t)0.f;
    const unsigned short* wp3 = wt3 + (size_t)(wave * 16 + col) * 32 + quad * 8;
    bf8_t bc = *(const bf8_t*)(wp3);
    #pragma unroll 2
    for (int s = 0; s < 8; ++s) {
      bf8_t am[4];
      #pragma unroll
      for (int mt = 0; mt < 4; ++mt)
        am[mt] = *(const bf8_t*)&H[mt * 16 + col][s * 32 + quad * 8];
      bf8_t bn;
      if (s + 1 < 8) bn = *(const bf8_t*)(wp3 + (size_t)((s + 1) * 64) * 32);
      #pragma unroll
      for (int mt = 0; mt < 4; ++mt)
        a3[mt] = __builtin_amdgcn_mfma_f32_16x16x32_bf16(am[mt], bc, a3[mt], 0, 0, 0);
      if (s + 1 < 8) bc = bn;
    }
    __syncthreads();                     // all lin3 reads of H complete
    // vv (fp32) overlaid into H's storage ([64][66] floats)
    float* fb = (float*)H;
    float s2d = 2.0f * d2a[0];
    int n = wave * 16 + col;
    float bsn = b3[n], wd = d2w[n], bd = d2b[n];
    #pragma unroll
    for (int mt = 0; mt < 4; ++mt)
      #pragma unroll
      for (int r4 = 0; r4 < 4; ++r4) {
        int row = mt * 16 + quad * 4 + r4;
        int gr = brow + row; if (gr >= M) gr = M - 1;
        float g = gelu_f(a3[mt][r4] + bsn);
        float x = x_res[(size_t)gr * 64 + n];
        fb[row * 66 + n] = dyt_f(g, s2d, wd, bd) + x;
      }
    __syncthreads();
    // each thread owns (row = t>>2, cols q*16..q*16+15): read to REGISTERS
    int row = t >> 2, q = t & 3;
    float vreg[16];
    float s2 = 0.f;
    #pragma unroll
    for (int c16 = 0; c16 < 16; ++c16) {
      vreg[c16] = fb[row * 66 + q * 16 + c16];
      s2 += vreg[c16] * vreg[c16];
    }
    fscr[row * 4 + q] = s2;
    __syncthreads();
    if (t < 64)
      fscr[256 + t] = 1.0f / (sqrtf(fscr[t * 4] + fscr[t * 4 + 1] + fscr[t * 4 + 2] + fscr[t * 4 + 3]) + 1e-10f);
    __syncthreads();                     // all fb reads complete; inv ready
    // write adyt1([x_res, zn]) into H (bf16 view) from registers; write zn_bf
    float sa1 = 2.0f * a1a[0];
    float inv = fscr[256 + row];
    int gr = brow + row;
    int grc = (gr >= M) ? (M - 1) : gr;
    #pragma unroll
    for (int c16 = 0; c16 < 16; ++c16) {
      int c = q * 16 + c16;
      float zv = vreg[c16] * inv;
      if (gr < M) zn_bf[(size_t)gr * 64 + c] = f2bf(zv);
      float x = x_res[(size_t)grc * 64 + c];
      H[row][64 + c] = f2bf(dyt_f(zv, sa1, a1w[64 + c], a1b[64 + c]));
      H[row][c]      = f2bf(dyt_f(x,  sa1, a1w[c],      a1b[c]));
    }
    __syncthreads();
  }

  // ---- aa1 (K=128), aa2 (K=256), aa3 (K=256, adyt2 epilogue) ----
  node_gemm<128, false>(H, wa1, ba1, wave, quad, col, nullptr, nullptr, nullptr);
  node_gemm<256, false>(H, wa2, ba2, wave, quad, col, nullptr, nullptr, nullptr);
  node_gemm<256, true >(H, wa3, ba3, wave, quad, col, a2w, a2b, a2a);

  // ---- aa4 (K=256, N=20 padded 32; wave w owns m-tile w) + log_softmax ----
  {
    f4_t a4[2];
    a4[0] = (f4_t)0.f; a4[1] = (f4_t)0.f;
    const unsigned short* wp4 = wa4 + (size_t)col * 32 + quad * 8;
    bf8_t bc[2];
    bc[0] = *(const bf8_t*)(wp4);
    bc[1] = *(const bf8_t*)(wp4 + (size_t)(16) * 32);
    #pragma unroll 2
    for (int s = 0; s < 8; ++s) {
      bf8_t am = *(const bf8_t*)&H[wave * 16 + col][s * 32 + quad * 8];
      bf8_t bn[2];
      if (s + 1 < 8) {
        bn[0] = *(const bf8_t*)(wp4 + (size_t)((s + 1) * 32) * 32);
        bn[1] = *(const bf8_t*)(wp4 + (size_t)((s + 1) * 32 + 16) * 32);
      }
      #pragma unroll
      for (int nt = 0; nt < 2; ++nt)
        a4[nt] = __builtin_amdgcn_mfma_f32_16x16x32_bf16(am, bc[nt], a4[nt], 0, 0, 0);
      if (s + 1 < 8) { bc[0] = bn[0]; bc[1] = bn[1]; }
    }
    float val[2][4];
    #pragma unroll
    for (int nt = 0; nt < 2; ++nt) {
      int n = nt * 16 + col;
      float bsv = (n < 20) ? ba4[n] : 0.f;
      #pragma unroll
      for (int r4 = 0; r4 < 4; ++r4) val[nt][r4] = a4[nt][r4] + bsv;
    }
    bool v1 = (col < 4);
    #pragma unroll
    for (int r4 = 0; r4 < 4; ++r4) {
      float m = val[0][r4];
      if (v1) m = fmaxf(m, val[1][r4]);
      m = fmaxf(m, __shfl_xor(m, 1, 64));
      m = fmaxf(m, __shfl_xor(m, 2, 64));
      m = fmaxf(m, __shfl_xor(m, 4, 64));
      m = fmaxf(m, __shfl_xor(m, 8, 64));
      float se = __expf(val[0][r4] - m) + (v1 ? __expf(val[1][r4] - m) : 0.f);
      se += __shfl_xor(se, 1, 64);
      se += __shfl_xor(se, 2, 64);
      se += __shfl_xor(se, 4, 64);
      se += __shfl_xor(se, 8, 64);
      float ls = __logf(se) + m;
      int row = brow + wave * 16 + quad * 4 + r4;
      if (row < M) {
        out[(size_t)row * 20 + col] = val[0][r4] - ls;
        if (v1) out[(size_t)row * 20 + 16 + col] = val[1][r4] - ls;
      }
    }
  }
}

// ---------------- fused edge head (prefetching, barrier-free) ----------------
__global__ __launch_bounds__(256) void k_edge(
    const unsigned short* __restrict__ zn_bf,
    const int* __restrict__ ci, const int* __restrict__ cj,
    const unsigned short* __restrict__ w1t, const float* __restrict__ b1,
    const unsigned short* __restrict__ w2t, const float* __restrict__ b2,
    const float* __restrict__ w3, const float* __restrict__ b3,
    float* __restrict__ out, int M) {
  __shared__ unsigned short h1s[4][16][136];
  int lane = threadIdx.x & 63, wave = threadIdx.x >> 6;
  int quad = lane >> 4, col = lane & 15;
  unsigned short (*h1)[136] = h1s[wave];
  int ntiles = (M + 63) >> 6;
  float b3v = b3[0];

  int tile = blockIdx.x;
  bf8_t afrag[4];
  if (tile < ntiles) {
    int r = tile * 64 + wave * 16 + col; if (r >= M) r = M - 1;
    const unsigned short* p0 = zn_bf + (size_t)ci[r] * 64;
    const unsigned short* p1 = zn_bf + (size_t)cj[r] * 64;
    afrag[0] = *(const bf8_t*)(p0 + quad * 8);
    afrag[1] = *(const bf8_t*)(p0 + 32 + quad * 8);
    afrag[2] = *(const bf8_t*)(p1 + quad * 8);
    afrag[3] = *(const bf8_t*)(p1 + 32 + quad * 8);
  }

  for (; tile < ntiles; tile += gridDim.x) {
    f4_t acc[8];
    #pragma unroll
    for (int nt = 0; nt < 8; ++nt) acc[nt] = (f4_t)0.f;
    #pragma unroll
    for (int s = 0; s < 4; ++s) {
      int kf = s * 32 + quad * 8;
      #pragma unroll
      for (int nt = 0; nt < 8; ++nt) {
        bf8_t b = *(const bf8_t*)(w1t + (size_t)(nt * 16 + col) * 128 + kf);
        acc[nt] = __builtin_amdgcn_mfma_f32_16x16x32_bf16(afrag[s], b, acc[nt], 0, 0, 0);
      }
    }

    int nxt = tile + gridDim.x;
    bf8_t nfrag[4];
    bool has_next = (nxt < ntiles);
    if (has_next) {
      int r = nxt * 64 + wave * 16 + col; if (r >= M) r = M - 1;
      const unsigned short* p0 = zn_bf + (size_t)ci[r] * 64;
      const unsigned short* p1 = zn_bf + (size_t)cj[r] * 64;
      nfrag[0] = *(const bf8_t*)(p0 + quad * 8);
      nfrag[1] = *(const bf8_t*)(p0 + 32 + quad * 8);
      nfrag[2] = *(const bf8_t*)(p1 + quad * 8);
      nfrag[3] = *(const bf8_t*)(p1 + 32 + quad * 8);
    }

    #pragma unroll
    for (int nt = 0; nt < 8; ++nt) {
      float bs = b1[nt * 16 + col];
      #pragma unroll
      for (int r4 = 0; r4 < 4; ++r4)
        h1[quad * 4 + r4][nt * 16 + col] = f2bf(gelu_f(acc[nt][r4] + bs));
    }

    f4_t a2[8];
    #pragma unroll
    for (int nt = 0; nt < 8; ++nt) a2[nt] = (f4_t)0.f;
    #pragma unroll
    for (int s = 0; s < 4; ++s) {
      int kc = s * 32 + quad * 8;
      bf8_t a0 = *(const bf8_t*)&h1[col][kc];
      #pragma unroll
      for (int nt = 0; nt < 8; ++nt) {
        bf8_t b = *(const bf8_t*)(w2t + (size_t)(nt * 16 + col) * 128 + kc);
        a2[nt] = __builtin_amdgcn_mfma_f32_16x16x32_bf16(a0, b, a2[nt], 0, 0, 0);
      }
    }
    float p[4] = {0.f, 0.f, 0.f, 0.f};
    #pragma unroll
    for (int nt = 0; nt < 8; ++nt) {
      float bs = b2[nt * 16 + col];
      float wv = w3[nt * 16 + col];
      #pragma unroll
      for (int r4 = 0; r4 < 4; ++r4)
        p[r4] += gelu_f(a2[nt][r4] + bs) * wv;
    }
    #pragma unroll
    for (int r4 = 0; r4 < 4; ++r4) {
      float s = p[r4];
      s += __shfl_xor(s, 1, 64);
      s += __shfl_xor(s, 2, 64);
      s += __shfl_xor(s, 4, 64);
      s += __shfl_xor(s, 8, 64);
      if (col == 0) {
        int row = tile * 64 + wave * 16 + quad * 4 + r4;
        if (row < M) out[row] = __builtin_amdgcn_rcpf(1.0f + __expf(-(s + b3v)));
      }
    }

    if (has_next) {
      afrag[0] = nfrag[0]; afrag[1] = nfrag[1];
      afrag[2] = nfrag[2]; afrag[3] = nfrag[3];
    }
  }
}

// ---------------- launcher ----------------
extern "C" void kernel_launch(void* const* d_in, const int* in_sizes, int n_in,
                              void* d_out, int out_size, void* d_ws, size_t ws_size,
                              hipStream_t stream) {
  const float* x_res  = (const float*)d_in[0];
  const float* Wl     = (const float*)d_in[1];
  const float* bl     = (const float*)d_in[2];
  const float* Wr     = (const float*)d_in[3];
  const float* gn_w   = (const float*)d_in[4];
  const float* gn_b   = (const float*)d_in[5];
  const float* gn_ms  = (const float*)d_in[6];
  const float* dyt1_w = (const float*)d_in[7];
  const float* dyt1_b = (const float*)d_in[8];
  const float* dyt1_a = (const float*)d_in[9];
  const float* lin1_w = (const float*)d_in[10];
  const float* lin1_b = (const float*)d_in[11];
  const float* lin2_w = (const float*)d_in[12];
  const float* lin2_b = (const float*)d_in[13];
  const float* lin3_w = (const float*)d_in[14];
  const float* lin3_b = (const float*)d_in[15];
  const float* dyt2_w = (const float*)d_in[16];
  const float* dyt2_b = (const float*)d_in[17];
  const float* dyt2_a = (const float*)d_in[18];
  const float* adyt1_w = (const float*)d_in[19];
  const float* adyt1_b = (const float*)d_in[20];
  const float* adyt1_a = (const float*)d_in[21];
  const float* aa1_w  = (const float*)d_in[22];
  const float* aa1_b  = (const float*)d_in[23];
  const float* aa2_w  = (const float*)d_in[24];
  const float* aa2_b  = (const float*)d_in[25];
  const float* aa3_w  = (const float*)d_in[26];
  const float* aa3_b  = (const float*)d_in[27];
  const float* adyt2_w = (const float*)d_in[28];
  const float* adyt2_b = (const float*)d_in[29];
  const float* adyt2_a = (const float*)d_in[30];
  const float* aa4_w  = (const float*)d_in[31];
  const float* aa4_b  = (const float*)d_in[32];
  const float* c1_w   = (const float*)d_in[33];
  const float* c1_b   = (const float*)d_in[34];
  const float* c2_w   = (const float*)d_in[35];
  const float* c2_b   = (const float*)d_in[36];
  const float* c3_w   = (const float*)d_in[37];
  const float* c3_b   = (const float*)d_in[38];
  const int*   edge   = (const int*)d_in[39];
  const int*   contact = (const int*)d_in[40];

  const size_t N = (size_t)Nn;
  const size_t ws_floats = ws_size / 4;

  float* ws    = (float*)d_ws;
  float* rdeg  = ws;
  float* hbuf  = rdeg + N;
  unsigned short* z_bf  = (unsigned short*)(hbuf + 64 * N);
  unsigned short* zn_bf = z_bf + 192 * N;
  float* stats = (float*)(zn_bf + 64 * N);
  unsigned short* wt_sage = (unsigned short*)(stats + 256);
  unsigned short* wt_lin1 = wt_sage + 3 * 64 * 128;
  unsigned short* wt_lin2 = wt_lin1 + 256 * 192;
  unsigned short* wt_lin3 = wt_lin2 + 256 * 256;
  unsigned short* wt_aa1  = wt_lin3 + 64 * 256;
  unsigned short* wt_aa2  = wt_aa1 + 256 * 128;
  unsigned short* wt_aa3  = wt_aa2 + 256 * 256;
  unsigned short* wt_aa4  = wt_aa3 + 256 * 256;
  unsigned short* wt_c1   = wt_aa4 + 32 * 256;
  unsigned short* wt_c2   = wt_c1 + 128 * 128;
  unsigned short* wt_end  = wt_c2 + 128 * 128;
  float* pool  = (float*)((((uintptr_t)wt_end + 15) & ~(uintptr_t)15));
  const size_t persist = (size_t)(pool - ws);

  const size_t gnn_need = 32 * N + N + (N + 1) + N + (size_t)Ee + 256;
  if (ws_floats < persist + gnn_need) return;

  unsigned short* agg_bf = (unsigned short*)pool;
  int* cnt     = (int*)(pool + 32 * N);
  int* rowptr  = cnt + N;
  int* cursor  = rowptr + N + 1;
  int* colidx  = cursor + N;
  int* bsum    = colidx + Ee;

  const int* esrc = edge;
  const int* edst = edge + Ee;

  // ---- CSR build ----
  hipMemsetAsync(cnt, 0, N * sizeof(int), stream);
  k_degi<<<(Ee + 255) / 256, 256, 0, stream>>>(edst, cnt, Ee);
  k_rdeg<<<(Nn + 255) / 256, 256, 0, stream>>>(cnt, rdeg, Nn);
  const int nb = (Nn + 1023) / 1024;
  k_scan1<<<nb, 256, 0, stream>>>(cnt, cursor, bsum, Nn);
  k_scan2<<<1, 256, 0, stream>>>(bsum, nb);
  k_scan3<<<(Nn + 255) / 256, 256, 0, stream>>>(cursor, bsum, rowptr, cursor, Nn, Ee);
  k_fill<<<(Ee + 255) / 256, 256, 0, stream>>>(esrc, edst, cursor, colidx, Ee);

  // ---- weight prep ----
  k_wtsage<<<(3 * 64 * 128 + 255) / 256, 256, 0, stream>>>(Wl, Wr, wt_sage);
  // node-pipeline weights in blocked [(k>>5)*Np + n][k&31] layout
  k_wt3<<<(192 * 256 + 255) / 256, 256, 0, stream>>>(lin1_w, wt_lin1, 256, 256, 192 * 256);
  k_wt3<<<(256 * 256 + 255) / 256, 256, 0, stream>>>(lin2_w, wt_lin2, 256, 256, 256 * 256);
  k_wt3<<<(256 * 64 + 255) / 256, 256, 0, stream>>>(lin3_w, wt_lin3, 64, 64, 256 * 64);
  k_wt3<<<(128 * 256 + 255) / 256, 256, 0, stream>>>(aa1_w, wt_aa1, 256, 256, 128 * 256);
  k_wt3<<<(256 * 256 + 255) / 256, 256, 0, stream>>>(aa2_w, wt_aa2, 256, 256, 256 * 256);
  k_wt3<<<(256 * 256 + 255) / 256, 256, 0, stream>>>(aa3_w, wt_aa3, 256, 256, 256 * 256);
  k_wt3<<<(256 * 32 + 255) / 256, 256, 0, stream>>>(aa4_w, wt_aa4, 32, 20, 256 * 32);
  // edge-head weights keep the [n][k] layout
  k_wt2<<<(128 * 128 + 255) / 256, 256, 0, stream>>>(c1_w, wt_c1, 128, 128, 128 * 128);
  k_wt2<<<(128 * 128 + 255) / 256, 256, 0, stream>>>(c2_w, wt_c2, 128, 128, 128 * 128);

  // xb = bf16(x_res) in zn_bf slot
  k_cvt<<<(int)((N * 64 + 255) / 256), 256, 0, stream>>>(x_res, zn_bf, (int)(N * 64));

  // ---- GNN phase ----
  for (int l = 0; l < 3; ++l) {
    const unsigned short* xi = (l == 0) ? zn_bf : (z_bf + (size_t)(l - 1) * 64);
    int ldx = (l == 0) ? 64 : 192;
    hipMemsetAsync(stats, 0, 128 * sizeof(float), stream);
    k_gather<<<(Nn + 3) / 4, 256, 0, stream>>>(xi, ldx, rowptr, colidx, rdeg, agg_bf, Nn);
    mgemm<4><<<dim3((Nn + 127) / 128, 1), 256, 0, stream>>>(
        agg_bf, 64, xi, ldx, 64, 1,
        wt_sage + (size_t)l * 8192, bl + l * 64, hbuf, 64, 0, 1, Nn, 128, 64);
    k_stats<<<1024, 256, 0, stream>>>(hbuf, stats, Nn);
    k_statfin<<<1, 64, 0, stream>>>(stats, gn_ms + l * 64, Nn);
    k_norm<<<(Nn * 64) / 256, 256, 0, stream>>>(hbuf, stats, gn_w + l * 64, gn_b + l * 64,
                                                z_bf + (size_t)l * 64,
                                                (l > 0) ? (z_bf + (size_t)(l - 1) * 64) : nullptr, Nn);
  }

  // ---- block-cooperative fused node pipeline ----
  k_node<<<(Nn + 63) / 64, 256, 0, stream>>>(
      z_bf, x_res,
      dyt1_w, dyt1_b, dyt1_a, wt_lin1, lin1_b, wt_lin2, lin2_b, wt_lin3, lin3_b,
      dyt2_w, dyt2_b, dyt2_a,
      adyt1_w, adyt1_b, adyt1_a, wt_aa1, aa1_b, wt_aa2, aa2_b, wt_aa3, aa3_b,
      adyt2_w, adyt2_b, adyt2_a, wt_aa4, aa4_b,
      zn_bf, (float*)d_out, Nn);

  // ---- fused edge head ----
  float* eout = (float*)d_out + (size_t)Nn * 20;
  k_edge<<<2048, 256, 0, stream>>>(zn_bf, contact, contact + EPp,
      wt_c1, c1_b, wt_c2, c2_b, c3_w, c3_b, eout, EPp);
}

// Round 6
// 1450.748 us; speedup vs baseline: 1.3320x; 1.0195x over previous
//
#include <hip/hip_runtime.h>
#include <cstdint>
#include <cstddef>

// ---------------- problem constants ----------------
constexpr int Nn  = 200000;
constexpr int Ee  = 1600000;
constexpr int EPp = 1000000;

typedef __attribute__((ext_vector_type(8))) short bf8_t;
typedef __attribute__((ext_vector_type(4))) float f4_t;

__device__ inline unsigned short f2bf(float f) {
  union { float f; unsigned u; } v; v.f = f;
  unsigned r = v.u + 0x7FFFu + ((v.u >> 16) & 1u);
  return (unsigned short)(r >> 16);
}
__device__ inline float bf2f(unsigned short u) {
  union { unsigned u; float f; } v; v.u = ((unsigned)u) << 16;
  return v.f;
}
// tanh-form GELU, algebraically reduced: 0.5v(1+tanh(u)) = v*(1-r), r=1/(e^{2u}+1)
__device__ inline float gelu_f(float v) {
  float u = v * fmaf(0.0356774081f, v * v, 0.7978845608f);
  float r = __builtin_amdgcn_rcpf(__expf(u + u) + 1.0f);
  return fmaf(-v, r, v);
}
// dyt: w*tanh(a x)+b with s2 = 2*a prefolded: tanh = 1-2r
__device__ inline float dyt_f(float x, float s2, float w, float b) {
  float r = __builtin_amdgcn_rcpf(__expf(s2 * x) + 1.0f);
  return fmaf(w, fmaf(-2.0f, r, 1.0f), b);
}

// ---------------- degree / CSR build ----------------

__global__ __launch_bounds__(256) void k_degi(const int* __restrict__ dst,
                                              int* __restrict__ cnt, int E) {
  int i = blockIdx.x * 256 + threadIdx.x;
  if (i < E) atomicAdd(&cnt[dst[i]], 1);
}

// scan of degree counts; also emits rdeg = 1/max(deg,1) (folded k_rdeg)
__global__ __launch_bounds__(256) void k_scan1(const int* __restrict__ in,
                                               int* __restrict__ out,
                                               int* __restrict__ bsum,
                                               float* __restrict__ rdeg, int n) {
  __shared__ int sd[256];
  int t = threadIdx.x;
  int base = blockIdx.x * 1024 + t * 4;
  int v[4]; int ts = 0;
  #pragma unroll
  for (int j = 0; j < 4; ++j) { v[j] = (base + j < n) ? in[base + j] : 0; ts += v[j]; }
  sd[t] = ts; __syncthreads();
  for (int off = 1; off < 256; off <<= 1) {
    int x = (t >= off) ? sd[t - off] : 0;
    __syncthreads();
    sd[t] += x;
    __syncthreads();
  }
  int excl = sd[t] - ts;
  #pragma unroll
  for (int j = 0; j < 4; ++j) {
    if (base + j < n) {
      out[base + j] = excl;
      rdeg[base + j] = 1.0f / (float)(v[j] > 1 ? v[j] : 1);
    }
    excl += v[j];
  }
  if (t == 255) bsum[blockIdx.x] = sd[255];
}

__global__ void k_scan2(int* bsum, int nb) {
  __shared__ int sd[256];
  int t = threadIdx.x;
  int v = (t < nb) ? bsum[t] : 0;
  sd[t] = v; __syncthreads();
  for (int off = 1; off < 256; off <<= 1) {
    int x = (t >= off) ? sd[t - off] : 0;
    __syncthreads();
    sd[t] += x;
    __syncthreads();
  }
  if (t < nb) bsum[t] = sd[t] - v;
}

__global__ __launch_bounds__(256) void k_scan3(const int* __restrict__ part,
                                               const int* __restrict__ bsum,
                                               int* __restrict__ rowptr,
                                               int* __restrict__ cursor,
                                               int n, int total) {
  int i = blockIdx.x * 256 + threadIdx.x;
  if (i == 0) rowptr[n] = total;
  if (i < n) { int v = part[i] + bsum[i >> 10]; rowptr[i] = v; cursor[i] = v; }
}

__global__ __launch_bounds__(256) void k_fill(const int* __restrict__ src,
                                              const int* __restrict__ dst,
                                              int* __restrict__ cursor,
                                              int* __restrict__ colidx, int E) {
  int e = blockIdx.x * 256 + threadIdx.x;
  if (e >= E) return;
  int pos = atomicAdd(&cursor[dst[e]], 1);
  colidx[pos] = src[e];
}

// gather-mean over bf16 features: one wave per node, 8 groups of 8 lanes
__global__ __launch_bounds__(256) void k_gather(const unsigned short* __restrict__ x, int ldx,
                                                const int* __restrict__ rowptr,
                                                const int* __restrict__ colidx,
                                                const float* __restrict__ rdeg,
                                                unsigned short* __restrict__ agg, int n) {
  int wave = threadIdx.x >> 6, lane = threadIdx.x & 63;
  int node = blockIdx.x * 4 + wave;
  if (node >= n) return;
  int grp = lane >> 3, c = (lane & 7) * 8;
  int r0 = rowptr[node], r1 = rowptr[node + 1];
  float s[8] = {0.f, 0.f, 0.f, 0.f, 0.f, 0.f, 0.f, 0.f};
  for (int j = r0 + grp; j < r1; j += 8) {
    bf8_t v = *(const bf8_t*)(x + (size_t)colidx[j] * ldx + c);
    #pragma unroll
    for (int jj = 0; jj < 8; ++jj) s[jj] += bf2f((unsigned short)v[jj]);
  }
  #pragma unroll
  for (int jj = 0; jj < 8; ++jj) {
    s[jj] += __shfl_xor(s[jj], 8, 64);
    s[jj] += __shfl_xor(s[jj], 16, 64);
    s[jj] += __shfl_xor(s[jj], 32, 64);
  }
  if (grp == 0) {
    float r = rdeg[node];
    bf8_t o;
    #pragma unroll
    for (int jj = 0; jj < 8; ++jj) o[jj] = (short)f2bf(s[jj] * r);
    *(bf8_t*)(agg + (size_t)node * 64 + c) = o;
  }
}

// ---------------- misc small kernels ----------------

__global__ __launch_bounds__(256) void k_cvt(const float* __restrict__ in,
                                             unsigned short* __restrict__ out, int n) {
  int i = blockIdx.x * 256 + threadIdx.x;
  if (i < n) out[i] = f2bf(in[i]);
}

// ---- merged weight prep: one launch for all 10 weight transforms ----
__device__ inline void wt3_elem(const float* __restrict__ W,
                                unsigned short* __restrict__ Wt,
                                int Np, int Nr, int i) {
  // blocked layout: Wt[((k>>5)*Np + n)*32 + (k&31)] = W[k][n], zero-pad n>=Nr
  int kin = i & 31;
  int j = i >> 5;
  int n = j % Np, kb = j / Np;
  int k = kb * 32 + kin;
  float v = (n < Nr) ? W[(size_t)k * Nr + n] : 0.f;
  Wt[i] = f2bf(v);
}
__device__ inline void wt2_elem(const float* __restrict__ W,
                                unsigned short* __restrict__ Wt,
                                int K, int N, int i) {
  int n = i / K, k = i - n * K;
  float v = (n < N) ? W[(size_t)k * N + n] : 0.f;
  Wt[i] = f2bf(v);
}

// total = 24576+49152+65536+16384+32768+65536+65536+8192+16384+16384 = 360448
__global__ __launch_bounds__(256) void k_wtall(
    const float* __restrict__ Wl, const float* __restrict__ Wr,
    const float* __restrict__ lin1_w, const float* __restrict__ lin2_w,
    const float* __restrict__ lin3_w,
    const float* __restrict__ aa1_w, const float* __restrict__ aa2_w,
    const float* __restrict__ aa3_w, const float* __restrict__ aa4_w,
    const float* __restrict__ c1_w, const float* __restrict__ c2_w,
    unsigned short* __restrict__ wt_sage,
    unsigned short* __restrict__ wt_lin1, unsigned short* __restrict__ wt_lin2,
    unsigned short* __restrict__ wt_lin3,
    unsigned short* __restrict__ wt_aa1, unsigned short* __restrict__ wt_aa2,
    unsigned short* __restrict__ wt_aa3, unsigned short* __restrict__ wt_aa4,
    unsigned short* __restrict__ wt_c1, unsigned short* __restrict__ wt_c2) {
  int i = blockIdx.x * 256 + threadIdx.x;
  if (i < 24576) {                              // SAGE [Wl|Wr] packed
    int l = i >> 13, r = i & 8191, n = r >> 7, k = r & 127;
    float v = (k < 64) ? Wl[l * 4096 + k * 64 + n] : Wr[l * 4096 + (k - 64) * 64 + n];
    wt_sage[i] = f2bf(v);
    return;
  }
  i -= 24576;
  if (i < 49152) { wt3_elem(lin1_w, wt_lin1, 256, 256, i); return; }  i -= 49152;
  if (i < 65536) { wt3_elem(lin2_w, wt_lin2, 256, 256, i); return; }  i -= 65536;
  if (i < 16384) { wt3_elem(lin3_w, wt_lin3, 64, 64, i);   return; }  i -= 16384;
  if (i < 32768) { wt3_elem(aa1_w, wt_aa1, 256, 256, i);   return; }  i -= 32768;
  if (i < 65536) { wt3_elem(aa2_w, wt_aa2, 256, 256, i);   return; }  i -= 65536;
  if (i < 65536) { wt3_elem(aa3_w, wt_aa3, 256, 256, i);   return; }  i -= 65536;
  if (i < 8192)  { wt3_elem(aa4_w, wt_aa4, 32, 20, i);     return; }  i -= 8192;
  if (i < 16384) { wt2_elem(c1_w, wt_c1, 128, 128, i);     return; }  i -= 16384;
  if (i < 16384) { wt2_elem(c2_w, wt_c2, 128, 128, i);     return; }
}

__global__ void k_statfin(float* stats, const float* __restrict__ ms_, int n) {
  int d = threadIdx.x;
  if (d < 64) {
    float invn = 1.0f / (float)n;
    float m  = stats[d] * invn;
    float e2 = stats[64 + d] * invn;
    float ms = ms_[d];
    float var = e2 - (2.0f * ms - ms * ms) * m * m;
    stats[128 + d] = ms * m;
    stats[192 + d] = rsqrtf(var + 1e-5f);
  }
}

__global__ __launch_bounds__(256) void k_norm(const float* __restrict__ h,
                                              const float* __restrict__ stats,
                                              const float* __restrict__ w,
                                              const float* __restrict__ b,
                                              unsigned short* __restrict__ zcol,
                                              const unsigned short* __restrict__ prev, int n) {
  int i = blockIdx.x * 256 + threadIdx.x;
  if (i >= n * 64) return;
  int r = i >> 6, d = i & 63;
  float v = (h[i] - stats[128 + d]) * stats[192 + d] * w[d] + b[d];
  if (prev) v += bf2f(prev[(size_t)r * 192 + d]);
  zcol[(size_t)r * 192 + d] = f2bf(v);
}

// ---------------- generic bf16 MFMA GEMM (for SAGE) ----------------
// Fused per-column stats (sum, sum^2 of the activated output) via LDS reduce
// + 128 global atomics per block — replaces the separate k_stats pass that
// re-read hbuf (51 MB fp32 per layer).
template <int NT>
__global__ __launch_bounds__(256) void mgemm(
    const void* __restrict__ A1, int lda1,
    const void* __restrict__ A2, int lda2, int K1, int a_bf16,
    const unsigned short* __restrict__ Wt,
    const float* __restrict__ bias,
    void* __restrict__ Cout, int ldc, int c_bf16, int act,
    float* __restrict__ stats_out,
    int M, int K, int N) {
  int lane = threadIdx.x & 63, wave = threadIdx.x >> 6;
  int quad = lane >> 4, col = lane & 15;
  int row0 = blockIdx.x * 128 + wave * 32;
  int n_base = blockIdx.y * NT * 16;

  __shared__ float ls[128];
  if (stats_out) {
    if (threadIdx.x < 128) ls[threadIdx.x] = 0.f;
    __syncthreads();
  }

  f4_t acc[2][NT];
  #pragma unroll
  for (int mt = 0; mt < 2; ++mt)
    #pragma unroll
    for (int nt = 0; nt < NT; ++nt) acc[mt][nt] = (f4_t)0.f;

  int gm[2];
  gm[0] = row0 + col;      if (gm[0] >= M) gm[0] = M - 1;
  gm[1] = row0 + 16 + col; if (gm[1] >= M) gm[1] = M - 1;

  for (int kc0 = 0; kc0 < K; kc0 += 32) {
    int kc = kc0 + quad * 8;
    bf8_t a[2];
    #pragma unroll
    for (int mt = 0; mt < 2; ++mt) {
      const void* src; size_t off;
      if (kc < K1) { src = A1; off = (size_t)gm[mt] * lda1 + kc; }
      else         { src = A2; off = (size_t)gm[mt] * lda2 + kc - K1; }
      if (a_bf16) {
        a[mt] = *(const bf8_t*)((const unsigned short*)src + off);
      } else {
        const float* p = (const float*)src + off;
        float4 f0 = *(const float4*)p;
        float4 f1 = *(const float4*)(p + 4);
        float ff[8] = {f0.x, f0.y, f0.z, f0.w, f1.x, f1.y, f1.z, f1.w};
        #pragma unroll
        for (int j = 0; j < 8; ++j) a[mt][j] = (short)f2bf(ff[j]);
      }
    }
    #pragma unroll
    for (int nt = 0; nt < NT; ++nt) {
      bf8_t b = *(const bf8_t*)(Wt + (size_t)(n_base + nt * 16 + col) * K + kc);
      acc[0][nt] = __builtin_amdgcn_mfma_f32_16x16x32_bf16(a[0], b, acc[0][nt], 0, 0, 0);
      acc[1][nt] = __builtin_amdgcn_mfma_f32_16x16x32_bf16(a[1], b, acc[1][nt], 0, 0, 0);
    }
  }

  #pragma unroll
  for (int nt = 0; nt < NT; ++nt) {
    int n = n_base + nt * 16 + col;
    float bs = (bias && n < N) ? bias[n] : 0.f;
    float sa = 0.f, s2a = 0.f;
    #pragma unroll
    for (int mt = 0; mt < 2; ++mt)
      #pragma unroll
      for (int r = 0; r < 4; ++r) {
        int row = row0 + mt * 16 + quad * 4 + r;
        if (row >= M || n >= N) continue;
        float v = acc[mt][nt][r] + bs;
        if (act) v = gelu_f(v);
        sa += v; s2a += v * v;
        if (c_bf16) ((unsigned short*)Cout)[(size_t)row * ldc + n] = f2bf(v);
        else        ((float*)Cout)[(size_t)row * ldc + n] = v;
      }
    if (stats_out && n < N) {
      atomicAdd(&ls[n & 63], sa);
      atomicAdd(&ls[64 + (n & 63)], s2a);
    }
  }
  if (stats_out) {
    __syncthreads();
    if (threadIdx.x < 128) atomicAdd(&stats_out[threadIdx.x], ls[threadIdx.x]);
  }
}

// ---------------- block-cooperative fused node pipeline ----------------
// Block = 256 thr = 4 waves = 64 rows; wave w owns output cols [64w,64w+64).
// Block reads each weight once per 64 rows (1.9 GB L2 traffic total).
// `#pragma unroll 2` on the k-loop bounds the load-hoist window (full unroll
// spilled 150-400 MB to scratch in rounds 2-4); (256,3) caps regs at ~168.
template <int K, bool DYT>
__device__ inline void node_gemm(unsigned short (*H)[264],
                                 const unsigned short* __restrict__ W,
                                 const float* __restrict__ bias,
                                 int wave, int quad, int col,
                                 const float* __restrict__ a2w,
                                 const float* __restrict__ a2b,
                                 const float* __restrict__ aal) {
  constexpr int KS = K >> 5;
  f4_t acc[4][4];
  #pragma unroll
  for (int mt = 0; mt < 4; ++mt)
    #pragma unroll
    for (int nt = 0; nt < 4; ++nt) acc[mt][nt] = (f4_t)0.f;

  // b(s,nt) at wp + (s*256 + nt*16)*32  (blocked layout, Np=256)
  const unsigned short* wp = W + (size_t)(wave * 64 + col) * 32 + quad * 8;
  bf8_t bc[4];
  #pragma unroll
  for (int nt = 0; nt < 4; ++nt)
    bc[nt] = *(const bf8_t*)(wp + (size_t)(nt * 16) * 32);

  #pragma unroll 2
  for (int s = 0; s < KS; ++s) {
    bf8_t am[4];
    #pragma unroll
    for (int mt = 0; mt < 4; ++mt)
      am[mt] = *(const bf8_t*)&H[mt * 16 + col][s * 32 + quad * 8];
    bf8_t bn[4];
    if (s + 1 < KS) {
      #pragma unroll
      for (int nt = 0; nt < 4; ++nt)
        bn[nt] = *(const bf8_t*)(wp + (size_t)((s + 1) * 256 + nt * 16) * 32);
    }
    #pragma unroll
    for (int nt = 0; nt < 4; ++nt)
      #pragma unroll
      for (int mt = 0; mt < 4; ++mt)
        acc[mt][nt] = __builtin_amdgcn_mfma_f32_16x16x32_bf16(am[mt], bc[nt], acc[mt][nt], 0, 0, 0);
    if (s + 1 < KS) {
      #pragma unroll
      for (int nt = 0; nt < 4; ++nt) bc[nt] = bn[nt];
    }
  }
  __syncthreads();   // all reads of H complete before epilogue writes
  float sa = DYT ? (2.0f * aal[0]) : 0.f;
  #pragma unroll
  for (int nt = 0; nt < 4; ++nt) {
    int n = wave * 64 + nt * 16 + col;
    float bs = bias[n];
    float w_ = DYT ? a2w[n] : 0.f;
    float b_ = DYT ? a2b[n] : 0.f;
    #pragma unroll
    for (int mt = 0; mt < 4; ++mt)
      #pragma unroll
      for (int r4 = 0; r4 < 4; ++r4) {
        float v = gelu_f(acc[mt][nt][r4] + bs);
        if (DYT) v = dyt_f(v, sa, w_, b_);
        H[mt * 16 + quad * 4 + r4][n] = f2bf(v);
      }
  }
  __syncthreads();
}

__global__ __launch_bounds__(256, 3) void k_node(
    const unsigned short* __restrict__ z_bf,
    const float* __restrict__ x_res,
    const float* __restrict__ d1w, const float* __restrict__ d1b, const float* __restrict__ d1a,
    const unsigned short* __restrict__ wt1, const float* __restrict__ b1,
    const unsigned short* __restrict__ wt2, const float* __restrict__ b2,
    const unsigned short* __restrict__ wt3, const float* __restrict__ b3,
    const float* __restrict__ d2w, const float* __restrict__ d2b, const float* __restrict__ d2a,
    const float* __restrict__ a1w, const float* __restrict__ a1b, const float* __restrict__ a1a,
    const unsigned short* __restrict__ wa1, const float* __restrict__ ba1,
    const unsigned short* __restrict__ wa2, const float* __restrict__ ba2,
    const unsigned short* __restrict__ wa3, const float* __restrict__ ba3,
    const float* __restrict__ a2w, const float* __restrict__ a2b, const float* __restrict__ a2a,
    const unsigned short* __restrict__ wa4, const float* __restrict__ ba4,
    unsigned short* __restrict__ zn_bf,
    float* __restrict__ out, int M) {
  __shared__ unsigned short H[64][264];   // 33.8 KB
  __shared__ float fscr[64 * 4 + 64];     // rownorm partials + inv norms
  int t = threadIdx.x;
  int lane = t & 63, wave = t >> 6;
  int quad = lane >> 4, col = lane & 15;
  int brow = blockIdx.x * 64;

  // ---- stage H = dyt1(z rows) ----
  {
    int row = t >> 2, part = t & 3;
    int gr = brow + row; if (gr >= M) gr = M - 1;
    const unsigned short* zp = z_bf + (size_t)gr * 192 + part * 48;
    float s1 = 2.0f * d1a[0];
    #pragma unroll
    for (int j = 0; j < 6; ++j) {
      bf8_t v = *(const bf8_t*)(zp + j * 8);
      int k0 = part * 48 + j * 8;
      #pragma unroll
      for (int jj = 0; jj < 8; ++jj) {
        float f = bf2f((unsigned short)v[jj]);
        v[jj] = (short)f2bf(dyt_f(f, s1, d1w[k0 + jj], d1b[k0 + jj]));
      }
      *(bf8_t*)&H[row][k0] = v;
    }
  }
  __syncthreads();

  // ---- lin1 (K=192), lin2 (K=256) ----
  node_gemm<192, false>(H, wt1, b1, wave, quad, col, nullptr, nullptr, nullptr);
  node_gemm<256, false>(H, wt2, b2, wave, quad, col, nullptr, nullptr, nullptr);

  // ---- lin3 (K=256, N=64; wave w owns n-tile w) + dyt2 + resid + rownorm + adyt1 ----
  {
    f4_t a3[4];
    #pragma unroll
    for (int mt = 0; mt < 4; ++mt) a3[mt] = (f4_t)0.f;
    const unsigned short* wp3 = wt3 + (size_t)(wave * 16 + col) * 32 + quad * 8;
    bf8_t bc = *(const bf8_t*)(wp3);
    #pragma unroll 2
    for (int s = 0; s < 8; ++s) {
      bf8_t am[4];
      #pragma unroll
      for (int mt = 0; mt < 4; ++mt)
        am[mt] = *(const bf8_t*)&H[mt * 16 + col][s * 32 + quad * 8];
      bf8_t bn;
      if (s + 1 < 8) bn = *(const bf8_t*)(wp3 + (size_t)((s + 1) * 64) * 32);
      #pragma unroll
      for (int mt = 0; mt < 4; ++mt)
        a3[mt] = __builtin_amdgcn_mfma_f32_16x16x32_bf16(am[mt], bc, a3[mt], 0, 0, 0);
      if (s + 1 < 8) bc = bn;
    }
    __syncthreads();                     // all lin3 reads of H complete
    // vv (fp32) overlaid into H's storage ([64][66] floats)
    float* fb = (float*)H;
    float s2d = 2.0f * d2a[0];
    int n = wave * 16 + col;
    float bsn = b3[n], wd = d2w[n], bd = d2b[n];
    #pragma unroll
    for (int mt = 0; mt < 4; ++mt)
      #pragma unroll
      for (int r4 = 0; r4 < 4; ++r4) {
        int row = mt * 16 + quad * 4 + r4;
        int gr = brow + row; if (gr >= M) gr = M - 1;
        float g = gelu_f(a3[mt][r4] + bsn);
        float x = x_res[(size_t)gr * 64 + n];
        fb[row * 66 + n] = dyt_f(g, s2d, wd, bd) + x;
      }
    __syncthreads();
    // each thread owns (row = t>>2, cols q*16..q*16+15): read to REGISTERS
    int row = t >> 2, q = t & 3;
    float vreg[16];
    float s2 = 0.f;
    #pragma unroll
    for (int c16 = 0; c16 < 16; ++c16) {
      vreg[c16] = fb[row * 66 + q * 16 + c16];
      s2 += vreg[c16] * vreg[c16];
    }
    fscr[row * 4 + q] = s2;
    __syncthreads();
    if (t < 64)
      fscr[256 + t] = 1.0f / (sqrtf(fscr[t * 4] + fscr[t * 4 + 1] + fscr[t * 4 + 2] + fscr[t * 4 + 3]) + 1e-10f);
    __syncthreads();                     // all fb reads complete; inv ready
    // write adyt1([x_res, zn]) into H (bf16 view) from registers; write zn_bf
    float sa1 = 2.0f * a1a[0];
    float inv = fscr[256 + row];
    int gr = brow + row;
    int grc = (gr >= M) ? (M - 1) : gr;
    #pragma unroll
    for (int c16 = 0; c16 < 16; ++c16) {
      int c = q * 16 + c16;
      float zv = vreg[c16] * inv;
      if (gr < M) zn_bf[(size_t)gr * 64 + c] = f2bf(zv);
      float x = x_res[(size_t)grc * 64 + c];
      H[row][64 + c] = f2bf(dyt_f(zv, sa1, a1w[64 + c], a1b[64 + c]));
      H[row][c]      = f2bf(dyt_f(x,  sa1, a1w[c],      a1b[c]));
    }
    __syncthreads();
  }

  // ---- aa1 (K=128), aa2 (K=256), aa3 (K=256, adyt2 epilogue) ----
  node_gemm<128, false>(H, wa1, ba1, wave, quad, col, nullptr, nullptr, nullptr);
  node_gemm<256, false>(H, wa2, ba2, wave, quad, col, nullptr, nullptr, nullptr);
  node_gemm<256, true >(H, wa3, ba3, wave, quad, col, a2w, a2b, a2a);

  // ---- aa4 (K=256, N=20 padded 32; wave w owns m-tile w) + log_softmax ----
  {
    f4_t a4[2];
    a4[0] = (f4_t)0.f; a4[1] = (f4_t)0.f;
    const unsigned short* wp4 = wa4 + (size_t)col * 32 + quad * 8;
    bf8_t bc[2];
    bc[0] = *(const bf8_t*)(wp4);
    bc[1] = *(const bf8_t*)(wp4 + (size_t)(16) * 32);
    #pragma unroll 2
    for (int s = 0; s < 8; ++s) {
      bf8_t am = *(const bf8_t*)&H[wave * 16 + col][s * 32 + quad * 8];
      bf8_t bn[2];
      if (s + 1 < 8) {
        bn[0] = *(const bf8_t*)(wp4 + (size_t)((s + 1) * 32) * 32);
        bn[1] = *(const bf8_t*)(wp4 + (size_t)((s + 1) * 32 + 16) * 32);
      }
      #pragma unroll
      for (int nt = 0; nt < 2; ++nt)
        a4[nt] = __builtin_amdgcn_mfma_f32_16x16x32_bf16(am, bc[nt], a4[nt], 0, 0, 0);
      if (s + 1 < 8) { bc[0] = bn[0]; bc[1] = bn[1]; }
    }
    float val[2][4];
    #pragma unroll
    for (int nt = 0; nt < 2; ++nt) {
      int n = nt * 16 + col;
      float bsv = (n < 20) ? ba4[n] : 0.f;
      #pragma unroll
      for (int r4 = 0; r4 < 4; ++r4) val[nt][r4] = a4[nt][r4] + bsv;
    }
    bool v1 = (col < 4);
    #pragma unroll
    for (int r4 = 0; r4 < 4; ++r4) {
      float m = val[0][r4];
      if (v1) m = fmaxf(m, val[1][r4]);
      m = fmaxf(m, __shfl_xor(m, 1, 64));
      m = fmaxf(m, __shfl_xor(m, 2, 64));
      m = fmaxf(m, __shfl_xor(m, 4, 64));
      m = fmaxf(m, __shfl_xor(m, 8, 64));
      float se = __expf(val[0][r4] - m) + (v1 ? __expf(val[1][r4] - m) : 0.f);
      se += __shfl_xor(se, 1, 64);
      se += __shfl_xor(se, 2, 64);
      se += __shfl_xor(se, 4, 64);
      se += __shfl_xor(se, 8, 64);
      float ls = __logf(se) + m;
      int row = brow + wave * 16 + quad * 4 + r4;
      if (row < M) {
        out[(size_t)row * 20 + col] = val[0][r4] - ls;
        if (v1) out[(size_t)row * 20 + 16 + col] = val[1][r4] - ls;
      }
    }
  }
}

// ---------------- fused edge head (prefetching, barrier-free) ----------------
__global__ __launch_bounds__(256) void k_edge(
    const unsigned short* __restrict__ zn_bf,
    const int* __restrict__ ci, const int* __restrict__ cj,
    const unsigned short* __restrict__ w1t, const float* __restrict__ b1,
    const unsigned short* __restrict__ w2t, const float* __restrict__ b2,
    const float* __restrict__ w3, const float* __restrict__ b3,
    float* __restrict__ out, int M) {
  __shared__ unsigned short h1s[4][16][136];
  int lane = threadIdx.x & 63, wave = threadIdx.x >> 6;
  int quad = lane >> 4, col = lane & 15;
  unsigned short (*h1)[136] = h1s[wave];
  int ntiles = (M + 63) >> 6;
  float b3v = b3[0];

  int tile = blockIdx.x;
  bf8_t afrag[4];
  if (tile < ntiles) {
    int r = tile * 64 + wave * 16 + col; if (r >= M) r = M - 1;
    const unsigned short* p0 = zn_bf + (size_t)ci[r] * 64;
    const unsigned short* p1 = zn_bf + (size_t)cj[r] * 64;
    afrag[0] = *(const bf8_t*)(p0 + quad * 8);
    afrag[1] = *(const bf8_t*)(p0 + 32 + quad * 8);
    afrag[2] = *(const bf8_t*)(p1 + quad * 8);
    afrag[3] = *(const bf8_t*)(p1 + 32 + quad * 8);
  }

  for (; tile < ntiles; tile += gridDim.x) {
    f4_t acc[8];
    #pragma unroll
    for (int nt = 0; nt < 8; ++nt) acc[nt] = (f4_t)0.f;
    #pragma unroll
    for (int s = 0; s < 4; ++s) {
      int kf = s * 32 + quad * 8;
      #pragma unroll
      for (int nt = 0; nt < 8; ++nt) {
        bf8_t b = *(const bf8_t*)(w1t + (size_t)(nt * 16 + col) * 128 + kf);
        acc[nt] = __builtin_amdgcn_mfma_f32_16x16x32_bf16(afrag[s], b, acc[nt], 0, 0, 0);
      }
    }

    int nxt = tile + gridDim.x;
    bf8_t nfrag[4];
    bool has_next = (nxt < ntiles);
    if (has_next) {
      int r = nxt * 64 + wave * 16 + col; if (r >= M) r = M - 1;
      const unsigned short* p0 = zn_bf + (size_t)ci[r] * 64;
      const unsigned short* p1 = zn_bf + (size_t)cj[r] * 64;
      nfrag[0] = *(const bf8_t*)(p0 + quad * 8);
      nfrag[1] = *(const bf8_t*)(p0 + 32 + quad * 8);
      nfrag[2] = *(const bf8_t*)(p1 + quad * 8);
      nfrag[3] = *(const bf8_t*)(p1 + 32 + quad * 8);
    }

    #pragma unroll
    for (int nt = 0; nt < 8; ++nt) {
      float bs = b1[nt * 16 + col];
      #pragma unroll
      for (int r4 = 0; r4 < 4; ++r4)
        h1[quad * 4 + r4][nt * 16 + col] = f2bf(gelu_f(acc[nt][r4] + bs));
    }

    f4_t a2[8];
    #pragma unroll
    for (int nt = 0; nt < 8; ++nt) a2[nt] = (f4_t)0.f;
    #pragma unroll
    for (int s = 0; s < 4; ++s) {
      int kc = s * 32 + quad * 8;
      bf8_t a0 = *(const bf8_t*)&h1[col][kc];
      #pragma unroll
      for (int nt = 0; nt < 8; ++nt) {
        bf8_t b = *(const bf8_t*)(w2t + (size_t)(nt * 16 + col) * 128 + kc);
        a2[nt] = __builtin_amdgcn_mfma_f32_16x16x32_bf16(a0, b, a2[nt], 0, 0, 0);
      }
    }
    float p[4] = {0.f, 0.f, 0.f, 0.f};
    #pragma unroll
    for (int nt = 0; nt < 8; ++nt) {
      float bs = b2[nt * 16 + col];
      float wv = w3[nt * 16 + col];
      #pragma unroll
      for (int r4 = 0; r4 < 4; ++r4)
        p[r4] += gelu_f(a2[nt][r4] + bs) * wv;
    }
    #pragma unroll
    for (int r4 = 0; r4 < 4; ++r4) {
      float s = p[r4];
      s += __shfl_xor(s, 1, 64);
      s += __shfl_xor(s, 2, 64);
      s += __shfl_xor(s, 4, 64);
      s += __shfl_xor(s, 8, 64);
      if (col == 0) {
        int row = tile * 64 + wave * 16 + quad * 4 + r4;
        if (row < M) out[row] = __builtin_amdgcn_rcpf(1.0f + __expf(-(s + b3v)));
      }
    }

    if (has_next) {
      afrag[0] = nfrag[0]; afrag[1] = nfrag[1];
      afrag[2] = nfrag[2]; afrag[3] = nfrag[3];
    }
  }
}

// ---------------- launcher ----------------
extern "C" void kernel_launch(void* const* d_in, const int* in_sizes, int n_in,
                              void* d_out, int out_size, void* d_ws, size_t ws_size,
                              hipStream_t stream) {
  const float* x_res  = (const float*)d_in[0];
  const float* Wl     = (const float*)d_in[1];
  const float* bl     = (const float*)d_in[2];
  const float* Wr     = (const float*)d_in[3];
  const float* gn_w   = (const float*)d_in[4];
  const float* gn_b   = (const float*)d_in[5];
  const float* gn_ms  = (const float*)d_in[6];
  const float* dyt1_w = (const float*)d_in[7];
  const float* dyt1_b = (const float*)d_in[8];
  const float* dyt1_a = (const float*)d_in[9];
  const float* lin1_w = (const float*)d_in[10];
  const float* lin1_b = (const float*)d_in[11];
  const float* lin2_w = (const float*)d_in[12];
  const float* lin2_b = (const float*)d_in[13];
  const float* lin3_w = (const float*)d_in[14];
  const float* lin3_b = (const float*)d_in[15];
  const float* dyt2_w = (const float*)d_in[16];
  const float* dyt2_b = (const float*)d_in[17];
  const float* dyt2_a = (const float*)d_in[18];
  const float* adyt1_w = (const float*)d_in[19];
  const float* adyt1_b = (const float*)d_in[20];
  const float* adyt1_a = (const float*)d_in[21];
  const float* aa1_w  = (const float*)d_in[22];
  const float* aa1_b  = (const float*)d_in[23];
  const float* aa2_w  = (const float*)d_in[24];
  const float* aa2_b  = (const float*)d_in[25];
  const float* aa3_w  = (const float*)d_in[26];
  const float* aa3_b  = (const float*)d_in[27];
  const float* adyt2_w = (const float*)d_in[28];
  const float* adyt2_b = (const float*)d_in[29];
  const float* adyt2_a = (const float*)d_in[30];
  const float* aa4_w  = (const float*)d_in[31];
  const float* aa4_b  = (const float*)d_in[32];
  const float* c1_w   = (const float*)d_in[33];
  const float* c1_b   = (const float*)d_in[34];
  const float* c2_w   = (const float*)d_in[35];
  const float* c2_b   = (const float*)d_in[36];
  const float* c3_w   = (const float*)d_in[37];
  const float* c3_b   = (const float*)d_in[38];
  const int*   edge   = (const int*)d_in[39];
  const int*   contact = (const int*)d_in[40];

  const size_t N = (size_t)Nn;
  const size_t ws_floats = ws_size / 4;

  float* ws    = (float*)d_ws;
  float* rdeg  = ws;
  float* hbuf  = rdeg + N;
  unsigned short* z_bf  = (unsigned short*)(hbuf + 64 * N);
  unsigned short* zn_bf = z_bf + 192 * N;
  float* stats = (float*)(zn_bf + 64 * N);          // 3 layers x 256 floats
  unsigned short* wt_sage = (unsigned short*)(stats + 768);
  unsigned short* wt_lin1 = wt_sage + 3 * 64 * 128;
  unsigned short* wt_lin2 = wt_lin1 + 256 * 192;
  unsigned short* wt_lin3 = wt_lin2 + 256 * 256;
  unsigned short* wt_aa1  = wt_lin3 + 64 * 256;
  unsigned short* wt_aa2  = wt_aa1 + 256 * 128;
  unsigned short* wt_aa3  = wt_aa2 + 256 * 256;
  unsigned short* wt_aa4  = wt_aa3 + 256 * 256;
  unsigned short* wt_c1   = wt_aa4 + 32 * 256;
  unsigned short* wt_c2   = wt_c1 + 128 * 128;
  unsigned short* wt_end  = wt_c2 + 128 * 128;
  float* pool  = (float*)((((uintptr_t)wt_end + 15) & ~(uintptr_t)15));
  const size_t persist = (size_t)(pool - ws);

  const size_t gnn_need = 32 * N + N + (N + 1) + N + (size_t)Ee + 256;
  if (ws_floats < persist + gnn_need) return;

  unsigned short* agg_bf = (unsigned short*)pool;
  int* cnt     = (int*)(pool + 32 * N);
  int* rowptr  = cnt + N;
  int* cursor  = rowptr + N + 1;
  int* colidx  = cursor + N;
  int* bsum    = colidx + Ee;

  const int* esrc = edge;
  const int* edst = edge + Ee;

  // ---- CSR build ----
  hipMemsetAsync(cnt, 0, N * sizeof(int), stream);
  hipMemsetAsync(stats, 0, 768 * sizeof(float), stream);
  k_degi<<<(Ee + 255) / 256, 256, 0, stream>>>(edst, cnt, Ee);
  const int nb = (Nn + 1023) / 1024;
  k_scan1<<<nb, 256, 0, stream>>>(cnt, cursor, bsum, rdeg, Nn);
  k_scan2<<<1, 256, 0, stream>>>(bsum, nb);
  k_scan3<<<(Nn + 255) / 256, 256, 0, stream>>>(cursor, bsum, rowptr, cursor, Nn, Ee);
  k_fill<<<(Ee + 255) / 256, 256, 0, stream>>>(esrc, edst, cursor, colidx, Ee);

  // ---- weight prep (single merged launch) ----
  k_wtall<<<(360448 + 255) / 256, 256, 0, stream>>>(
      Wl, Wr, lin1_w, lin2_w, lin3_w, aa1_w, aa2_w, aa3_w, aa4_w, c1_w, c2_w,
      wt_sage, wt_lin1, wt_lin2, wt_lin3, wt_aa1, wt_aa2, wt_aa3, wt_aa4,
      wt_c1, wt_c2);

  // xb = bf16(x_res) in zn_bf slot
  k_cvt<<<(int)((N * 64 + 255) / 256), 256, 0, stream>>>(x_res, zn_bf, (int)(N * 64));

  // ---- GNN phase (stats fused into mgemm epilogue; k_stats removed) ----
  for (int l = 0; l < 3; ++l) {
    const unsigned short* xi = (l == 0) ? zn_bf : (z_bf + (size_t)(l - 1) * 64);
    int ldx = (l == 0) ? 64 : 192;
    float* stats_l = stats + (size_t)l * 256;
    k_gather<<<(Nn + 3) / 4, 256, 0, stream>>>(xi, ldx, rowptr, colidx, rdeg, agg_bf, Nn);
    mgemm<4><<<dim3((Nn + 127) / 128, 1), 256, 0, stream>>>(
        agg_bf, 64, xi, ldx, 64, 1,
        wt_sage + (size_t)l * 8192, bl + l * 64, hbuf, 64, 0, 1, stats_l, Nn, 128, 64);
    k_statfin<<<1, 64, 0, stream>>>(stats_l, gn_ms + l * 64, Nn);
    k_norm<<<(Nn * 64) / 256, 256, 0, stream>>>(hbuf, stats_l, gn_w + l * 64, gn_b + l * 64,
                                                z_bf + (size_t)l * 64,
                                                (l > 0) ? (z_bf + (size_t)(l - 1) * 64) : nullptr, Nn);
  }

  // ---- block-cooperative fused node pipeline ----
  k_node<<<(Nn + 63) / 64, 256, 0, stream>>>(
      z_bf, x_res,
      dyt1_w, dyt1_b, dyt1_a, wt_lin1, lin1_b, wt_lin2, lin2_b, wt_lin3, lin3_b,
      dyt2_w, dyt2_b, dyt2_a,
      adyt1_w, adyt1_b, adyt1_a, wt_aa1, aa1_b, wt_aa2, aa2_b, wt_aa3, aa3_b,
      adyt2_w, adyt2_b, adyt2_a, wt_aa4, aa4_b,
      zn_bf, (float*)d_out, Nn);

  // ---- fused edge head ----
  float* eout = (float*)d_out + (size_t)Nn * 20;
  k_edge<<<2048, 256, 0, stream>>>(zn_bf, contact, contact + EPp,
      wt_c1, c1_b, wt_c2, c2_b, c3_w, c3_b, eout, EPp);
}

// Round 7
// 1436.330 us; speedup vs baseline: 1.3453x; 1.0100x over previous
//
#include <hip/hip_runtime.h>
#include <cstdint>
#include <cstddef>

// ---------------- problem constants ----------------
constexpr int Nn  = 200000;
constexpr int Ee  = 1600000;
constexpr int EPp = 1000000;

typedef __attribute__((ext_vector_type(8))) short bf8_t;
typedef __attribute__((ext_vector_type(4))) float f4_t;

__device__ inline unsigned short f2bf(float f) {
  union { float f; unsigned u; } v; v.f = f;
  unsigned r = v.u + 0x7FFFu + ((v.u >> 16) & 1u);
  return (unsigned short)(r >> 16);
}
__device__ inline float bf2f(unsigned short u) {
  union { unsigned u; float f; } v; v.u = ((unsigned)u) << 16;
  return v.f;
}
// tanh-form GELU, algebraically reduced: 0.5v(1+tanh(u)) = v*(1-r), r=1/(e^{2u}+1)
__device__ inline float gelu_f(float v) {
  float u = v * fmaf(0.0356774081f, v * v, 0.7978845608f);
  float r = __builtin_amdgcn_rcpf(__expf(u + u) + 1.0f);
  return fmaf(-v, r, v);
}
// dyt: w*tanh(a x)+b with s2 = 2*a prefolded: tanh = 1-2r
__device__ inline float dyt_f(float x, float s2, float w, float b) {
  float r = __builtin_amdgcn_rcpf(__expf(s2 * x) + 1.0f);
  return fmaf(w, fmaf(-2.0f, r, 1.0f), b);
}

// ---------------- degree / CSR build ----------------

__global__ __launch_bounds__(256) void k_degi(const int* __restrict__ dst,
                                              int* __restrict__ cnt, int E) {
  int i = blockIdx.x * 256 + threadIdx.x;
  if (i < E) atomicAdd(&cnt[dst[i]], 1);
}

// scan of degree counts; also emits rdeg = 1/max(deg,1) (folded k_rdeg)
__global__ __launch_bounds__(256) void k_scan1(const int* __restrict__ in,
                                               int* __restrict__ out,
                                               int* __restrict__ bsum,
                                               float* __restrict__ rdeg, int n) {
  __shared__ int sd[256];
  int t = threadIdx.x;
  int base = blockIdx.x * 1024 + t * 4;
  int v[4]; int ts = 0;
  #pragma unroll
  for (int j = 0; j < 4; ++j) { v[j] = (base + j < n) ? in[base + j] : 0; ts += v[j]; }
  sd[t] = ts; __syncthreads();
  for (int off = 1; off < 256; off <<= 1) {
    int x = (t >= off) ? sd[t - off] : 0;
    __syncthreads();
    sd[t] += x;
    __syncthreads();
  }
  int excl = sd[t] - ts;
  #pragma unroll
  for (int j = 0; j < 4; ++j) {
    if (base + j < n) {
      out[base + j] = excl;
      rdeg[base + j] = 1.0f / (float)(v[j] > 1 ? v[j] : 1);
    }
    excl += v[j];
  }
  if (t == 255) bsum[blockIdx.x] = sd[255];
}

__global__ void k_scan2(int* bsum, int nb) {
  __shared__ int sd[256];
  int t = threadIdx.x;
  int v = (t < nb) ? bsum[t] : 0;
  sd[t] = v; __syncthreads();
  for (int off = 1; off < 256; off <<= 1) {
    int x = (t >= off) ? sd[t - off] : 0;
    __syncthreads();
    sd[t] += x;
    __syncthreads();
  }
  if (t < nb) bsum[t] = sd[t] - v;
}

__global__ __launch_bounds__(256) void k_scan3(const int* __restrict__ part,
                                               const int* __restrict__ bsum,
                                               int* __restrict__ rowptr,
                                               int* __restrict__ cursor,
                                               int n, int total) {
  int i = blockIdx.x * 256 + threadIdx.x;
  if (i == 0) rowptr[n] = total;
  if (i < n) { int v = part[i] + bsum[i >> 10]; rowptr[i] = v; cursor[i] = v; }
}

__global__ __launch_bounds__(256) void k_fill(const int* __restrict__ src,
                                              const int* __restrict__ dst,
                                              int* __restrict__ cursor,
                                              int* __restrict__ colidx, int E) {
  int e = blockIdx.x * 256 + threadIdx.x;
  if (e >= E) return;
  int pos = atomicAdd(&cursor[dst[e]], 1);
  colidx[pos] = src[e];
}

// gather-mean over bf16 features: one wave per node, 8 groups of 8 lanes
__global__ __launch_bounds__(256) void k_gather(const unsigned short* __restrict__ x, int ldx,
                                                const int* __restrict__ rowptr,
                                                const int* __restrict__ colidx,
                                                const float* __restrict__ rdeg,
                                                unsigned short* __restrict__ agg, int n) {
  int wave = threadIdx.x >> 6, lane = threadIdx.x & 63;
  int node = blockIdx.x * 4 + wave;
  if (node >= n) return;
  int grp = lane >> 3, c = (lane & 7) * 8;
  int r0 = rowptr[node], r1 = rowptr[node + 1];
  float s[8] = {0.f, 0.f, 0.f, 0.f, 0.f, 0.f, 0.f, 0.f};
  for (int j = r0 + grp; j < r1; j += 8) {
    bf8_t v = *(const bf8_t*)(x + (size_t)colidx[j] * ldx + c);
    #pragma unroll
    for (int jj = 0; jj < 8; ++jj) s[jj] += bf2f((unsigned short)v[jj]);
  }
  #pragma unroll
  for (int jj = 0; jj < 8; ++jj) {
    s[jj] += __shfl_xor(s[jj], 8, 64);
    s[jj] += __shfl_xor(s[jj], 16, 64);
    s[jj] += __shfl_xor(s[jj], 32, 64);
  }
  if (grp == 0) {
    float r = rdeg[node];
    bf8_t o;
    #pragma unroll
    for (int jj = 0; jj < 8; ++jj) o[jj] = (short)f2bf(s[jj] * r);
    *(bf8_t*)(agg + (size_t)node * 64 + c) = o;
  }
}

// ---------------- misc small kernels ----------------

__global__ __launch_bounds__(256) void k_cvt(const float* __restrict__ in,
                                             unsigned short* __restrict__ out, int n) {
  int i = blockIdx.x * 256 + threadIdx.x;
  if (i < n) out[i] = f2bf(in[i]);
}

// ---- merged weight prep: one launch for all 10 weight transforms ----
__device__ inline void wt3_elem(const float* __restrict__ W,
                                unsigned short* __restrict__ Wt,
                                int Np, int Nr, int i) {
  // blocked layout: Wt[((k>>5)*Np + n)*32 + (k&31)] = W[k][n], zero-pad n>=Nr
  int kin = i & 31;
  int j = i >> 5;
  int n = j % Np, kb = j / Np;
  int k = kb * 32 + kin;
  float v = (n < Nr) ? W[(size_t)k * Nr + n] : 0.f;
  Wt[i] = f2bf(v);
}
__device__ inline void wt2_elem(const float* __restrict__ W,
                                unsigned short* __restrict__ Wt,
                                int K, int N, int i) {
  int n = i / K, k = i - n * K;
  float v = (n < N) ? W[(size_t)k * N + n] : 0.f;
  Wt[i] = f2bf(v);
}

// total = 24576+49152+65536+16384+32768+65536+65536+8192+16384+16384 = 360448
__global__ __launch_bounds__(256) void k_wtall(
    const float* __restrict__ Wl, const float* __restrict__ Wr,
    const float* __restrict__ lin1_w, const float* __restrict__ lin2_w,
    const float* __restrict__ lin3_w,
    const float* __restrict__ aa1_w, const float* __restrict__ aa2_w,
    const float* __restrict__ aa3_w, const float* __restrict__ aa4_w,
    const float* __restrict__ c1_w, const float* __restrict__ c2_w,
    unsigned short* __restrict__ wt_sage,
    unsigned short* __restrict__ wt_lin1, unsigned short* __restrict__ wt_lin2,
    unsigned short* __restrict__ wt_lin3,
    unsigned short* __restrict__ wt_aa1, unsigned short* __restrict__ wt_aa2,
    unsigned short* __restrict__ wt_aa3, unsigned short* __restrict__ wt_aa4,
    unsigned short* __restrict__ wt_c1, unsigned short* __restrict__ wt_c2) {
  int i = blockIdx.x * 256 + threadIdx.x;
  if (i < 24576) {                              // SAGE [Wl|Wr] packed
    int l = i >> 13, r = i & 8191, n = r >> 7, k = r & 127;
    float v = (k < 64) ? Wl[l * 4096 + k * 64 + n] : Wr[l * 4096 + (k - 64) * 64 + n];
    wt_sage[i] = f2bf(v);
    return;
  }
  i -= 24576;
  if (i < 49152) { wt3_elem(lin1_w, wt_lin1, 256, 256, i); return; }  i -= 49152;
  if (i < 65536) { wt3_elem(lin2_w, wt_lin2, 256, 256, i); return; }  i -= 65536;
  if (i < 16384) { wt3_elem(lin3_w, wt_lin3, 64, 64, i);   return; }  i -= 16384;
  if (i < 32768) { wt3_elem(aa1_w, wt_aa1, 256, 256, i);   return; }  i -= 32768;
  if (i < 65536) { wt3_elem(aa2_w, wt_aa2, 256, 256, i);   return; }  i -= 65536;
  if (i < 65536) { wt3_elem(aa3_w, wt_aa3, 256, 256, i);   return; }  i -= 65536;
  if (i < 8192)  { wt3_elem(aa4_w, wt_aa4, 32, 20, i);     return; }  i -= 8192;
  if (i < 16384) { wt2_elem(c1_w, wt_c1, 128, 128, i);     return; }  i -= 16384;
  if (i < 16384) { wt2_elem(c2_w, wt_c2, 128, 128, i);     return; }
}

__global__ void k_statfin(float* stats, const float* __restrict__ ms_, int n) {
  int d = threadIdx.x;
  if (d < 64) {
    float invn = 1.0f / (float)n;
    float m  = stats[d] * invn;
    float e2 = stats[64 + d] * invn;
    float ms = ms_[d];
    float var = e2 - (2.0f * ms - ms * ms) * m * m;
    stats[128 + d] = ms * m;
    stats[192 + d] = rsqrtf(var + 1e-5f);
  }
}

__global__ __launch_bounds__(256) void k_norm(const float* __restrict__ h,
                                              const float* __restrict__ stats,
                                              const float* __restrict__ w,
                                              const float* __restrict__ b,
                                              unsigned short* __restrict__ zcol,
                                              const unsigned short* __restrict__ prev, int n) {
  int i = blockIdx.x * 256 + threadIdx.x;
  if (i >= n * 64) return;
  int r = i >> 6, d = i & 63;
  float v = (h[i] - stats[128 + d]) * stats[192 + d] * w[d] + b[d];
  if (prev) v += bf2f(prev[(size_t)r * 192 + d]);
  zcol[(size_t)r * 192 + d] = f2bf(v);
}

// ---------------- generic bf16 MFMA GEMM (for SAGE) ----------------
// Fused per-column stats (sum, sum^2 of the activated output) via LDS reduce
// + 128 global atomics per block — replaces the separate k_stats pass.
template <int NT>
__global__ __launch_bounds__(256) void mgemm(
    const void* __restrict__ A1, int lda1,
    const void* __restrict__ A2, int lda2, int K1, int a_bf16,
    const unsigned short* __restrict__ Wt,
    const float* __restrict__ bias,
    void* __restrict__ Cout, int ldc, int c_bf16, int act,
    float* __restrict__ stats_out,
    int M, int K, int N) {
  int lane = threadIdx.x & 63, wave = threadIdx.x >> 6;
  int quad = lane >> 4, col = lane & 15;
  int row0 = blockIdx.x * 128 + wave * 32;
  int n_base = blockIdx.y * NT * 16;

  __shared__ float ls[128];
  if (stats_out) {
    if (threadIdx.x < 128) ls[threadIdx.x] = 0.f;
    __syncthreads();
  }

  f4_t acc[2][NT];
  #pragma unroll
  for (int mt = 0; mt < 2; ++mt)
    #pragma unroll
    for (int nt = 0; nt < NT; ++nt) acc[mt][nt] = (f4_t)0.f;

  int gm[2];
  gm[0] = row0 + col;      if (gm[0] >= M) gm[0] = M - 1;
  gm[1] = row0 + 16 + col; if (gm[1] >= M) gm[1] = M - 1;

  for (int kc0 = 0; kc0 < K; kc0 += 32) {
    int kc = kc0 + quad * 8;
    bf8_t a[2];
    #pragma unroll
    for (int mt = 0; mt < 2; ++mt) {
      const void* src; size_t off;
      if (kc < K1) { src = A1; off = (size_t)gm[mt] * lda1 + kc; }
      else         { src = A2; off = (size_t)gm[mt] * lda2 + kc - K1; }
      if (a_bf16) {
        a[mt] = *(const bf8_t*)((const unsigned short*)src + off);
      } else {
        const float* p = (const float*)src + off;
        float4 f0 = *(const float4*)p;
        float4 f1 = *(const float4*)(p + 4);
        float ff[8] = {f0.x, f0.y, f0.z, f0.w, f1.x, f1.y, f1.z, f1.w};
        #pragma unroll
        for (int j = 0; j < 8; ++j) a[mt][j] = (short)f2bf(ff[j]);
      }
    }
    #pragma unroll
    for (int nt = 0; nt < NT; ++nt) {
      bf8_t b = *(const bf8_t*)(Wt + (size_t)(n_base + nt * 16 + col) * K + kc);
      acc[0][nt] = __builtin_amdgcn_mfma_f32_16x16x32_bf16(a[0], b, acc[0][nt], 0, 0, 0);
      acc[1][nt] = __builtin_amdgcn_mfma_f32_16x16x32_bf16(a[1], b, acc[1][nt], 0, 0, 0);
    }
  }

  #pragma unroll
  for (int nt = 0; nt < NT; ++nt) {
    int n = n_base + nt * 16 + col;
    float bs = (bias && n < N) ? bias[n] : 0.f;
    float sa = 0.f, s2a = 0.f;
    #pragma unroll
    for (int mt = 0; mt < 2; ++mt)
      #pragma unroll
      for (int r = 0; r < 4; ++r) {
        int row = row0 + mt * 16 + quad * 4 + r;
        if (row >= M || n >= N) continue;
        float v = acc[mt][nt][r] + bs;
        if (act) v = gelu_f(v);
        sa += v; s2a += v * v;
        if (c_bf16) ((unsigned short*)Cout)[(size_t)row * ldc + n] = f2bf(v);
        else        ((float*)Cout)[(size_t)row * ldc + n] = v;
      }
    if (stats_out && n < N) {
      atomicAdd(&ls[n & 63], sa);
      atomicAdd(&ls[64 + (n & 63)], s2a);
    }
  }
  if (stats_out) {
    __syncthreads();
    if (threadIdx.x < 128) atomicAdd(&stats_out[threadIdx.x], ls[threadIdx.x]);
  }
}

// ---------------- block-cooperative fused node pipeline (8 waves) ----------
// Block = 512 thr = 8 waves = 64 rows; wave w owns output cols [32w,32w+32).
// ANTI-SPILL (round 7): halving the per-wave column slice halves the
// accumulator to acc[4][2] = 32 VGPRs. Rounds 3-6 proved the 4-wave acc[4][4]
// (64 regs) + prefetch window cannot fit any launch-bounds cap without
// 130-400 MB of scratch traffic. Live set now ~95 regs <= the 128 cap of
// (512,4) -> 16 waves/CU (2 blocks), no scratch. Weight traffic per block
// unchanged (each weight read once per 64 rows).
template <int K, bool DYT>
__device__ inline void node_gemm8(unsigned short (*H)[264],
                                  const unsigned short* __restrict__ W,
                                  const float* __restrict__ bias,
                                  int wave, int quad, int col,
                                  const float* __restrict__ a2w,
                                  const float* __restrict__ a2b,
                                  const float* __restrict__ aal) {
  constexpr int KS = K >> 5;
  f4_t acc[4][2];
  #pragma unroll
  for (int mt = 0; mt < 4; ++mt)
    #pragma unroll
    for (int nt = 0; nt < 2; ++nt) acc[mt][nt] = (f4_t)0.f;

  // b(s,nt) at wp + (s*256 + nt*16)*32  (blocked layout, Np=256)
  const unsigned short* wp = W + (size_t)(wave * 32 + col) * 32 + quad * 8;
  bf8_t bc[2];
  #pragma unroll
  for (int nt = 0; nt < 2; ++nt)
    bc[nt] = *(const bf8_t*)(wp + (size_t)(nt * 16) * 32);

  #pragma unroll 2
  for (int s = 0; s < KS; ++s) {
    bf8_t am[4];
    #pragma unroll
    for (int mt = 0; mt < 4; ++mt)
      am[mt] = *(const bf8_t*)&H[mt * 16 + col][s * 32 + quad * 8];
    bf8_t bn[2];
    if (s + 1 < KS) {
      #pragma unroll
      for (int nt = 0; nt < 2; ++nt)
        bn[nt] = *(const bf8_t*)(wp + (size_t)((s + 1) * 256 + nt * 16) * 32);
    }
    #pragma unroll
    for (int nt = 0; nt < 2; ++nt)
      #pragma unroll
      for (int mt = 0; mt < 4; ++mt)
        acc[mt][nt] = __builtin_amdgcn_mfma_f32_16x16x32_bf16(am[mt], bc[nt], acc[mt][nt], 0, 0, 0);
    if (s + 1 < KS) {
      #pragma unroll
      for (int nt = 0; nt < 2; ++nt) bc[nt] = bn[nt];
    }
  }
  __syncthreads();   // all reads of H complete before epilogue writes
  float sa = DYT ? (2.0f * aal[0]) : 0.f;
  #pragma unroll
  for (int nt = 0; nt < 2; ++nt) {
    int n = wave * 32 + nt * 16 + col;
    float bs = bias[n];
    float w_ = DYT ? a2w[n] : 0.f;
    float b_ = DYT ? a2b[n] : 0.f;
    #pragma unroll
    for (int mt = 0; mt < 4; ++mt)
      #pragma unroll
      for (int r4 = 0; r4 < 4; ++r4) {
        float v = gelu_f(acc[mt][nt][r4] + bs);
        if (DYT) v = dyt_f(v, sa, w_, b_);
        H[mt * 16 + quad * 4 + r4][n] = f2bf(v);
      }
  }
  __syncthreads();
}

__global__ __launch_bounds__(512, 4) void k_node(
    const unsigned short* __restrict__ z_bf,
    const float* __restrict__ x_res,
    const float* __restrict__ d1w, const float* __restrict__ d1b, const float* __restrict__ d1a,
    const unsigned short* __restrict__ wt1, const float* __restrict__ b1,
    const unsigned short* __restrict__ wt2, const float* __restrict__ b2,
    const unsigned short* __restrict__ wt3, const float* __restrict__ b3,
    const float* __restrict__ d2w, const float* __restrict__ d2b, const float* __restrict__ d2a,
    const float* __restrict__ a1w, const float* __restrict__ a1b, const float* __restrict__ a1a,
    const unsigned short* __restrict__ wa1, const float* __restrict__ ba1,
    const unsigned short* __restrict__ wa2, const float* __restrict__ ba2,
    const unsigned short* __restrict__ wa3, const float* __restrict__ ba3,
    const float* __restrict__ a2w, const float* __restrict__ a2b, const float* __restrict__ a2a,
    const unsigned short* __restrict__ wa4, const float* __restrict__ ba4,
    unsigned short* __restrict__ zn_bf,
    float* __restrict__ out, int M) {
  __shared__ unsigned short H[64][264];   // 33.8 KB
  __shared__ float fscr[512 + 64];        // rownorm partials + inv norms
  int t = threadIdx.x;
  int lane = t & 63, wave = t >> 6;       // 8 waves
  int quad = lane >> 4, col = lane & 15;
  int brow = blockIdx.x * 64;

  // ---- stage H = dyt1(z rows): 512 thr = 64 rows x 8 parts x 24 cols ----
  {
    int row = t >> 3, part = t & 7;
    int gr = brow + row; if (gr >= M) gr = M - 1;
    const unsigned short* zp = z_bf + (size_t)gr * 192 + part * 24;
    float s1 = 2.0f * d1a[0];
    #pragma unroll
    for (int j = 0; j < 3; ++j) {
      bf8_t v = *(const bf8_t*)(zp + j * 8);
      int k0 = part * 24 + j * 8;
      #pragma unroll
      for (int jj = 0; jj < 8; ++jj) {
        float f = bf2f((unsigned short)v[jj]);
        v[jj] = (short)f2bf(dyt_f(f, s1, d1w[k0 + jj], d1b[k0 + jj]));
      }
      *(bf8_t*)&H[row][k0] = v;
    }
  }
  __syncthreads();

  // ---- lin1 (K=192), lin2 (K=256) ----
  node_gemm8<192, false>(H, wt1, b1, wave, quad, col, nullptr, nullptr, nullptr);
  node_gemm8<256, false>(H, wt2, b2, wave, quad, col, nullptr, nullptr, nullptr);

  // ---- lin3 (K=256, N=64): 8 waves = 2 m-halves x 4 col-tiles ----
  {
    int mhalf = wave >> 2, ctile = wave & 3;
    f4_t a3[2];
    a3[0] = (f4_t)0.f; a3[1] = (f4_t)0.f;
    const unsigned short* wp3 = wt3 + (size_t)(ctile * 16 + col) * 32 + quad * 8;
    bf8_t bc = *(const bf8_t*)(wp3);
    #pragma unroll 2
    for (int s = 0; s < 8; ++s) {
      bf8_t am[2];
      #pragma unroll
      for (int i = 0; i < 2; ++i)
        am[i] = *(const bf8_t*)&H[(mhalf * 2 + i) * 16 + col][s * 32 + quad * 8];
      bf8_t bn;
      if (s + 1 < 8) bn = *(const bf8_t*)(wp3 + (size_t)((s + 1) * 64) * 32);
      #pragma unroll
      for (int i = 0; i < 2; ++i)
        a3[i] = __builtin_amdgcn_mfma_f32_16x16x32_bf16(am[i], bc, a3[i], 0, 0, 0);
      if (s + 1 < 8) bc = bn;
    }
    __syncthreads();                     // all lin3 reads of H complete
    // vv (fp32) overlaid into H's storage ([64][66] floats)
    float* fb = (float*)H;
    float s2d = 2.0f * d2a[0];
    int n = ctile * 16 + col;
    float bsn = b3[n], wd = d2w[n], bd = d2b[n];
    #pragma unroll
    for (int i = 0; i < 2; ++i)
      #pragma unroll
      for (int r4 = 0; r4 < 4; ++r4) {
        int row = (mhalf * 2 + i) * 16 + quad * 4 + r4;
        int gr = brow + row; if (gr >= M) gr = M - 1;
        float g = gelu_f(a3[i][r4] + bsn);
        float x = x_res[(size_t)gr * 64 + n];
        fb[row * 66 + n] = dyt_f(g, s2d, wd, bd) + x;
      }
    __syncthreads();
    // each thread owns (row = t>>3, cols q*8..q*8+8): read to REGISTERS
    int row = t >> 3, q = t & 7;
    float vreg[8];
    float s2 = 0.f;
    #pragma unroll
    for (int c8 = 0; c8 < 8; ++c8) {
      vreg[c8] = fb[row * 66 + q * 8 + c8];
      s2 += vreg[c8] * vreg[c8];
    }
    fscr[row * 8 + q] = s2;
    __syncthreads();
    if (t < 64) {
      float ssum = 0.f;
      #pragma unroll
      for (int j = 0; j < 8; ++j) ssum += fscr[t * 8 + j];
      fscr[512 + t] = 1.0f / (sqrtf(ssum) + 1e-10f);
    }
    __syncthreads();                     // all fb reads complete; inv ready
    // write adyt1([x_res, zn]) into H (bf16 view) from registers; write zn_bf
    float sa1 = 2.0f * a1a[0];
    float inv = fscr[512 + row];
    int gr = brow + row;
    int grc = (gr >= M) ? (M - 1) : gr;
    #pragma unroll
    for (int c8 = 0; c8 < 8; ++c8) {
      int c = q * 8 + c8;
      float zv = vreg[c8] * inv;
      if (gr < M) zn_bf[(size_t)gr * 64 + c] = f2bf(zv);
      float x = x_res[(size_t)grc * 64 + c];
      H[row][64 + c] = f2bf(dyt_f(zv, sa1, a1w[64 + c], a1b[64 + c]));
      H[row][c]      = f2bf(dyt_f(x,  sa1, a1w[c],      a1b[c]));
    }
    __syncthreads();
  }

  // ---- aa1 (K=128), aa2 (K=256), aa3 (K=256, adyt2 epilogue) ----
  node_gemm8<128, false>(H, wa1, ba1, wave, quad, col, nullptr, nullptr, nullptr);
  node_gemm8<256, false>(H, wa2, ba2, wave, quad, col, nullptr, nullptr, nullptr);
  node_gemm8<256, true >(H, wa3, ba3, wave, quad, col, a2w, a2b, a2a);

  // ---- aa4 (K=256, N=20 padded 32): waves 0-3 own m-tiles; 4-7 idle ----
  if (wave < 4) {
    f4_t a4[2];
    a4[0] = (f4_t)0.f; a4[1] = (f4_t)0.f;
    const unsigned short* wp4 = wa4 + (size_t)col * 32 + quad * 8;
    bf8_t bc[2];
    bc[0] = *(const bf8_t*)(wp4);
    bc[1] = *(const bf8_t*)(wp4 + (size_t)(16) * 32);
    #pragma unroll 2
    for (int s = 0; s < 8; ++s) {
      bf8_t am = *(const bf8_t*)&H[wave * 16 + col][s * 32 + quad * 8];
      bf8_t bn[2];
      if (s + 1 < 8) {
        bn[0] = *(const bf8_t*)(wp4 + (size_t)((s + 1) * 32) * 32);
        bn[1] = *(const bf8_t*)(wp4 + (size_t)((s + 1) * 32 + 16) * 32);
      }
      #pragma unroll
      for (int nt = 0; nt < 2; ++nt)
        a4[nt] = __builtin_amdgcn_mfma_f32_16x16x32_bf16(am, bc[nt], a4[nt], 0, 0, 0);
      if (s + 1 < 8) { bc[0] = bn[0]; bc[1] = bn[1]; }
    }
    float val[2][4];
    #pragma unroll
    for (int nt = 0; nt < 2; ++nt) {
      int n = nt * 16 + col;
      float bsv = (n < 20) ? ba4[n] : 0.f;
      #pragma unroll
      for (int r4 = 0; r4 < 4; ++r4) val[nt][r4] = a4[nt][r4] + bsv;
    }
    bool v1 = (col < 4);
    #pragma unroll
    for (int r4 = 0; r4 < 4; ++r4) {
      float m = val[0][r4];
      if (v1) m = fmaxf(m, val[1][r4]);
      m = fmaxf(m, __shfl_xor(m, 1, 64));
      m = fmaxf(m, __shfl_xor(m, 2, 64));
      m = fmaxf(m, __shfl_xor(m, 4, 64));
      m = fmaxf(m, __shfl_xor(m, 8, 64));
      float se = __expf(val[0][r4] - m) + (v1 ? __expf(val[1][r4] - m) : 0.f);
      se += __shfl_xor(se, 1, 64);
      se += __shfl_xor(se, 2, 64);
      se += __shfl_xor(se, 4, 64);
      se += __shfl_xor(se, 8, 64);
      float ls = __logf(se) + m;
      int row = brow + wave * 16 + quad * 4 + r4;
      if (row < M) {
        out[(size_t)row * 20 + col] = val[0][r4] - ls;
        if (v1) out[(size_t)row * 20 + 16 + col] = val[1][r4] - ls;
      }
    }
  }
}

// ---------------- fused edge head (prefetching, barrier-free) ----------------
__global__ __launch_bounds__(256) void k_edge(
    const unsigned short* __restrict__ zn_bf,
    const int* __restrict__ ci, const int* __restrict__ cj,
    const unsigned short* __restrict__ w1t, const float* __restrict__ b1,
    const unsigned short* __restrict__ w2t, const float* __restrict__ b2,
    const float* __restrict__ w3, const float* __restrict__ b3,
    float* __restrict__ out, int M) {
  __shared__ unsigned short h1s[4][16][136];
  int lane = threadIdx.x & 63, wave = threadIdx.x >> 6;
  int quad = lane >> 4, col = lane & 15;
  unsigned short (*h1)[136] = h1s[wave];
  int ntiles = (M + 63) >> 6;
  float b3v = b3[0];

  int tile = blockIdx.x;
  bf8_t afrag[4];
  if (tile < ntiles) {
    int r = tile * 64 + wave * 16 + col; if (r >= M) r = M - 1;
    const unsigned short* p0 = zn_bf + (size_t)ci[r] * 64;
    const unsigned short* p1 = zn_bf + (size_t)cj[r] * 64;
    afrag[0] = *(const bf8_t*)(p0 + quad * 8);
    afrag[1] = *(const bf8_t*)(p0 + 32 + quad * 8);
    afrag[2] = *(const bf8_t*)(p1 + quad * 8);
    afrag[3] = *(const bf8_t*)(p1 + 32 + quad * 8);
  }

  for (; tile < ntiles; tile += gridDim.x) {
    f4_t acc[8];
    #pragma unroll
    for (int nt = 0; nt < 8; ++nt) acc[nt] = (f4_t)0.f;
    #pragma unroll
    for (int s = 0; s < 4; ++s) {
      int kf = s * 32 + quad * 8;
      #pragma unroll
      for (int nt = 0; nt < 8; ++nt) {
        bf8_t b = *(const bf8_t*)(w1t + (size_t)(nt * 16 + col) * 128 + kf);
        acc[nt] = __builtin_amdgcn_mfma_f32_16x16x32_bf16(afrag[s], b, acc[nt], 0, 0, 0);
      }
    }

    int nxt = tile + gridDim.x;
    bf8_t nfrag[4];
    bool has_next = (nxt < ntiles);
    if (has_next) {
      int r = nxt * 64 + wave * 16 + col; if (r >= M) r = M - 1;
      const unsigned short* p0 = zn_bf + (size_t)ci[r] * 64;
      const unsigned short* p1 = zn_bf + (size_t)cj[r] * 64;
      nfrag[0] = *(const bf8_t*)(p0 + quad * 8);
      nfrag[1] = *(const bf8_t*)(p0 + 32 + quad * 8);
      nfrag[2] = *(const bf8_t*)(p1 + quad * 8);
      nfrag[3] = *(const bf8_t*)(p1 + 32 + quad * 8);
    }

    #pragma unroll
    for (int nt = 0; nt < 8; ++nt) {
      float bs = b1[nt * 16 + col];
      #pragma unroll
      for (int r4 = 0; r4 < 4; ++r4)
        h1[quad * 4 + r4][nt * 16 + col] = f2bf(gelu_f(acc[nt][r4] + bs));
    }

    f4_t a2[8];
    #pragma unroll
    for (int nt = 0; nt < 8; ++nt) a2[nt] = (f4_t)0.f;
    #pragma unroll
    for (int s = 0; s < 4; ++s) {
      int kc = s * 32 + quad * 8;
      bf8_t a0 = *(const bf8_t*)&h1[col][kc];
      #pragma unroll
      for (int nt = 0; nt < 8; ++nt) {
        bf8_t b = *(const bf8_t*)(w2t + (size_t)(nt * 16 + col) * 128 + kc);
        a2[nt] = __builtin_amdgcn_mfma_f32_16x16x32_bf16(a0, b, a2[nt], 0, 0, 0);
      }
    }
    float p[4] = {0.f, 0.f, 0.f, 0.f};
    #pragma unroll
    for (int nt = 0; nt < 8; ++nt) {
      float bs = b2[nt * 16 + col];
      float wv = w3[nt * 16 + col];
      #pragma unroll
      for (int r4 = 0; r4 < 4; ++r4)
        p[r4] += gelu_f(a2[nt][r4] + bs) * wv;
    }
    #pragma unroll
    for (int r4 = 0; r4 < 4; ++r4) {
      float s = p[r4];
      s += __shfl_xor(s, 1, 64);
      s += __shfl_xor(s, 2, 64);
      s += __shfl_xor(s, 4, 64);
      s += __shfl_xor(s, 8, 64);
      if (col == 0) {
        int row = tile * 64 + wave * 16 + quad * 4 + r4;
        if (row < M) out[row] = __builtin_amdgcn_rcpf(1.0f + __expf(-(s + b3v)));
      }
    }

    if (has_next) {
      afrag[0] = nfrag[0]; afrag[1] = nfrag[1];
      afrag[2] = nfrag[2]; afrag[3] = nfrag[3];
    }
  }
}

// ---------------- launcher ----------------
extern "C" void kernel_launch(void* const* d_in, const int* in_sizes, int n_in,
                              void* d_out, int out_size, void* d_ws, size_t ws_size,
                              hipStream_t stream) {
  const float* x_res  = (const float*)d_in[0];
  const float* Wl     = (const float*)d_in[1];
  const float* bl     = (const float*)d_in[2];
  const float* Wr     = (const float*)d_in[3];
  const float* gn_w   = (const float*)d_in[4];
  const float* gn_b   = (const float*)d_in[5];
  const float* gn_ms  = (const float*)d_in[6];
  const float* dyt1_w = (const float*)d_in[7];
  const float* dyt1_b = (const float*)d_in[8];
  const float* dyt1_a = (const float*)d_in[9];
  const float* lin1_w = (const float*)d_in[10];
  const float* lin1_b = (const float*)d_in[11];
  const float* lin2_w = (const float*)d_in[12];
  const float* lin2_b = (const float*)d_in[13];
  const float* lin3_w = (const float*)d_in[14];
  const float* lin3_b = (const float*)d_in[15];
  const float* dyt2_w = (const float*)d_in[16];
  const float* dyt2_b = (const float*)d_in[17];
  const float* dyt2_a = (const float*)d_in[18];
  const float* adyt1_w = (const float*)d_in[19];
  const float* adyt1_b = (const float*)d_in[20];
  const float* adyt1_a = (const float*)d_in[21];
  const float* aa1_w  = (const float*)d_in[22];
  const float* aa1_b  = (const float*)d_in[23];
  const float* aa2_w  = (const float*)d_in[24];
  const float* aa2_b  = (const float*)d_in[25];
  const float* aa3_w  = (const float*)d_in[26];
  const float* aa3_b  = (const float*)d_in[27];
  const float* adyt2_w = (const float*)d_in[28];
  const float* adyt2_b = (const float*)d_in[29];
  const float* adyt2_a = (const float*)d_in[30];
  const float* aa4_w  = (const float*)d_in[31];
  const float* aa4_b  = (const float*)d_in[32];
  const float* c1_w   = (const float*)d_in[33];
  const float* c1_b   = (const float*)d_in[34];
  const float* c2_w   = (const float*)d_in[35];
  const float* c2_b   = (const float*)d_in[36];
  const float* c3_w   = (const float*)d_in[37];
  const float* c3_b   = (const float*)d_in[38];
  const int*   edge   = (const int*)d_in[39];
  const int*   contact = (const int*)d_in[40];

  const size_t N = (size_t)Nn;
  const size_t ws_floats = ws_size / 4;

  float* ws    = (float*)d_ws;
  float* rdeg  = ws;
  float* hbuf  = rdeg + N;
  unsigned short* z_bf  = (unsigned short*)(hbuf + 64 * N);
  unsigned short* zn_bf = z_bf + 192 * N;
  float* stats = (float*)(zn_bf + 64 * N);          // 3 layers x 256 floats
  unsigned short* wt_sage = (unsigned short*)(stats + 768);
  unsigned short* wt_lin1 = wt_sage + 3 * 64 * 128;
  unsigned short* wt_lin2 = wt_lin1 + 256 * 192;
  unsigned short* wt_lin3 = wt_lin2 + 256 * 256;
  unsigned short* wt_aa1  = wt_lin3 + 64 * 256;
  unsigned short* wt_aa2  = wt_aa1 + 256 * 128;
  unsigned short* wt_aa3  = wt_aa2 + 256 * 256;
  unsigned short* wt_aa4  = wt_aa3 + 256 * 256;
  unsigned short* wt_c1   = wt_aa4 + 32 * 256;
  unsigned short* wt_c2   = wt_c1 + 128 * 128;
  unsigned short* wt_end  = wt_c2 + 128 * 128;
  float* pool  = (float*)((((uintptr_t)wt_end + 15) & ~(uintptr_t)15));
  const size_t persist = (size_t)(pool - ws);

  const size_t gnn_need = 32 * N + N + (N + 1) + N + (size_t)Ee + 256;
  if (ws_floats < persist + gnn_need) return;

  unsigned short* agg_bf = (unsigned short*)pool;
  int* cnt     = (int*)(pool + 32 * N);
  int* rowptr  = cnt + N;
  int* cursor  = rowptr + N + 1;
  int* colidx  = cursor + N;
  int* bsum    = colidx + Ee;

  const int* esrc = edge;
  const int* edst = edge + Ee;

  // ---- CSR build ----
  hipMemsetAsync(cnt, 0, N * sizeof(int), stream);
  hipMemsetAsync(stats, 0, 768 * sizeof(float), stream);
  k_degi<<<(Ee + 255) / 256, 256, 0, stream>>>(edst, cnt, Ee);
  const int nb = (Nn + 1023) / 1024;
  k_scan1<<<nb, 256, 0, stream>>>(cnt, cursor, bsum, rdeg, Nn);
  k_scan2<<<1, 256, 0, stream>>>(bsum, nb);
  k_scan3<<<(Nn + 255) / 256, 256, 0, stream>>>(cursor, bsum, rowptr, cursor, Nn, Ee);
  k_fill<<<(Ee + 255) / 256, 256, 0, stream>>>(esrc, edst, cursor, colidx, Ee);

  // ---- weight prep (single merged launch) ----
  k_wtall<<<(360448 + 255) / 256, 256, 0, stream>>>(
      Wl, Wr, lin1_w, lin2_w, lin3_w, aa1_w, aa2_w, aa3_w, aa4_w, c1_w, c2_w,
      wt_sage, wt_lin1, wt_lin2, wt_lin3, wt_aa1, wt_aa2, wt_aa3, wt_aa4,
      wt_c1, wt_c2);

  // xb = bf16(x_res) in zn_bf slot
  k_cvt<<<(int)((N * 64 + 255) / 256), 256, 0, stream>>>(x_res, zn_bf, (int)(N * 64));

  // ---- GNN phase (stats fused into mgemm epilogue) ----
  for (int l = 0; l < 3; ++l) {
    const unsigned short* xi = (l == 0) ? zn_bf : (z_bf + (size_t)(l - 1) * 64);
    int ldx = (l == 0) ? 64 : 192;
    float* stats_l = stats + (size_t)l * 256;
    k_gather<<<(Nn + 3) / 4, 256, 0, stream>>>(xi, ldx, rowptr, colidx, rdeg, agg_bf, Nn);
    mgemm<4><<<dim3((Nn + 127) / 128, 1), 256, 0, stream>>>(
        agg_bf, 64, xi, ldx, 64, 1,
        wt_sage + (size_t)l * 8192, bl + l * 64, hbuf, 64, 0, 1, stats_l, Nn, 128, 64);
    k_statfin<<<1, 64, 0, stream>>>(stats_l, gn_ms + l * 64, Nn);
    k_norm<<<(Nn * 64) / 256, 256, 0, stream>>>(hbuf, stats_l, gn_w + l * 64, gn_b + l * 64,
                                                z_bf + (size_t)l * 64,
                                                (l > 0) ? (z_bf + (size_t)(l - 1) * 64) : nullptr, Nn);
  }

  // ---- block-cooperative fused node pipeline (8 waves, anti-spill) ----
  k_node<<<(Nn + 63) / 64, 512, 0, stream>>>(
      z_bf, x_res,
      dyt1_w, dyt1_b, dyt1_a, wt_lin1, lin1_b, wt_lin2, lin2_b, wt_lin3, lin3_b,
      dyt2_w, dyt2_b, dyt2_a,
      adyt1_w, adyt1_b, adyt1_a, wt_aa1, aa1_b, wt_aa2, aa2_b, wt_aa3, aa3_b,
      adyt2_w, adyt2_b, adyt2_a, wt_aa4, aa4_b,
      zn_bf, (float*)d_out, Nn);

  // ---- fused edge head ----
  float* eout = (float*)d_out + (size_t)Nn * 20;
  k_edge<<<2048, 256, 0, stream>>>(zn_bf, contact, contact + EPp,
      wt_c1, c1_b, wt_c2, c2_b, c3_w, c3_b, eout, EPp);
}